// Round 11
// baseline (211.140 us; speedup 1.0000x reference)
//
#include <hip/hip_runtime.h>
#include <stdint.h>

#define NN 65536
#define EE 524288
#define BB 512

typedef unsigned short u16;
typedef __attribute__((ext_vector_type(8))) short s8v;    // 8 bf16 (4 VGPRs)
typedef __attribute__((ext_vector_type(4))) float f32x4;  // MFMA acc

__device__ __forceinline__ u16 f2b(float f) {
  union { float f; uint32_t u; } a{f};
  uint32_t r = a.u + 0x7fff + ((a.u >> 16) & 1);
  return (u16)(r >> 16);
}
__device__ __forceinline__ float b2f(u16 v) {
  union { uint32_t u; float f; } a{(uint32_t)v << 16};
  return a.f;
}
__device__ __forceinline__ int swz128(int r, int c) { return r * 128 + (c ^ ((r & 7) << 3)); }
__device__ __forceinline__ int swz64(int r, int c) { return r * 64 + (c ^ ((r & 7) << 3)); }

// ===================== graph prep: dense per-parcel u8 count matrix =====================
__global__ void k_scatterS(const int* __restrict__ src, const int* __restrict__ dst,
                           uint32_t* __restrict__ Sg) {
  int e = blockIdx.x * 256 + threadIdx.x;
  if (e >= EE) return;
  int s = src[e] & 127, d = dst[e];
  atomicAdd(&Sg[((size_t)d * 128 + s) >> 2], 1u << ((s & 3) * 8));
}

// ===================== weight prep: transposes + GAT folding =====================
// blocks 0..95: W1/W2 transpose->bf16; block 96: wv/q/ch
__global__ void k_prepAll(const float* __restrict__ W1, const float* __restrict__ W2,
                          const float* __restrict__ Wg_in, const float* __restrict__ al_in,
                          const float* __restrict__ ar_in, const float* __restrict__ Wpp,
                          const float* __restrict__ bpp, u16* __restrict__ w1t,
                          u16* __restrict__ w2t, float* __restrict__ wv,
                          float* __restrict__ q, float* __restrict__ ch) {
  int blk = blockIdx.x, t = threadIdx.x;
  if (blk < 96) {
    int i = blk * 256 + t;  // 24576
    if (i < 8192) {
      int n = i >> 6, k = i & 63;
      w1t[i] = f2b(W1[k * 128 + n]);
    } else {
      int j = i - 8192;
      int n = j >> 7, k = j & 127;
      w2t[j] = f2b(W2[k * 128 + n]);
    }
  } else {
    __shared__ float su[384];
    for (int i = t; i < 384; i += 256) {
      int h = i >> 7, k = i & 127;
      float s = 0.f, sw = 0.f;
#pragma unroll 4
      for (int c = 0; c < 128; ++c) {
        float g = Wg_in[k * 384 + h * 128 + c];
        s += g * al_in[h * 128 + c];
        sw += g * ar_in[h * 128 + c];
      }
      su[i] = s;
      wv[i] = sw;
    }
    __syncthreads();
    for (int i = t; i < 384; i += 256) {
      int h = i >> 7, j = i & 127;
      float s = 0.f;
#pragma unroll 4
      for (int k = 0; k < 128; ++k) s += Wpp[j * 128 + k] * su[h * 128 + k];
      q[i] = s;
    }
    if (t < 3) {
      float s = 0.f;
#pragma unroll 4
      for (int k = 0; k < 128; ++k) s += bpp[k] * su[t * 128 + k];
      ch[t] = s;
    }
  }
}

// ===================== epilogue weight folding =====================
// Afold layout [6][128][16]: 0=A_hrs (hrs path via img2poi), 1=A_T1 (hrs_agg),
// 2=A_T2 (poi_agg), 3..5=A_pld_h (poi2img). bias_out[16].
__global__ void __launch_bounds__(256) k_fold(
    const float* __restrict__ Wg_w, const float* __restrict__ bg_w,
    const float* __restrict__ bg_in, const float* __restrict__ Wph,
    const float* __restrict__ bph, const float* __restrict__ Wh1,
    const float* __restrict__ bh1, const float* __restrict__ Wp1,
    const float* __restrict__ bp1, const float* __restrict__ Wpp,
    const float* __restrict__ bpp, const float* __restrict__ Wg_in,
    const float* __restrict__ Wfc, const float* __restrict__ bfc,
    float* __restrict__ Afold, float* __restrict__ bias_out) {
  __shared__ float sB[128 * 16];
  int blk = blockIdx.x, t = threadIdx.x;
  if (blk == 0) {
    // B0 = G @ Wfc_s0 (G = mean_h Wg_w_h), then A_hrs = Wph @ B0
    for (int i = t; i < 2048; i += 256) {
      int m = i >> 4, o = i & 15;
      float acc = 0.f;
      for (int j = 0; j < 128; ++j) {
        float g = (Wg_w[m * 384 + j] + Wg_w[m * 384 + 128 + j] + Wg_w[m * 384 + 256 + j]) *
                  (1.0f / 3.0f);
        acc += g * Wfc[j * 16 + o];
      }
      sB[i] = acc;
    }
    __syncthreads();
    for (int i = t; i < 2048; i += 256) {
      int k = i >> 4, o = i & 15;
      float acc = 0.f;
      for (int m = 0; m < 128; ++m) acc += Wph[k * 128 + m] * sB[m * 16 + o];
      Afold[i] = acc;
    }
  } else if (blk == 1) {
    for (int i = t; i < 2048; i += 256) {
      int k = i >> 4, o = i & 15;
      float acc = 0.f;
      for (int m = 0; m < 128; ++m) acc += Wh1[k * 128 + m] * Wfc[(384 + m) * 16 + o];
      Afold[2048 + i] = acc;
    }
  } else if (blk == 2) {
    for (int i = t; i < 2048; i += 256) {
      int k = i >> 4, o = i & 15;
      float acc = 0.f;
      for (int m = 0; m < 128; ++m) acc += Wp1[k * 128 + m] * Wfc[(128 + m) * 16 + o];
      Afold[4096 + i] = acc;
    }
  } else if (blk < 6) {
    int h = blk - 3;
    // C_h = Wg_in_h @ Wfc_s2, A_pld_h = (1/3) Wpp @ C_h
    for (int i = t; i < 2048; i += 256) {
      int m = i >> 4, o = i & 15;
      float acc = 0.f;
      for (int c = 0; c < 128; ++c) acc += Wg_in[m * 384 + h * 128 + c] * Wfc[(256 + c) * 16 + o];
      sB[i] = acc;
    }
    __syncthreads();
    for (int i = t; i < 2048; i += 256) {
      int k = i >> 4, o = i & 15;
      float acc = 0.f;
      for (int m = 0; m < 128; ++m) acc += Wpp[k * 128 + m] * sB[m * 16 + o];
      Afold[(3 + h) * 2048 + i] = acc * (1.0f / 3.0f);
    }
  } else {
    // bias_out
    __shared__ float sD0[128];   // bph @ G
    __shared__ float sE[128];    // (1/3) sum_h bpp @ Wg_in_h  (+ g0in added later)
    if (t < 128) {
      float acc = 0.f;
      for (int k = 0; k < 128; ++k) {
        float g = (Wg_w[k * 384 + t] + Wg_w[k * 384 + 128 + t] + Wg_w[k * 384 + 256 + t]) *
                  (1.0f / 3.0f);
        acc += bph[k] * g;
      }
      sD0[t] = acc;
      float e = 0.f;
      for (int h = 0; h < 3; ++h) {
        float a2 = 0.f;
        for (int m = 0; m < 128; ++m) a2 += bpp[m] * Wg_in[m * 384 + h * 128 + t];
        e += a2;
      }
      float g0in = (bg_in[t] + bg_in[128 + t] + bg_in[256 + t]) * (1.0f / 3.0f);
      sE[t] = e * (1.0f / 3.0f) + g0in;
    }
    __syncthreads();
    if (t < 16) {
      float acc = bfc[t];
      for (int j = 0; j < 128; ++j) {
        float g0w = (bg_w[j] + bg_w[128 + j] + bg_w[256 + j]) * (1.0f / 3.0f);
        acc += (sD0[j] + g0w) * Wfc[j * 16 + t];              // img2poi bias
        acc += bp1[j] * Wfc[(128 + j) * 16 + t];              // poi_agg bias
        acc += sE[j] * Wfc[(256 + j) * 16 + t];               // poi2img bias
        acc += bh1[j] * Wfc[(384 + j) * 16 + t];              // hrs_agg bias
      }
      bias_out[t] = acc;
    }
  }
}

// ===================== hrs encoder + er (fused) =====================
__global__ void __launch_bounds__(512) k_hrs(const float* __restrict__ img,
                                             const float* __restrict__ Whrs,
                                             const float* __restrict__ bhrs,
                                             const float* __restrict__ Wph,
                                             const float* __restrict__ bph,
                                             const float* __restrict__ wv,
                                             float* __restrict__ hrs, float* __restrict__ er) {
  __shared__ float sI[4096];
  __shared__ float sRed[4][128];
  __shared__ float sHrs[2][128];
  __shared__ float sPh[2][128];
  int r0 = blockIdx.x * 2;
  int t = threadIdx.x;
  const float4* gsrc = (const float4*)(img + (size_t)r0 * 2048);
  float4* ldst = (float4*)sI;
  for (int i = t; i < 1024; i += 512) ldst[i] = gsrc[i];
  __syncthreads();
  int c = t & 127, g = t >> 7;
  int row = g & 1, ks = g >> 1;
  const float* s = sI + row * 2048 + ks * 1024;
  const float* W = Whrs + (size_t)(ks * 1024) * 128 + c;
  float a0 = 0.f, a1 = 0.f, a2 = 0.f, a3 = 0.f;
  for (int k = 0; k < 1024; k += 4) {
    a0 += s[k] * W[(size_t)k * 128];
    a1 += s[k + 1] * W[(size_t)(k + 1) * 128];
    a2 += s[k + 2] * W[(size_t)(k + 2) * 128];
    a3 += s[k + 3] * W[(size_t)(k + 3) * 128];
  }
  sRed[g][c] = (a0 + a1) + (a2 + a3);
  __syncthreads();
  if (t < 256) {
    int rr = t >> 7, cc = t & 127;
    float v = sRed[rr][cc] + sRed[rr + 2][cc] + bhrs[cc];
    hrs[(r0 + rr) * 128 + cc] = v;
    sHrs[rr][cc] = v;
  }
  __syncthreads();
  if (t < 256) {
    int rr = t >> 7, cc = t & 127;
    float acc = bph[cc];
#pragma unroll 4
    for (int k = 0; k < 128; ++k) acc += sHrs[rr][k] * Wph[k * 128 + cc];
    sPh[rr][cc] = acc;
  }
  __syncthreads();
  if (t < 6) {
    int rr = t / 3, h = t % 3;
    float s2 = 0.f;
#pragma unroll 4
    for (int k = 0; k < 128; ++k) s2 += sPh[rr][k] * wv[h * 128 + k];
    er[(r0 + rr) * 3 + h] = s2;
  }
}

// ===================== FUSED GCN via dense S' + MFMA (A-fragments reg-hoisted) ============
__global__ void __launch_bounds__(512) k_gcn_fused(
    const float* __restrict__ x, const float* __restrict__ b1, const float* __restrict__ b2,
    const uint8_t* __restrict__ Sg8, const float* __restrict__ q, const float* __restrict__ ch,
    const float* __restrict__ er, const float* __restrict__ hrs,
    const u16* __restrict__ w1t, const u16* __restrict__ w2t, float* __restrict__ poi_pool,
    float* __restrict__ pooled, u16* __restrict__ mfnb) {
  extern __shared__ char sm[];
  u16* sS = (u16*)sm;
  u16* sB2 = (u16*)(sm + 32768);
  u16* sPt = (u16*)(sm + 32768);
  u16* sXt = (u16*)(sm + 65536);
  u16* sAgg1 = (u16*)(sm + 81920);
  u16* sW1t = (u16*)(sm + 98304);
  float* sXrm = (float*)(sm + 114688);
  u16* sW2t = (u16*)(sm + 114688);
  u16* sAgg2 = (u16*)(sm + 65536);
  u16* sP = (u16*)sm;
  float* sNorm = (float*)(sm + 147968);
  float* sQ = (float*)(sm + 148480);
  float* sAl = (float*)(sm + 150016);
  float* sPool = (float*)(sm + 151552);
  float* sEr = (float*)(sm + 152064);
  float* sCh = (float*)(sm + 152080);

  int b = blockIdx.x, t = threadIdx.x;
  int base = b << 7;
  int l = t & 63, w = t >> 6;
  const uint8_t* Sgb = Sg8 + (size_t)base * 128;

  // ---- phase 0: norms from u8 row-sums; stage Xrm, W1t, q/er/ch ----
  if (t < 128) {
    const uint4* rp = (const uint4*)(Sgb + (size_t)t * 128);
    uint32_t s = 0;
#pragma unroll
    for (int k = 0; k < 8; ++k) {
      uint4 v = rp[k];
      uint32_t ws[4] = {v.x, v.y, v.z, v.w};
#pragma unroll
      for (int p = 0; p < 4; ++p)
        s += (ws[p] & 0xff) + ((ws[p] >> 8) & 0xff) + ((ws[p] >> 16) & 0xff) + (ws[p] >> 24);
    }
    sNorm[t] = rsqrtf((float)s + 1.0f);
  }
  for (int i = t; i < 8192; i += 512) {
    int s = i >> 6, f = i & 63;
    sXrm[s * 65 + f] = x[(size_t)(base + s) * 64 + f];
  }
  for (int g = t; g < 1024; g += 512) {
    int n = g >> 3, blk = g & 7;
    *(uint4*)(sW1t + n * 64 + ((blk ^ (n & 7)) << 3)) = ((const uint4*)w1t)[g];
  }
  for (int i = t; i < 384; i += 512) sQ[i] = q[i];
  if (t < 3) {
    sEr[t] = er[b * 3 + t];
    sCh[t] = ch[t];
  }
  __syncthreads();

  // ---- phase 1: S' from u8 counts + X transpose->bf16 ----
  {
    int r = t >> 2, sb = (t & 3) * 32;
    const uint4* cp = (const uint4*)(Sgb + r * 128 + sb);
    uint4 c0 = cp[0], c1 = cp[1];
    float nr = sNorm[r];
    int sw = (r & 7) << 3;
    uint32_t words[8] = {c0.x, c0.y, c0.z, c0.w, c1.x, c1.y, c1.z, c1.w};
#pragma unroll
    for (int qd = 0; qd < 8; ++qd) {
      uint32_t wd = words[qd];
#pragma unroll
      for (int p = 0; p < 4; p += 2) {
        int s0 = sb + qd * 4 + p;
        float v0 = ((float)((wd >> (p * 8)) & 0xff) + (r == s0 ? 1.f : 0.f)) * nr * sNorm[s0];
        float v1 =
            ((float)((wd >> (p * 8 + 8)) & 0xff) + (r == s0 + 1 ? 1.f : 0.f)) * nr * sNorm[s0 + 1];
        uint32_t pk = (uint32_t)f2b(v0) | ((uint32_t)f2b(v1) << 16);
        *(uint32_t*)(sS + r * 128 + (s0 ^ sw)) = pk;
      }
    }
  }
  for (int i = t; i < 4096; i += 512) {
    int f = i >> 6, s = (i & 63) * 2;
    float v0 = sXrm[s * 65 + f] * sNorm[s];
    float v1 = sXrm[(s + 1) * 65 + f] * sNorm[s + 1];
    uint32_t pk = (uint32_t)f2b(v0) | ((uint32_t)f2b(v1) << 16);
    *(uint32_t*)(sXt + (f * 128 + (s ^ ((f & 7) << 3)))) = pk;
  }
  __syncthreads();

  int mrow = w * 16 + (l & 15);
  int kblk = (l >> 4) * 8;
  int rbase = w * 16 + (l >> 4) * 4;

  // ---- phase 3: agg1 = S' @ X (A hoisted); stage W2t ----
  {
    s8v a4[4];
#pragma unroll
    for (int ks = 0; ks < 4; ++ks) a4[ks] = *(const s8v*)(sS + swz128(mrow, ks * 32 + kblk));
    for (int nt = 0; nt < 4; ++nt) {
      f32x4 acc = {0.f, 0.f, 0.f, 0.f};
      int cg = nt * 16 + (l & 15);
#pragma unroll
      for (int ks = 0; ks < 4; ++ks)
        acc = __builtin_amdgcn_mfma_f32_16x16x32_bf16(
            a4[ks], *(const s8v*)(sXt + swz128(cg, ks * 32 + kblk)), acc, 0, 0, 0);
#pragma unroll
      for (int rg = 0; rg < 4; ++rg) sAgg1[swz64(rbase + rg, cg)] = f2b(acc[rg]);
    }
  }
  for (int g = t; g < 2048; g += 512) {
    int n = g >> 4, blk = g & 15;
    *(uint4*)(sW2t + n * 128 + ((blk ^ (n & 7)) << 3)) = ((const uint4*)w2t)[g];
  }
  __syncthreads();

  // ---- phase 4: h1 = relu(agg1 @ W1 + b1) -> h1^T (A hoisted) ----
  {
    s8v a2[2];
#pragma unroll
    for (int ks = 0; ks < 2; ++ks) a2[ks] = *(const s8v*)(sAgg1 + swz64(mrow, ks * 32 + kblk));
    for (int nt = 0; nt < 8; ++nt) {
      int cg = nt * 16 + (l & 15);
      float bv = b1[cg];
      f32x4 acc = {bv, bv, bv, bv};
#pragma unroll
      for (int ks = 0; ks < 2; ++ks)
        acc = __builtin_amdgcn_mfma_f32_16x16x32_bf16(
            a2[ks], *(const s8v*)(sW1t + swz64(cg, ks * 32 + kblk)), acc, 0, 0, 0);
      u16 h0 = f2b(fmaxf(acc[0], 0.f)), h1v = f2b(fmaxf(acc[1], 0.f));
      u16 h2 = f2b(fmaxf(acc[2], 0.f)), h3 = f2b(fmaxf(acc[3], 0.f));
      uint2 pk;
      pk.x = (uint32_t)h0 | ((uint32_t)h1v << 16);
      pk.y = (uint32_t)h2 | ((uint32_t)h3 << 16);
      *(uint2*)(sB2 + swz128(cg, rbase)) = pk;
    }
  }
  __syncthreads();

  // ---- phase 5: agg2 = S' @ h1 (A hoisted) ----
  {
    s8v a4[4];
#pragma unroll
    for (int ks = 0; ks < 4; ++ks) a4[ks] = *(const s8v*)(sS + swz128(mrow, ks * 32 + kblk));
    for (int nt = 0; nt < 8; ++nt) {
      f32x4 acc = {0.f, 0.f, 0.f, 0.f};
      int cg = nt * 16 + (l & 15);
#pragma unroll
      for (int ks = 0; ks < 4; ++ks)
        acc = __builtin_amdgcn_mfma_f32_16x16x32_bf16(
            a4[ks], *(const s8v*)(sB2 + swz128(cg, ks * 32 + kblk)), acc, 0, 0, 0);
#pragma unroll
      for (int rg = 0; rg < 4; ++rg) sAgg2[swz128(rbase + rg, cg)] = f2b(acc[rg]);
    }
  }
  __syncthreads();

  // ---- phase 6: poi = agg2 @ W2 + b2 -> sP + sPt (A hoisted) ----
  {
    s8v a4[4];
#pragma unroll
    for (int ks = 0; ks < 4; ++ks) a4[ks] = *(const s8v*)(sAgg2 + swz128(mrow, ks * 32 + kblk));
    for (int nt = 0; nt < 8; ++nt) {
      int cg = nt * 16 + (l & 15);
      float bv = b2[cg];
      f32x4 acc = {bv, bv, bv, bv};
#pragma unroll
      for (int ks = 0; ks < 4; ++ks)
        acc = __builtin_amdgcn_mfma_f32_16x16x32_bf16(
            a4[ks], *(const s8v*)(sW2t + swz128(cg, ks * 32 + kblk)), acc, 0, 0, 0);
      u16 p0 = f2b(acc[0]), p1 = f2b(acc[1]), p2 = f2b(acc[2]), p3 = f2b(acc[3]);
#pragma unroll
      for (int rg = 0; rg < 4; ++rg)
        sP[swz128(rbase + rg, cg)] = (rg == 0) ? p0 : (rg == 1) ? p1 : (rg == 2) ? p2 : p3;
      uint2 pk;
      pk.x = (uint32_t)p0 | ((uint32_t)p1 << 16);
      pk.y = (uint32_t)p2 | ((uint32_t)p3 << 16);
      *(uint2*)(sPt + swz128(cg, rbase)) = pk;
    }
  }
  __syncthreads();

  // ---- tail: pool from Pt rows ----
  if (t < 128) {
    int c = t;
    float s = 0.f;
    const u16* rowp = sPt + c * 128;
    int sw = (c & 7) << 3;
#pragma unroll
    for (int k8 = 0; k8 < 16; ++k8) {
      s8v v = *(const s8v*)(rowp + ((k8 * 8) ^ sw));
#pragma unroll
      for (int j = 0; j < 8; ++j) s += b2f((u16)v[j]);
    }
    sPool[c] = s;
    poi_pool[b * 128 + c] = s * (1.0f / 128.0f);
  }
  if (t < 384) {
    int r = t & 127, h = t >> 7;
    int sw = (r & 7) << 3;
    const u16* rowp = sP + r * 128;
    const float* qh = &sQ[h * 128];
    float d = 0.f;
#pragma unroll
    for (int k8 = 0; k8 < 16; ++k8) {
      int c8 = (k8 * 8) ^ sw;
      s8v v = *(const s8v*)(rowp + c8);
#pragma unroll
      for (int j = 0; j < 8; ++j) d += b2f((u16)v[j]) * qh[c8 + j];
    }
    float e = d + sCh[h] + sEr[h];
    sAl[h * 128 + r] = (e > 0.f) ? e : 0.2f * e;
  }
  __syncthreads();

  if (t < 192) {
    int h = t >> 6, ll = t & 63;
    float v0 = sAl[h * 128 + ll], v1 = sAl[h * 128 + 64 + ll];
    float m = fmaxf(v0, v1);
    for (int off = 32; off > 0; off >>= 1) m = fmaxf(m, __shfl_xor(m, off));
    float x0 = __expf(v0 - m), x1 = __expf(v1 - m);
    float s = x0 + x1;
    for (int off = 32; off > 0; off >>= 1) s += __shfl_xor(s, off);
    float inv = 1.0f / s;
    sAl[h * 128 + ll] = x0 * inv;
    sAl[h * 128 + 64 + ll] = x1 * inv;
  }
  __syncthreads();

  if (t < 384) {
    int hh = t >> 7, c = t & 127;
    int sw = (c & 7) << 3;
    const u16* rowp = sPt + c * 128;
    const float* al = &sAl[hh * 128];
    float s = 0.f;
#pragma unroll
    for (int k8 = 0; k8 < 16; ++k8) {
      int r8 = (k8 * 8) ^ sw;
      s8v v = *(const s8v*)(rowp + r8);
#pragma unroll
      for (int j = 0; j < 8; ++j) s += b2f((u16)v[j]) * al[r8 + j];
    }
    pooled[((size_t)b * 3 + hh) * 128 + c] = s;
  }
  __syncthreads();

  // ---- fused mfn (bf16 out) ----
  float hv = 0.f, pv = 0.f;
  if (t < 128) {
    hv = hrs[base + t];
    pv = sPool[t] * (1.0f / 128.0f);
    sQ[t] = hv * hv + pv * pv;
  }
  __syncthreads();
  if (t < 64) {
    float v = sQ[t] + sQ[t + 64];
    for (int off = 32; off > 0; off >>= 1) v += __shfl_xor(v, off);
    if (t == 0) sQ[0] = rsqrtf(v);
  }
  __syncthreads();
  if (t < 128) {
    float rn = sQ[0];
    mfnb[b * 256 + t] = f2b(hv * rn);
    mfnb[b * 256 + 128 + t] = f2b(pv * rn);
  }
}

// ===================== med via MFMA: med = (mfn @ mfn^T + 1)/2 =====================
__global__ void __launch_bounds__(256) k_med(const u16* __restrict__ mfnb,
                                             float* __restrict__ med) {
  __shared__ u16 sA[32 * 256];
  __shared__ u16 sB[32 * 256];
  int bi = blockIdx.x >> 4, bj = blockIdx.x & 15;
  int t = threadIdx.x;
  const uint4* srcA = (const uint4*)(mfnb + (size_t)bi * 32 * 256);
  const uint4* srcB = (const uint4*)(mfnb + (size_t)bj * 32 * 256);
  for (int g = t; g < 1024; g += 256) {
    int r = g >> 5, blk = g & 31;
    int db = (blk & 24) | ((blk ^ (r & 7)) & 7);
    uint4 va = srcA[g];
    uint4 vb = srcB[g];
    *(uint4*)(sA + r * 256 + db * 8) = va;
    *(uint4*)(sB + r * 256 + db * 8) = vb;
  }
  __syncthreads();
  int l = t & 63, w = t >> 6;
  int wr = w >> 1, wc = w & 1;
  int arow = wr * 16 + (l & 15);
  int brow = wc * 16 + (l & 15);
  int kblk = (l >> 4) * 8;
  f32x4 acc = {0.f, 0.f, 0.f, 0.f};
#pragma unroll
  for (int ks = 0; ks < 8; ++ks) {
    int kc = ks * 32 + kblk;
    s8v a = *(const s8v*)(sA + arow * 256 + (kc ^ ((arow & 7) << 3)));
    s8v bb = *(const s8v*)(sB + brow * 256 + (kc ^ ((brow & 7) << 3)));
    acc = __builtin_amdgcn_mfma_f32_16x16x32_bf16(a, bb, acc, 0, 0, 0);
  }
  int row0 = bi * 32 + wr * 16 + (l >> 4) * 4;
  int col = bj * 32 + wc * 16 + (l & 15);
#pragma unroll
  for (int rg = 0; rg < 4; ++rg)
    med[(size_t)(row0 + rg) * 512 + col] = (acc[rg] + 1.0f) * 0.5f;
}

__global__ void k_rowsum(const float* __restrict__ med, const float* __restrict__ T0p,
                         float* __restrict__ dinv) {
  int r = blockIdx.x, l = threadIdx.x;
  float T0 = *T0p;
  float cnt = 0.f;
  for (int j = l; j < 512; j += 64) cnt += ((med[(size_t)r * 512 + j] >= T0) || (j == r)) ? 1.0f : 0.0f;
  for (int off = 32; off > 0; off >>= 1) cnt += __shfl_xor(cnt, off);
  if (l == 0) dinv[r] = rsqrtf(cnt);
}

// ===================== slim epilogue: sparse Aagg + folded 768->16 dot =====================
__global__ void __launch_bounds__(256) k_epilogue(
    const float* __restrict__ med, const float* __restrict__ T0p,
    const float* __restrict__ dinv, const float* __restrict__ hrs,
    const float* __restrict__ pool, const float* __restrict__ pooled,
    const float* __restrict__ Afold, const float* __restrict__ bias_out,
    float* __restrict__ out) {
  __shared__ float sMedRow[512];
  __shared__ float sIn[6][128];  // 0=hrs, 1=T1, 2=T2, 3..5=pooled_h
  __shared__ float sRed[16][16];
  __shared__ int sNbr[64];
  __shared__ float sDw[64];
  __shared__ int sNnz;
  int i = blockIdx.x, t = threadIdx.x;
  float T0 = *T0p;

  for (int j = t; j < 512; j += 256) sMedRow[j] = med[(size_t)i * 512 + j];
  if (t < 128) sIn[0][t] = hrs[i * 128 + t];
  for (int k = t; k < 384; k += 256) sIn[3 + (k >> 7)][k & 127] = pooled[(size_t)i * 384 + k];
  __syncthreads();

  // deterministic neighbor-list build: wave 0
  if (t < 64) {
    int cnt = 0, flags = 0;
#pragma unroll
    for (int k = 0; k < 8; ++k) {
      int j = t * 8 + k;
      if (sMedRow[j] >= T0 || j == i) {
        flags |= 1 << k;
        ++cnt;
      }
    }
    int off = cnt;
    for (int d = 1; d < 64; d <<= 1) {
      int v = __shfl_up(off, d);
      if (t >= d) off += v;
    }
    off -= cnt;
    int pos = off;
#pragma unroll
    for (int k = 0; k < 8; ++k)
      if (flags & (1 << k)) {
        int j = t * 8 + k;
        if (pos < 64) {
          sNbr[pos] = j;
          sDw[pos] = dinv[j];
        }
        ++pos;
      }
    if (t == 63) sNnz = off + cnt;
  }
  __syncthreads();

  // T1 = Aagg(hrs), T2 = Aagg(pool)
  {
    int half = t >> 7, c = t & 127;
    float di = dinv[i];
    const float* srcm = half ? pool : hrs;
    float acc = 0.f;
    int nnz = sNnz;
    if (nnz <= 64) {
      for (int n = 0; n < nnz; ++n) acc += sDw[n] * srcm[sNbr[n] * 128 + c];
    } else {
      for (int j = 0; j < 512; ++j)
        if (sMedRow[j] >= T0 || j == i) acc += dinv[j] * srcm[j * 128 + c];
    }
    sIn[1 + half][c] = acc * di;
  }
  __syncthreads();

  // out[o] = bias[o] + sum_m sum_c sIn[m][c] * Afold[m][c][o]
  {
    int o = t >> 4, chunk = t & 15;
    int c0 = chunk * 8;
    float acc = 0.f;
#pragma unroll
    for (int m = 0; m < 6; ++m) {
      const float* A = Afold + m * 2048;
      const float* xm = sIn[m];
#pragma unroll
      for (int k = 0; k < 8; ++k) acc += xm[c0 + k] * A[(c0 + k) * 16 + o];
    }
    sRed[o][chunk] = acc;
  }
  __syncthreads();
  if (t < 16) {
    float acc = bias_out[t];
#pragma unroll
    for (int j = 0; j < 16; ++j) acc += sRed[t][j];
    out[i * 16 + t] = acc;
  }
}

// ===================== host =====================
extern "C" void kernel_launch(void* const* d_in, const int* in_sizes, int n_in,
                              void* d_out, int out_size, void* d_ws, size_t ws_size,
                              hipStream_t stream) {
  const float* poi_x = (const float*)d_in[0];
  const float* img = (const float*)d_in[1];
  const int* edges = (const int*)d_in[2];
  const float* T0p = (const float*)d_in[4];
  const float* W1 = (const float*)d_in[5];
  const float* b1 = (const float*)d_in[6];
  const float* W2 = (const float*)d_in[7];
  const float* b2 = (const float*)d_in[8];
  const float* Whrs = (const float*)d_in[9];
  const float* bhrs = (const float*)d_in[10];
  const float* Wph = (const float*)d_in[11];
  const float* bph = (const float*)d_in[12];
  const float* Wpp = (const float*)d_in[13];
  const float* bpp = (const float*)d_in[14];
  const float* Wg_in = (const float*)d_in[15];
  const float* al_in = (const float*)d_in[16];
  const float* ar_in = (const float*)d_in[17];
  const float* bg_in = (const float*)d_in[18];
  const float* Wg_w = (const float*)d_in[19];
  const float* bg_w = (const float*)d_in[22];
  const float* Wh1 = (const float*)d_in[23];
  const float* bh1 = (const float*)d_in[24];
  const float* Wp1 = (const float*)d_in[25];
  const float* bp1 = (const float*)d_in[26];
  const float* Wfc = (const float*)d_in[27];
  const float* bfc = (const float*)d_in[28];

  const int* esrc = edges;
  const int* edst = edges + EE;

  char* ws = (char*)d_ws;
  size_t off = 0;
  auto alloc = [&](size_t nbytes) -> char* {
    char* p = ws + off;
    off += (nbytes + 255) & ~(size_t)255;
    return p;
  };
  uint8_t* Sg8 = (uint8_t*)alloc((size_t)NN * 128);  // 8.4 MB u8 count matrix
  u16* w1t = (u16*)alloc(8192 * 2);
  u16* w2t = (u16*)alloc(16384 * 2);
  float* hrs = (float*)alloc(512 * 128 * 4);
  float* er = (float*)alloc(512 * 3 * 4);
  float* wv = (float*)alloc(384 * 4);
  float* q = (float*)alloc(384 * 4);
  float* chv = (float*)alloc(16);
  float* Afold = (float*)alloc(6 * 2048 * 4);
  float* bias_out = (float*)alloc(16 * 4);
  float* pool = (float*)alloc(512 * 128 * 4);
  float* pooled = (float*)alloc((size_t)1536 * 128 * 4);
  u16* mfnb = (u16*)alloc(512 * 256 * 2);
  float* dinv = (float*)alloc(512 * 4);

  float* out = (float*)d_out;
  float* med = out + 512 * 16;

  hipMemsetAsync(Sg8, 0, (size_t)NN * 128, stream);

  size_t dynf = 152096;
  hipFuncSetAttribute((const void*)k_gcn_fused, hipFuncAttributeMaxDynamicSharedMemorySize,
                      (int)dynf);

  k_prepAll<<<97, 256, 0, stream>>>(W1, W2, Wg_in, al_in, ar_in, Wpp, bpp, w1t, w2t, wv, q,
                                    chv);
  k_fold<<<7, 256, 0, stream>>>(Wg_w, bg_w, bg_in, Wph, bph, Wh1, bh1, Wp1, bp1, Wpp, bpp,
                                Wg_in, Wfc, bfc, Afold, bias_out);
  k_scatterS<<<EE / 256, 256, 0, stream>>>(esrc, edst, (uint32_t*)Sg8);
  k_hrs<<<256, 512, 0, stream>>>(img, Whrs, bhrs, Wph, bph, wv, hrs, er);
  k_gcn_fused<<<512, 512, dynf, stream>>>(poi_x, b1, b2, Sg8, q, chv, er, hrs, w1t, w2t, pool,
                                          pooled, mfnb);
  k_med<<<256, 256, 0, stream>>>(mfnb, med);
  k_rowsum<<<512, 64, 0, stream>>>(med, T0p, dinv);
  k_epilogue<<<512, 256, 0, stream>>>(med, T0p, dinv, hrs, pool, pooled, Afold, bias_out, out);

  (void)in_sizes; (void)n_in; (void)out_size; (void)ws_size;
}

// Round 12
// 191.386 us; speedup vs baseline: 1.1032x; 1.1032x over previous
//
#include <hip/hip_runtime.h>
#include <stdint.h>

#define NN 65536
#define EE 524288
#define BB 512

typedef unsigned short u16;
typedef __attribute__((ext_vector_type(8))) short s8v;    // 8 bf16 (4 VGPRs)
typedef __attribute__((ext_vector_type(4))) float f32x4;  // MFMA acc

__device__ __forceinline__ u16 f2b(float f) {
  union { float f; uint32_t u; } a{f};
  uint32_t r = a.u + 0x7fff + ((a.u >> 16) & 1);
  return (u16)(r >> 16);
}
__device__ __forceinline__ float b2f(u16 v) {
  union { uint32_t u; float f; } a{(uint32_t)v << 16};
  return a.f;
}
__device__ __forceinline__ int swz128(int r, int c) { return r * 128 + (c ^ ((r & 7) << 3)); }
__device__ __forceinline__ int swz64(int r, int c) { return r * 64 + (c ^ ((r & 7) << 3)); }

// ===================== graph prep: dense per-parcel u8 count matrix =====================
__global__ void k_scatterS(const int* __restrict__ src, const int* __restrict__ dst,
                           uint32_t* __restrict__ Sg) {
  int e = blockIdx.x * 256 + threadIdx.x;
  if (e >= EE) return;
  int s = src[e] & 127, d = dst[e];
  atomicAdd(&Sg[((size_t)d * 128 + s) >> 2], 1u << ((s & 3) * 8));
}

// ===================== weight prep: transposes + GAT folding =====================
__global__ void k_prepAll(const float* __restrict__ W1, const float* __restrict__ W2,
                          const float* __restrict__ Wg_in, const float* __restrict__ al_in,
                          const float* __restrict__ ar_in, const float* __restrict__ Wpp,
                          const float* __restrict__ bpp, u16* __restrict__ w1t,
                          u16* __restrict__ w2t, float* __restrict__ wv,
                          float* __restrict__ q, float* __restrict__ ch) {
  int blk = blockIdx.x, t = threadIdx.x;
  if (blk < 96) {
    int i = blk * 256 + t;  // 24576
    if (i < 8192) {
      int n = i >> 6, k = i & 63;
      w1t[i] = f2b(W1[k * 128 + n]);
    } else {
      int j = i - 8192;
      int n = j >> 7, k = j & 127;
      w2t[j] = f2b(W2[k * 128 + n]);
    }
  } else {
    __shared__ float su[384];
    for (int i = t; i < 384; i += 256) {
      int h = i >> 7, k = i & 127;
      float s = 0.f, sw = 0.f;
#pragma unroll 4
      for (int c = 0; c < 128; ++c) {
        float g = Wg_in[k * 384 + h * 128 + c];
        s += g * al_in[h * 128 + c];
        sw += g * ar_in[h * 128 + c];
      }
      su[i] = s;
      wv[i] = sw;
    }
    __syncthreads();
    for (int i = t; i < 384; i += 256) {
      int h = i >> 7, j = i & 127;
      float s = 0.f;
#pragma unroll 4
      for (int k = 0; k < 128; ++k) s += Wpp[j * 128 + k] * su[h * 128 + k];
      q[i] = s;
    }
    if (t < 3) {
      float s = 0.f;
#pragma unroll 4
      for (int k = 0; k < 128; ++k) s += bpp[k] * su[t * 128 + k];
      ch[t] = s;
    }
  }
}

// ===================== fold stage 1: intermediates (parallel grid) =====================
// blocks 0..7: B0 = G @ Wfc_s0 ; blocks 8..31: C_h = Wg_in_h @ Wfc_s2 ; block 32: D0 + E
__global__ void __launch_bounds__(256) k_fold1(
    const float* __restrict__ Wg_w, const float* __restrict__ Wg_in,
    const float* __restrict__ Wfc, const float* __restrict__ bph,
    const float* __restrict__ bpp, const float* __restrict__ bg_in,
    float* __restrict__ B0, float* __restrict__ Ch, float* __restrict__ D0,
    float* __restrict__ Evec) {
  int blk = blockIdx.x, t = threadIdx.x;
  if (blk < 8) {
    __shared__ float sW[2048];
    for (int i = t; i < 2048; i += 256) sW[i] = Wfc[i];  // Wfc rows 0..127
    __syncthreads();
    int m = blk * 16 + (t >> 4), o = t & 15;
    const float* wr = Wg_w + (size_t)m * 384;
    float acc = 0.f;
#pragma unroll 4
    for (int j = 0; j < 128; ++j) {
      float g = (wr[j] + wr[128 + j] + wr[256 + j]) * (1.0f / 3.0f);
      acc += g * sW[j * 16 + o];
    }
    B0[m * 16 + o] = acc;
  } else if (blk < 32) {
    int h = (blk - 8) >> 3, rc = (blk - 8) & 7;
    __shared__ float sW[2048];
    for (int i = t; i < 2048; i += 256) sW[i] = Wfc[256 * 16 + i];  // rows 256..383
    __syncthreads();
    int m = rc * 16 + (t >> 4), o = t & 15;
    const float* wr = Wg_in + (size_t)m * 384 + h * 128;
    float acc = 0.f;
#pragma unroll 4
    for (int c = 0; c < 128; ++c) acc += wr[c] * sW[c * 16 + o];
    Ch[((size_t)h * 128 + m) * 16 + o] = acc;
  } else {
    if (t < 128) {
      float acc = 0.f;
#pragma unroll 4
      for (int k = 0; k < 128; ++k) {
        float g = (Wg_w[k * 384 + t] + Wg_w[k * 384 + 128 + t] + Wg_w[k * 384 + 256 + t]) *
                  (1.0f / 3.0f);
        acc += bph[k] * g;
      }
      D0[t] = acc;
    } else {
      int j = t - 128;
      float e = 0.f;
      for (int h = 0; h < 3; ++h) {
#pragma unroll 4
        for (int m = 0; m < 128; ++m) e += bpp[m] * Wg_in[m * 384 + h * 128 + j];
      }
      float g0in = (bg_in[j] + bg_in[128 + j] + bg_in[256 + j]) * (1.0f / 3.0f);
      Evec[j] = e * (1.0f / 3.0f) + g0in;
    }
  }
}

// ===================== fold stage 2: Afold[6][128][16] + bias_out[16] =====================
// blocks 0..47: mat = blk>>3 (0=A_hrs,1=A_T1,2=A_T2,3..5=A_pld_h), rc = blk&7 ; block 48: bias
__global__ void __launch_bounds__(256) k_fold2(
    const float* __restrict__ Wph, const float* __restrict__ Wh1,
    const float* __restrict__ Wp1, const float* __restrict__ Wpp,
    const float* __restrict__ Wfc, const float* __restrict__ bfc,
    const float* __restrict__ bh1, const float* __restrict__ bp1,
    const float* __restrict__ bg_w, const float* __restrict__ B0,
    const float* __restrict__ Ch, const float* __restrict__ D0,
    const float* __restrict__ Evec, float* __restrict__ Afold,
    float* __restrict__ bias_out) {
  int blk = blockIdx.x, t = threadIdx.x;
  if (blk < 48) {
    int mat = blk >> 3, rc = blk & 7;
    __shared__ float sW[2048];
    if (mat == 0)
      for (int i = t; i < 2048; i += 256) sW[i] = B0[i];
    else if (mat == 1)
      for (int i = t; i < 2048; i += 256) sW[i] = Wfc[384 * 16 + i];
    else if (mat == 2)
      for (int i = t; i < 2048; i += 256) sW[i] = Wfc[128 * 16 + i];
    else
      for (int i = t; i < 2048; i += 256) sW[i] = Ch[(size_t)(mat - 3) * 2048 + i];
    __syncthreads();
    int k = rc * 16 + (t >> 4), o = t & 15;
    const float* L = (mat == 0) ? Wph : (mat == 1) ? Wh1 : (mat == 2) ? Wp1 : Wpp;
    float scale = (mat >= 3) ? (1.0f / 3.0f) : 1.0f;
    const float* lr = L + (size_t)k * 128;
    float acc = 0.f;
#pragma unroll 4
    for (int m = 0; m < 128; ++m) acc += lr[m] * sW[m * 16 + o];
    Afold[(size_t)mat * 2048 + k * 16 + o] = acc * scale;
  } else {
    if (t < 16) {
      float acc = bfc[t];
      for (int j = 0; j < 128; ++j) {
        float g0w = (bg_w[j] + bg_w[128 + j] + bg_w[256 + j]) * (1.0f / 3.0f);
        acc += (D0[j] + g0w) * Wfc[j * 16 + t];
        acc += bp1[j] * Wfc[(128 + j) * 16 + t];
        acc += Evec[j] * Wfc[(256 + j) * 16 + t];
        acc += bh1[j] * Wfc[(384 + j) * 16 + t];
      }
      bias_out[t] = acc;
    }
  }
}

// ===================== hrs encoder + er (fused) =====================
__global__ void __launch_bounds__(512) k_hrs(const float* __restrict__ img,
                                             const float* __restrict__ Whrs,
                                             const float* __restrict__ bhrs,
                                             const float* __restrict__ Wph,
                                             const float* __restrict__ bph,
                                             const float* __restrict__ wv,
                                             float* __restrict__ hrs, float* __restrict__ er) {
  __shared__ float sI[4096];
  __shared__ float sRed[4][128];
  __shared__ float sHrs[2][128];
  __shared__ float sPh[2][128];
  int r0 = blockIdx.x * 2;
  int t = threadIdx.x;
  const float4* gsrc = (const float4*)(img + (size_t)r0 * 2048);
  float4* ldst = (float4*)sI;
  for (int i = t; i < 1024; i += 512) ldst[i] = gsrc[i];
  __syncthreads();
  int c = t & 127, g = t >> 7;
  int row = g & 1, ks = g >> 1;
  const float* s = sI + row * 2048 + ks * 1024;
  const float* W = Whrs + (size_t)(ks * 1024) * 128 + c;
  float a0 = 0.f, a1 = 0.f, a2 = 0.f, a3 = 0.f;
  for (int k = 0; k < 1024; k += 4) {
    a0 += s[k] * W[(size_t)k * 128];
    a1 += s[k + 1] * W[(size_t)(k + 1) * 128];
    a2 += s[k + 2] * W[(size_t)(k + 2) * 128];
    a3 += s[k + 3] * W[(size_t)(k + 3) * 128];
  }
  sRed[g][c] = (a0 + a1) + (a2 + a3);
  __syncthreads();
  if (t < 256) {
    int rr = t >> 7, cc = t & 127;
    float v = sRed[rr][cc] + sRed[rr + 2][cc] + bhrs[cc];
    hrs[(r0 + rr) * 128 + cc] = v;
    sHrs[rr][cc] = v;
  }
  __syncthreads();
  if (t < 256) {
    int rr = t >> 7, cc = t & 127;
    float acc = bph[cc];
#pragma unroll 4
    for (int k = 0; k < 128; ++k) acc += sHrs[rr][k] * Wph[k * 128 + cc];
    sPh[rr][cc] = acc;
  }
  __syncthreads();
  if (t < 6) {
    int rr = t / 3, h = t % 3;
    float s2 = 0.f;
#pragma unroll 4
    for (int k = 0; k < 128; ++k) s2 += sPh[rr][k] * wv[h * 128 + k];
    er[(r0 + rr) * 3 + h] = s2;
  }
}

// ===================== FUSED GCN via dense S' + MFMA =====================
__global__ void __launch_bounds__(512) k_gcn_fused(
    const float* __restrict__ x, const float* __restrict__ b1, const float* __restrict__ b2,
    const uint8_t* __restrict__ Sg8, const float* __restrict__ q, const float* __restrict__ ch,
    const float* __restrict__ er, const float* __restrict__ hrs,
    const u16* __restrict__ w1t, const u16* __restrict__ w2t, float* __restrict__ poi_pool,
    float* __restrict__ pooled, u16* __restrict__ mfnb) {
  extern __shared__ char sm[];
  u16* sS = (u16*)sm;
  u16* sB2 = (u16*)(sm + 32768);
  u16* sPt = (u16*)(sm + 32768);
  u16* sXt = (u16*)(sm + 65536);
  u16* sAgg1 = (u16*)(sm + 81920);
  u16* sW1t = (u16*)(sm + 98304);
  float* sXrm = (float*)(sm + 114688);
  u16* sW2t = (u16*)(sm + 114688);
  u16* sAgg2 = (u16*)(sm + 65536);
  u16* sP = (u16*)sm;
  float* sNorm = (float*)(sm + 147968);
  float* sQ = (float*)(sm + 148480);
  float* sAl = (float*)(sm + 150016);
  float* sPool = (float*)(sm + 151552);
  float* sEr = (float*)(sm + 152064);
  float* sCh = (float*)(sm + 152080);

  int b = blockIdx.x, t = threadIdx.x;
  int base = b << 7;
  int l = t & 63, w = t >> 6;
  const uint8_t* Sgb = Sg8 + (size_t)base * 128;

  // ---- phase 0: norms from u8 row-sums; stage Xrm, W1t, q/er/ch ----
  if (t < 128) {
    const uint4* rp = (const uint4*)(Sgb + (size_t)t * 128);
    uint32_t s = 0;
#pragma unroll
    for (int k = 0; k < 8; ++k) {
      uint4 v = rp[k];
      uint32_t ws[4] = {v.x, v.y, v.z, v.w};
#pragma unroll
      for (int p = 0; p < 4; ++p)
        s += (ws[p] & 0xff) + ((ws[p] >> 8) & 0xff) + ((ws[p] >> 16) & 0xff) + (ws[p] >> 24);
    }
    sNorm[t] = rsqrtf((float)s + 1.0f);
  }
  for (int i = t; i < 8192; i += 512) {
    int s = i >> 6, f = i & 63;
    sXrm[s * 65 + f] = x[(size_t)(base + s) * 64 + f];
  }
  for (int g = t; g < 1024; g += 512) {
    int n = g >> 3, blk = g & 7;
    *(uint4*)(sW1t + n * 64 + ((blk ^ (n & 7)) << 3)) = ((const uint4*)w1t)[g];
  }
  for (int i = t; i < 384; i += 512) sQ[i] = q[i];
  if (t < 3) {
    sEr[t] = er[b * 3 + t];
    sCh[t] = ch[t];
  }
  __syncthreads();

  // ---- phase 1: S' from u8 counts + X transpose->bf16 ----
  {
    int r = t >> 2, sb = (t & 3) * 32;
    const uint4* cp = (const uint4*)(Sgb + r * 128 + sb);
    uint4 c0 = cp[0], c1 = cp[1];
    float nr = sNorm[r];
    int sw = (r & 7) << 3;
    uint32_t words[8] = {c0.x, c0.y, c0.z, c0.w, c1.x, c1.y, c1.z, c1.w};
#pragma unroll
    for (int qd = 0; qd < 8; ++qd) {
      uint32_t wd = words[qd];
#pragma unroll
      for (int p = 0; p < 4; p += 2) {
        int s0 = sb + qd * 4 + p;
        float v0 = ((float)((wd >> (p * 8)) & 0xff) + (r == s0 ? 1.f : 0.f)) * nr * sNorm[s0];
        float v1 =
            ((float)((wd >> (p * 8 + 8)) & 0xff) + (r == s0 + 1 ? 1.f : 0.f)) * nr * sNorm[s0 + 1];
        uint32_t pk = (uint32_t)f2b(v0) | ((uint32_t)f2b(v1) << 16);
        *(uint32_t*)(sS + r * 128 + (s0 ^ sw)) = pk;
      }
    }
  }
  for (int i = t; i < 4096; i += 512) {
    int f = i >> 6, s = (i & 63) * 2;
    float v0 = sXrm[s * 65 + f] * sNorm[s];
    float v1 = sXrm[(s + 1) * 65 + f] * sNorm[s + 1];
    uint32_t pk = (uint32_t)f2b(v0) | ((uint32_t)f2b(v1) << 16);
    *(uint32_t*)(sXt + (f * 128 + (s ^ ((f & 7) << 3)))) = pk;
  }
  __syncthreads();

  int mrow = w * 16 + (l & 15);
  int kblk = (l >> 4) * 8;
  int rbase = w * 16 + (l >> 4) * 4;

  // ---- phase 3: agg1 = S' @ X (A hoisted); stage W2t ----
  {
    s8v a4[4];
#pragma unroll
    for (int ks = 0; ks < 4; ++ks) a4[ks] = *(const s8v*)(sS + swz128(mrow, ks * 32 + kblk));
    for (int nt = 0; nt < 4; ++nt) {
      f32x4 acc = {0.f, 0.f, 0.f, 0.f};
      int cg = nt * 16 + (l & 15);
#pragma unroll
      for (int ks = 0; ks < 4; ++ks)
        acc = __builtin_amdgcn_mfma_f32_16x16x32_bf16(
            a4[ks], *(const s8v*)(sXt + swz128(cg, ks * 32 + kblk)), acc, 0, 0, 0);
#pragma unroll
      for (int rg = 0; rg < 4; ++rg) sAgg1[swz64(rbase + rg, cg)] = f2b(acc[rg]);
    }
  }
  for (int g = t; g < 2048; g += 512) {
    int n = g >> 4, blk = g & 15;
    *(uint4*)(sW2t + n * 128 + ((blk ^ (n & 7)) << 3)) = ((const uint4*)w2t)[g];
  }
  __syncthreads();

  // ---- phase 4: h1 = relu(agg1 @ W1 + b1) -> h1^T ----
  {
    s8v a2[2];
#pragma unroll
    for (int ks = 0; ks < 2; ++ks) a2[ks] = *(const s8v*)(sAgg1 + swz64(mrow, ks * 32 + kblk));
    for (int nt = 0; nt < 8; ++nt) {
      int cg = nt * 16 + (l & 15);
      float bv = b1[cg];
      f32x4 acc = {bv, bv, bv, bv};
#pragma unroll
      for (int ks = 0; ks < 2; ++ks)
        acc = __builtin_amdgcn_mfma_f32_16x16x32_bf16(
            a2[ks], *(const s8v*)(sW1t + swz64(cg, ks * 32 + kblk)), acc, 0, 0, 0);
      u16 h0 = f2b(fmaxf(acc[0], 0.f)), h1v = f2b(fmaxf(acc[1], 0.f));
      u16 h2 = f2b(fmaxf(acc[2], 0.f)), h3 = f2b(fmaxf(acc[3], 0.f));
      uint2 pk;
      pk.x = (uint32_t)h0 | ((uint32_t)h1v << 16);
      pk.y = (uint32_t)h2 | ((uint32_t)h3 << 16);
      *(uint2*)(sB2 + swz128(cg, rbase)) = pk;
    }
  }
  __syncthreads();

  // ---- phase 5: agg2 = S' @ h1 ----
  {
    s8v a4[4];
#pragma unroll
    for (int ks = 0; ks < 4; ++ks) a4[ks] = *(const s8v*)(sS + swz128(mrow, ks * 32 + kblk));
    for (int nt = 0; nt < 8; ++nt) {
      f32x4 acc = {0.f, 0.f, 0.f, 0.f};
      int cg = nt * 16 + (l & 15);
#pragma unroll
      for (int ks = 0; ks < 4; ++ks)
        acc = __builtin_amdgcn_mfma_f32_16x16x32_bf16(
            a4[ks], *(const s8v*)(sB2 + swz128(cg, ks * 32 + kblk)), acc, 0, 0, 0);
#pragma unroll
      for (int rg = 0; rg < 4; ++rg) sAgg2[swz128(rbase + rg, cg)] = f2b(acc[rg]);
    }
  }
  __syncthreads();

  // ---- phase 6: poi = agg2 @ W2 + b2 -> sP + sPt ----
  {
    s8v a4[4];
#pragma unroll
    for (int ks = 0; ks < 4; ++ks) a4[ks] = *(const s8v*)(sAgg2 + swz128(mrow, ks * 32 + kblk));
    for (int nt = 0; nt < 8; ++nt) {
      int cg = nt * 16 + (l & 15);
      float bv = b2[cg];
      f32x4 acc = {bv, bv, bv, bv};
#pragma unroll
      for (int ks = 0; ks < 4; ++ks)
        acc = __builtin_amdgcn_mfma_f32_16x16x32_bf16(
            a4[ks], *(const s8v*)(sW2t + swz128(cg, ks * 32 + kblk)), acc, 0, 0, 0);
      u16 p0 = f2b(acc[0]), p1 = f2b(acc[1]), p2 = f2b(acc[2]), p3 = f2b(acc[3]);
#pragma unroll
      for (int rg = 0; rg < 4; ++rg)
        sP[swz128(rbase + rg, cg)] = (rg == 0) ? p0 : (rg == 1) ? p1 : (rg == 2) ? p2 : p3;
      uint2 pk;
      pk.x = (uint32_t)p0 | ((uint32_t)p1 << 16);
      pk.y = (uint32_t)p2 | ((uint32_t)p3 << 16);
      *(uint2*)(sPt + swz128(cg, rbase)) = pk;
    }
  }
  __syncthreads();

  // ---- tail: pool from Pt rows ----
  if (t < 128) {
    int c = t;
    float s = 0.f;
    const u16* rowp = sPt + c * 128;
    int sw = (c & 7) << 3;
#pragma unroll
    for (int k8 = 0; k8 < 16; ++k8) {
      s8v v = *(const s8v*)(rowp + ((k8 * 8) ^ sw));
#pragma unroll
      for (int j = 0; j < 8; ++j) s += b2f((u16)v[j]);
    }
    sPool[c] = s;
    poi_pool[b * 128 + c] = s * (1.0f / 128.0f);
  }
  if (t < 384) {
    int r = t & 127, h = t >> 7;
    int sw = (r & 7) << 3;
    const u16* rowp = sP + r * 128;
    const float* qh = &sQ[h * 128];
    float d = 0.f;
#pragma unroll
    for (int k8 = 0; k8 < 16; ++k8) {
      int c8 = (k8 * 8) ^ sw;
      s8v v = *(const s8v*)(rowp + c8);
#pragma unroll
      for (int j = 0; j < 8; ++j) d += b2f((u16)v[j]) * qh[c8 + j];
    }
    float e = d + sCh[h] + sEr[h];
    sAl[h * 128 + r] = (e > 0.f) ? e : 0.2f * e;
  }
  __syncthreads();

  if (t < 192) {
    int h = t >> 6, ll = t & 63;
    float v0 = sAl[h * 128 + ll], v1 = sAl[h * 128 + 64 + ll];
    float m = fmaxf(v0, v1);
    for (int off = 32; off > 0; off >>= 1) m = fmaxf(m, __shfl_xor(m, off));
    float x0 = __expf(v0 - m), x1 = __expf(v1 - m);
    float s = x0 + x1;
    for (int off = 32; off > 0; off >>= 1) s += __shfl_xor(s, off);
    float inv = 1.0f / s;
    sAl[h * 128 + ll] = x0 * inv;
    sAl[h * 128 + 64 + ll] = x1 * inv;
  }
  __syncthreads();

  if (t < 384) {
    int hh = t >> 7, c = t & 127;
    int sw = (c & 7) << 3;
    const u16* rowp = sPt + c * 128;
    const float* al = &sAl[hh * 128];
    float s = 0.f;
#pragma unroll
    for (int k8 = 0; k8 < 16; ++k8) {
      int r8 = (k8 * 8) ^ sw;
      s8v v = *(const s8v*)(rowp + r8);
#pragma unroll
      for (int j = 0; j < 8; ++j) s += b2f((u16)v[j]) * al[r8 + j];
    }
    pooled[((size_t)b * 3 + hh) * 128 + c] = s;
  }
  __syncthreads();

  // ---- fused mfn (bf16 out) ----
  float hv = 0.f, pv = 0.f;
  if (t < 128) {
    hv = hrs[base + t];
    pv = sPool[t] * (1.0f / 128.0f);
    sQ[t] = hv * hv + pv * pv;
  }
  __syncthreads();
  if (t < 64) {
    float v = sQ[t] + sQ[t + 64];
    for (int off = 32; off > 0; off >>= 1) v += __shfl_xor(v, off);
    if (t == 0) sQ[0] = rsqrtf(v);
  }
  __syncthreads();
  if (t < 128) {
    float rn = sQ[0];
    mfnb[b * 256 + t] = f2b(hv * rn);
    mfnb[b * 256 + 128 + t] = f2b(pv * rn);
  }
}

// ===================== med via MFMA: med = (mfn @ mfn^T + 1)/2 =====================
__global__ void __launch_bounds__(256) k_med(const u16* __restrict__ mfnb,
                                             float* __restrict__ med) {
  __shared__ u16 sA[32 * 256];
  __shared__ u16 sB[32 * 256];
  int bi = blockIdx.x >> 4, bj = blockIdx.x & 15;
  int t = threadIdx.x;
  const uint4* srcA = (const uint4*)(mfnb + (size_t)bi * 32 * 256);
  const uint4* srcB = (const uint4*)(mfnb + (size_t)bj * 32 * 256);
  for (int g = t; g < 1024; g += 256) {
    int r = g >> 5, blk = g & 31;
    int db = (blk & 24) | ((blk ^ (r & 7)) & 7);
    uint4 va = srcA[g];
    uint4 vb = srcB[g];
    *(uint4*)(sA + r * 256 + db * 8) = va;
    *(uint4*)(sB + r * 256 + db * 8) = vb;
  }
  __syncthreads();
  int l = t & 63, w = t >> 6;
  int wr = w >> 1, wc = w & 1;
  int arow = wr * 16 + (l & 15);
  int brow = wc * 16 + (l & 15);
  int kblk = (l >> 4) * 8;
  f32x4 acc = {0.f, 0.f, 0.f, 0.f};
#pragma unroll
  for (int ks = 0; ks < 8; ++ks) {
    int kc = ks * 32 + kblk;
    s8v a = *(const s8v*)(sA + arow * 256 + (kc ^ ((arow & 7) << 3)));
    s8v bb = *(const s8v*)(sB + brow * 256 + (kc ^ ((brow & 7) << 3)));
    acc = __builtin_amdgcn_mfma_f32_16x16x32_bf16(a, bb, acc, 0, 0, 0);
  }
  int row0 = bi * 32 + wr * 16 + (l >> 4) * 4;
  int col = bj * 32 + wc * 16 + (l & 15);
#pragma unroll
  for (int rg = 0; rg < 4; ++rg)
    med[(size_t)(row0 + rg) * 512 + col] = (acc[rg] + 1.0f) * 0.5f;
}

__global__ void k_rowsum(const float* __restrict__ med, const float* __restrict__ T0p,
                         float* __restrict__ dinv) {
  int r = blockIdx.x, l = threadIdx.x;
  float T0 = *T0p;
  float cnt = 0.f;
  for (int j = l; j < 512; j += 64) cnt += ((med[(size_t)r * 512 + j] >= T0) || (j == r)) ? 1.0f : 0.0f;
  for (int off = 32; off > 0; off >>= 1) cnt += __shfl_xor(cnt, off);
  if (l == 0) dinv[r] = rsqrtf(cnt);
}

// ===================== slim epilogue: sparse Aagg + folded 768->16 dot =====================
__global__ void __launch_bounds__(256) k_epilogue(
    const float* __restrict__ med, const float* __restrict__ T0p,
    const float* __restrict__ dinv, const float* __restrict__ hrs,
    const float* __restrict__ pool, const float* __restrict__ pooled,
    const float* __restrict__ Afold, const float* __restrict__ bias_out,
    float* __restrict__ out) {
  __shared__ float sMedRow[512];
  __shared__ float sIn[6][128];  // 0=hrs, 1=T1, 2=T2, 3..5=pooled_h
  __shared__ float sRed[16][16];
  __shared__ int sNbr[64];
  __shared__ float sDw[64];
  __shared__ int sNnz;
  int i = blockIdx.x, t = threadIdx.x;
  float T0 = *T0p;

  for (int j = t; j < 512; j += 256) sMedRow[j] = med[(size_t)i * 512 + j];
  if (t < 128) sIn[0][t] = hrs[i * 128 + t];
  for (int k = t; k < 384; k += 256) sIn[3 + (k >> 7)][k & 127] = pooled[(size_t)i * 384 + k];
  __syncthreads();

  // deterministic neighbor-list build: wave 0
  if (t < 64) {
    int cnt = 0, flags = 0;
#pragma unroll
    for (int k = 0; k < 8; ++k) {
      int j = t * 8 + k;
      if (sMedRow[j] >= T0 || j == i) {
        flags |= 1 << k;
        ++cnt;
      }
    }
    int off = cnt;
    for (int d = 1; d < 64; d <<= 1) {
      int v = __shfl_up(off, d);
      if (t >= d) off += v;
    }
    off -= cnt;
    int pos = off;
#pragma unroll
    for (int k = 0; k < 8; ++k)
      if (flags & (1 << k)) {
        int j = t * 8 + k;
        if (pos < 64) {
          sNbr[pos] = j;
          sDw[pos] = dinv[j];
        }
        ++pos;
      }
    if (t == 63) sNnz = off + cnt;
  }
  __syncthreads();

  // T1 = Aagg(hrs), T2 = Aagg(pool)
  {
    int half = t >> 7, c = t & 127;
    float di = dinv[i];
    const float* srcm = half ? pool : hrs;
    float acc = 0.f;
    int nnz = sNnz;
    if (nnz <= 64) {
      for (int n = 0; n < nnz; ++n) acc += sDw[n] * srcm[sNbr[n] * 128 + c];
    } else {
      for (int j = 0; j < 512; ++j)
        if (sMedRow[j] >= T0 || j == i) acc += dinv[j] * srcm[j * 128 + c];
    }
    sIn[1 + half][c] = acc * di;
  }
  __syncthreads();

  // out[o] = bias[o] + sum_m sum_c sIn[m][c] * Afold[m][c][o]
  {
    int o = t >> 4, chunk = t & 15;
    int c0 = chunk * 8;
    float acc = 0.f;
#pragma unroll
    for (int m = 0; m < 6; ++m) {
      const float* A = Afold + m * 2048;
      const float* xm = sIn[m];
#pragma unroll
      for (int k = 0; k < 8; ++k) acc += xm[c0 + k] * A[(c0 + k) * 16 + o];
    }
    sRed[o][chunk] = acc;
  }
  __syncthreads();
  if (t < 16) {
    float acc = bias_out[t];
#pragma unroll
    for (int j = 0; j < 16; ++j) acc += sRed[t][j];
    out[i * 16 + t] = acc;
  }
}

// ===================== host =====================
extern "C" void kernel_launch(void* const* d_in, const int* in_sizes, int n_in,
                              void* d_out, int out_size, void* d_ws, size_t ws_size,
                              hipStream_t stream) {
  const float* poi_x = (const float*)d_in[0];
  const float* img = (const float*)d_in[1];
  const int* edges = (const int*)d_in[2];
  const float* T0p = (const float*)d_in[4];
  const float* W1 = (const float*)d_in[5];
  const float* b1 = (const float*)d_in[6];
  const float* W2 = (const float*)d_in[7];
  const float* b2 = (const float*)d_in[8];
  const float* Whrs = (const float*)d_in[9];
  const float* bhrs = (const float*)d_in[10];
  const float* Wph = (const float*)d_in[11];
  const float* bph = (const float*)d_in[12];
  const float* Wpp = (const float*)d_in[13];
  const float* bpp = (const float*)d_in[14];
  const float* Wg_in = (const float*)d_in[15];
  const float* al_in = (const float*)d_in[16];
  const float* ar_in = (const float*)d_in[17];
  const float* bg_in = (const float*)d_in[18];
  const float* Wg_w = (const float*)d_in[19];
  const float* bg_w = (const float*)d_in[22];
  const float* Wh1 = (const float*)d_in[23];
  const float* bh1 = (const float*)d_in[24];
  const float* Wp1 = (const float*)d_in[25];
  const float* bp1 = (const float*)d_in[26];
  const float* Wfc = (const float*)d_in[27];
  const float* bfc = (const float*)d_in[28];

  const int* esrc = edges;
  const int* edst = edges + EE;

  char* ws = (char*)d_ws;
  size_t off = 0;
  auto alloc = [&](size_t nbytes) -> char* {
    char* p = ws + off;
    off += (nbytes + 255) & ~(size_t)255;
    return p;
  };
  uint8_t* Sg8 = (uint8_t*)alloc((size_t)NN * 128);  // 8.4 MB u8 count matrix
  u16* w1t = (u16*)alloc(8192 * 2);
  u16* w2t = (u16*)alloc(16384 * 2);
  float* hrs = (float*)alloc(512 * 128 * 4);
  float* er = (float*)alloc(512 * 3 * 4);
  float* wv = (float*)alloc(384 * 4);
  float* q = (float*)alloc(384 * 4);
  float* chv = (float*)alloc(16);
  float* B0 = (float*)alloc(2048 * 4);
  float* Chb = (float*)alloc(3 * 2048 * 4);
  float* D0 = (float*)alloc(128 * 4);
  float* Evec = (float*)alloc(128 * 4);
  float* Afold = (float*)alloc(6 * 2048 * 4);
  float* bias_out = (float*)alloc(16 * 4);
  float* pool = (float*)alloc(512 * 128 * 4);
  float* pooled = (float*)alloc((size_t)1536 * 128 * 4);
  u16* mfnb = (u16*)alloc(512 * 256 * 2);
  float* dinv = (float*)alloc(512 * 4);

  float* out = (float*)d_out;
  float* med = out + 512 * 16;

  hipMemsetAsync(Sg8, 0, (size_t)NN * 128, stream);

  size_t dynf = 152096;
  hipFuncSetAttribute((const void*)k_gcn_fused, hipFuncAttributeMaxDynamicSharedMemorySize,
                      (int)dynf);

  k_prepAll<<<97, 256, 0, stream>>>(W1, W2, Wg_in, al_in, ar_in, Wpp, bpp, w1t, w2t, wv, q,
                                    chv);
  k_fold1<<<33, 256, 0, stream>>>(Wg_w, Wg_in, Wfc, bph, bpp, bg_in, B0, Chb, D0, Evec);
  k_fold2<<<49, 256, 0, stream>>>(Wph, Wh1, Wp1, Wpp, Wfc, bfc, bh1, bp1, bg_w, B0, Chb, D0,
                                  Evec, Afold, bias_out);
  k_scatterS<<<EE / 256, 256, 0, stream>>>(esrc, edst, (uint32_t*)Sg8);
  k_hrs<<<256, 512, 0, stream>>>(img, Whrs, bhrs, Wph, bph, wv, hrs, er);
  k_gcn_fused<<<512, 512, dynf, stream>>>(poi_x, b1, b2, Sg8, q, chv, er, hrs, w1t, w2t, pool,
                                          pooled, mfnb);
  k_med<<<256, 256, 0, stream>>>(mfnb, med);
  k_rowsum<<<512, 64, 0, stream>>>(med, T0p, dinv);
  k_epilogue<<<512, 256, 0, stream>>>(med, T0p, dinv, hrs, pool, pooled, Afold, bias_out, out);

  (void)in_sizes; (void)n_in; (void)out_size; (void)ws_size;
}

// Round 13
// 145.531 us; speedup vs baseline: 1.4508x; 1.3151x over previous
//
#include <hip/hip_runtime.h>
#include <stdint.h>

#define NN 65536
#define EE 524288
#define BB 512

typedef unsigned short u16;
typedef __attribute__((ext_vector_type(8))) short s8v;    // 8 bf16 (4 VGPRs)
typedef __attribute__((ext_vector_type(4))) float f32x4;  // MFMA acc

__device__ __forceinline__ u16 f2b(float f) {
  union { float f; uint32_t u; } a{f};
  uint32_t r = a.u + 0x7fff + ((a.u >> 16) & 1);
  return (u16)(r >> 16);
}
__device__ __forceinline__ float b2f(u16 v) {
  union { uint32_t u; float f; } a{(uint32_t)v << 16};
  return a.f;
}
__device__ __forceinline__ int swz128(int r, int c) { return r * 128 + (c ^ ((r & 7) << 3)); }
__device__ __forceinline__ int swz64(int r, int c) { return r * 64 + (c ^ ((r & 7) << 3)); }

// ===================== merged: scatterS (2048) + prepAll (97) + fold1 (34) =====================
__global__ void __launch_bounds__(256) k_prep_graph(
    const int* __restrict__ src, const int* __restrict__ dst, uint32_t* __restrict__ Sg,
    const float* __restrict__ W1, const float* __restrict__ W2,
    const float* __restrict__ Wg_in, const float* __restrict__ al_in,
    const float* __restrict__ ar_in, const float* __restrict__ Wpp,
    const float* __restrict__ bpp, u16* __restrict__ w1t, u16* __restrict__ w2t,
    float* __restrict__ wv, float* __restrict__ q, float* __restrict__ ch,
    const float* __restrict__ Wg_w, const float* __restrict__ Wfc,
    const float* __restrict__ bph, const float* __restrict__ bg_in,
    float* __restrict__ B0, float* __restrict__ Ch, float* __restrict__ D0,
    float* __restrict__ Evec) {
  int blk = blockIdx.x, t = threadIdx.x;
  if (blk < 2048) {
    // scatterS
    int e = blk * 256 + t;
    int s = src[e] & 127, d = dst[e];
    atomicAdd(&Sg[((size_t)d * 128 + s) >> 2], 1u << ((s & 3) * 8));
  } else if (blk < 2144) {
    // W1/W2 transpose -> bf16
    int i = (blk - 2048) * 256 + t;  // 24576
    if (i < 8192) {
      int n = i >> 6, k = i & 63;
      w1t[i] = f2b(W1[k * 128 + n]);
    } else {
      int j = i - 8192;
      int n = j >> 7, k = j & 127;
      w2t[j] = f2b(W2[k * 128 + n]);
    }
  } else if (blk == 2144) {
    // wv / q / ch
    __shared__ float su[384];
    for (int i = t; i < 384; i += 256) {
      int h = i >> 7, k = i & 127;
      float s = 0.f, sw = 0.f;
#pragma unroll 4
      for (int c = 0; c < 128; ++c) {
        float g = Wg_in[k * 384 + h * 128 + c];
        s += g * al_in[h * 128 + c];
        sw += g * ar_in[h * 128 + c];
      }
      su[i] = s;
      wv[i] = sw;
    }
    __syncthreads();
    for (int i = t; i < 384; i += 256) {
      int h = i >> 7, j = i & 127;
      float s = 0.f;
#pragma unroll 4
      for (int k = 0; k < 128; ++k) s += Wpp[j * 128 + k] * su[h * 128 + k];
      q[i] = s;
    }
    if (t < 3) {
      float s = 0.f;
#pragma unroll 4
      for (int k = 0; k < 128; ++k) s += bpp[k] * su[t * 128 + k];
      ch[t] = s;
    }
  } else if (blk < 2153) {
    // fold1: B0 = G @ Wfc_s0  (8 blocks)
    int bb = blk - 2145;
    __shared__ float sW[2048];
    for (int i = t; i < 2048; i += 256) sW[i] = Wfc[i];
    __syncthreads();
    int m = bb * 16 + (t >> 4), o = t & 15;
    const float* wr = Wg_w + (size_t)m * 384;
    float acc = 0.f;
#pragma unroll 4
    for (int j = 0; j < 128; ++j) {
      float g = (wr[j] + wr[128 + j] + wr[256 + j]) * (1.0f / 3.0f);
      acc += g * sW[j * 16 + o];
    }
    B0[m * 16 + o] = acc;
  } else if (blk < 2177) {
    // fold1: C_h = Wg_in_h @ Wfc_s2  (24 blocks)
    int bb = blk - 2153;
    int h = bb >> 3, rc = bb & 7;
    __shared__ float sW[2048];
    for (int i = t; i < 2048; i += 256) sW[i] = Wfc[256 * 16 + i];
    __syncthreads();
    int m = rc * 16 + (t >> 4), o = t & 15;
    const float* wr = Wg_in + (size_t)m * 384 + h * 128;
    float acc = 0.f;
#pragma unroll 4
    for (int c = 0; c < 128; ++c) acc += wr[c] * sW[c * 16 + o];
    Ch[((size_t)h * 128 + m) * 16 + o] = acc;
  } else if (blk == 2177) {
    // fold1: D0[j] = bph . G[:,j], k-split 2-way across 256 threads
    __shared__ float sD[2][128];
    int j = t & 127, half = t >> 7;
    int k0 = half * 64;
    float acc = 0.f;
#pragma unroll 4
    for (int k = k0; k < k0 + 64; ++k) {
      float g = (Wg_w[k * 384 + j] + Wg_w[k * 384 + 128 + j] + Wg_w[k * 384 + 256 + j]) *
                (1.0f / 3.0f);
      acc += bph[k] * g;
    }
    sD[half][j] = acc;
    __syncthreads();
    if (t < 128) D0[t] = sD[0][t] + sD[1][t];
  } else {
    // fold1: Evec[j], m-split 2-way
    __shared__ float sE[2][128];
    int j = t & 127, half = t >> 7;
    int m0 = half * 64;
    float e = 0.f;
    for (int h = 0; h < 3; ++h) {
#pragma unroll 4
      for (int m = m0; m < m0 + 64; ++m) e += bpp[m] * Wg_in[m * 384 + h * 128 + j];
    }
    sE[half][j] = e;
    __syncthreads();
    if (t < 128) {
      float g0in = (bg_in[t] + bg_in[128 + t] + bg_in[256 + t]) * (1.0f / 3.0f);
      Evec[t] = (sE[0][t] + sE[1][t]) * (1.0f / 3.0f) + g0in;
    }
  }
}

// ===================== fold stage 2: Afold[6][128][16] + bias_out[16] =====================
__global__ void __launch_bounds__(256) k_fold2(
    const float* __restrict__ Wph, const float* __restrict__ Wh1,
    const float* __restrict__ Wp1, const float* __restrict__ Wpp,
    const float* __restrict__ Wfc, const float* __restrict__ bfc,
    const float* __restrict__ bh1, const float* __restrict__ bp1,
    const float* __restrict__ bg_w, const float* __restrict__ B0,
    const float* __restrict__ Ch, const float* __restrict__ D0,
    const float* __restrict__ Evec, float* __restrict__ Afold,
    float* __restrict__ bias_out) {
  int blk = blockIdx.x, t = threadIdx.x;
  if (blk < 48) {
    int mat = blk >> 3, rc = blk & 7;
    __shared__ float sW[2048];
    if (mat == 0)
      for (int i = t; i < 2048; i += 256) sW[i] = B0[i];
    else if (mat == 1)
      for (int i = t; i < 2048; i += 256) sW[i] = Wfc[384 * 16 + i];
    else if (mat == 2)
      for (int i = t; i < 2048; i += 256) sW[i] = Wfc[128 * 16 + i];
    else
      for (int i = t; i < 2048; i += 256) sW[i] = Ch[(size_t)(mat - 3) * 2048 + i];
    __syncthreads();
    int k = rc * 16 + (t >> 4), o = t & 15;
    const float* L = (mat == 0) ? Wph : (mat == 1) ? Wh1 : (mat == 2) ? Wp1 : Wpp;
    float scale = (mat >= 3) ? (1.0f / 3.0f) : 1.0f;
    const float* lr = L + (size_t)k * 128;
    float acc = 0.f;
#pragma unroll 4
    for (int m = 0; m < 128; ++m) acc += lr[m] * sW[m * 16 + o];
    Afold[(size_t)mat * 2048 + k * 16 + o] = acc * scale;
  } else {
    // bias: out[o] = bfc[o] + sum_j 4 terms; j-split 16-way
    __shared__ float sRed[16][16];
    int o = t & 15, chunk = t >> 4;
    int j0 = chunk * 8;
    float acc = 0.f;
#pragma unroll
    for (int jj = 0; jj < 8; ++jj) {
      int j = j0 + jj;
      float g0w = (bg_w[j] + bg_w[128 + j] + bg_w[256 + j]) * (1.0f / 3.0f);
      acc += (D0[j] + g0w) * Wfc[j * 16 + o];
      acc += bp1[j] * Wfc[(128 + j) * 16 + o];
      acc += Evec[j] * Wfc[(256 + j) * 16 + o];
      acc += bh1[j] * Wfc[(384 + j) * 16 + o];
    }
    sRed[o][chunk] = acc;
    __syncthreads();
    if (t < 16) {
      float a = bfc[t];
#pragma unroll
      for (int c = 0; c < 16; ++c) a += sRed[t][c];
      bias_out[t] = a;
    }
  }
}

// ===================== hrs encoder + er: 1024 threads, 8-way (row x K/4) split ==============
__global__ void __launch_bounds__(1024) k_hrs(const float* __restrict__ img,
                                              const float* __restrict__ Whrs,
                                              const float* __restrict__ bhrs,
                                              const float* __restrict__ Wph,
                                              const float* __restrict__ bph,
                                              const float* __restrict__ wv,
                                              float* __restrict__ hrs, float* __restrict__ er) {
  __shared__ float sI[4096];
  __shared__ float sRed[8][128];
  __shared__ float sHrs[2][128];
  __shared__ float sPh[2][128];
  int r0 = blockIdx.x * 2;
  int t = threadIdx.x;
  const float4* gsrc = (const float4*)(img + (size_t)r0 * 2048);
  float4* ldst = (float4*)sI;
  if (t < 1024) ldst[t] = gsrc[t];
  __syncthreads();
  int c = t & 127, g = t >> 7;  // g 0..7
  int row = g & 1, ks = g >> 1; // ks 0..3 (512 k each)
  const float* s = sI + row * 2048 + ks * 512;
  const float* W = Whrs + (size_t)(ks * 512) * 128 + c;
  float a0 = 0.f, a1 = 0.f, a2 = 0.f, a3 = 0.f;
  for (int k = 0; k < 512; k += 4) {
    a0 += s[k] * W[(size_t)k * 128];
    a1 += s[k + 1] * W[(size_t)(k + 1) * 128];
    a2 += s[k + 2] * W[(size_t)(k + 2) * 128];
    a3 += s[k + 3] * W[(size_t)(k + 3) * 128];
  }
  sRed[g][c] = (a0 + a1) + (a2 + a3);
  __syncthreads();
  if (t < 256) {
    int rr = t >> 7, cc = t & 127;
    float v = sRed[rr][cc] + sRed[rr + 2][cc] + sRed[rr + 4][cc] + sRed[rr + 6][cc] + bhrs[cc];
    hrs[(r0 + rr) * 128 + cc] = v;
    sHrs[rr][cc] = v;
  }
  __syncthreads();
  if (t < 256) {
    int rr = t >> 7, cc = t & 127;
    float acc = bph[cc];
#pragma unroll 4
    for (int k = 0; k < 128; ++k) acc += sHrs[rr][k] * Wph[k * 128 + cc];
    sPh[rr][cc] = acc;
  }
  __syncthreads();
  if (t < 6) {
    int rr = t / 3, h = t % 3;
    float s2 = 0.f;
#pragma unroll 4
    for (int k = 0; k < 128; ++k) s2 += sPh[rr][k] * wv[h * 128 + k];
    er[(r0 + rr) * 3 + h] = s2;
  }
}

// ===================== FUSED GCN via dense S' + MFMA (1024 threads, nt-split wave pairs) ====
__global__ void __launch_bounds__(1024) k_gcn_fused(
    const float* __restrict__ x, const float* __restrict__ b1, const float* __restrict__ b2,
    const uint8_t* __restrict__ Sg8, const float* __restrict__ q, const float* __restrict__ ch,
    const float* __restrict__ er, const float* __restrict__ hrs,
    const u16* __restrict__ w1t, const u16* __restrict__ w2t, float* __restrict__ poi_pool,
    float* __restrict__ pooled, u16* __restrict__ mfnb) {
  extern __shared__ char sm[];
  u16* sS = (u16*)sm;
  u16* sB2 = (u16*)(sm + 32768);
  u16* sPt = (u16*)(sm + 32768);
  u16* sXt = (u16*)(sm + 65536);
  u16* sAgg1 = (u16*)(sm + 81920);
  u16* sW1t = (u16*)(sm + 98304);
  float* sXrm = (float*)(sm + 114688);
  u16* sW2t = (u16*)(sm + 114688);
  u16* sAgg2 = (u16*)(sm + 65536);
  u16* sP = (u16*)sm;
  float* sNorm = (float*)(sm + 147968);
  float* sQ = (float*)(sm + 148480);
  float* sAl = (float*)(sm + 150016);
  float* sPool = (float*)(sm + 151552);
  float* sEr = (float*)(sm + 152064);
  float* sCh = (float*)(sm + 152080);

  int b = blockIdx.x, t = threadIdx.x;
  int base = b << 7;
  int l = t & 63, w = t >> 6;       // w 0..15
  int wm = w & 7, wn = w >> 3;      // wave pair: wm = row-group, wn = nt-half
  const uint8_t* Sgb = Sg8 + (size_t)base * 128;

  // ---- phase 0: norms; stage Xrm, W1t, q/er/ch ----
  if (t < 128) {
    const uint4* rp = (const uint4*)(Sgb + (size_t)t * 128);
    uint32_t s = 0;
#pragma unroll
    for (int k = 0; k < 8; ++k) {
      uint4 v = rp[k];
      uint32_t ws[4] = {v.x, v.y, v.z, v.w};
#pragma unroll
      for (int p = 0; p < 4; ++p)
        s += (ws[p] & 0xff) + ((ws[p] >> 8) & 0xff) + ((ws[p] >> 16) & 0xff) + (ws[p] >> 24);
    }
    sNorm[t] = rsqrtf((float)s + 1.0f);
  }
  for (int i = t; i < 8192; i += 1024) {
    int s = i >> 6, f = i & 63;
    sXrm[s * 65 + f] = x[(size_t)(base + s) * 64 + f];
  }
  if (t < 1024) {
    int g = t;
    int n = g >> 3, blk = g & 7;
    *(uint4*)(sW1t + n * 64 + ((blk ^ (n & 7)) << 3)) = ((const uint4*)w1t)[g];
  }
  if (t < 384) sQ[t] = q[t];
  if (t < 3) {
    sEr[t] = er[b * 3 + t];
    sCh[t] = ch[t];
  }
  __syncthreads();

  // ---- phase 1: S' from u8 counts (1 uint4 = 16 counts per thread) + X transpose ----
  {
    int r = t >> 3, q8 = t & 7;
    uint4 cw = *(const uint4*)(Sgb + r * 128 + q8 * 16);
    float nr = sNorm[r];
    int sw = (r & 7) << 3;
    uint32_t words[4] = {cw.x, cw.y, cw.z, cw.w};
#pragma unroll
    for (int qd = 0; qd < 4; ++qd) {
      uint32_t wd = words[qd];
#pragma unroll
      for (int p = 0; p < 4; p += 2) {
        int s0 = q8 * 16 + qd * 4 + p;
        float v0 = ((float)((wd >> (p * 8)) & 0xff) + (r == s0 ? 1.f : 0.f)) * nr * sNorm[s0];
        float v1 =
            ((float)((wd >> (p * 8 + 8)) & 0xff) + (r == s0 + 1 ? 1.f : 0.f)) * nr * sNorm[s0 + 1];
        uint32_t pk = (uint32_t)f2b(v0) | ((uint32_t)f2b(v1) << 16);
        *(uint32_t*)(sS + r * 128 + (s0 ^ sw)) = pk;
      }
    }
  }
  for (int i = t; i < 4096; i += 1024) {
    int f = i >> 6, s = (i & 63) * 2;
    float v0 = sXrm[s * 65 + f] * sNorm[s];
    float v1 = sXrm[(s + 1) * 65 + f] * sNorm[s + 1];
    uint32_t pk = (uint32_t)f2b(v0) | ((uint32_t)f2b(v1) << 16);
    *(uint32_t*)(sXt + (f * 128 + (s ^ ((f & 7) << 3)))) = pk;
  }
  __syncthreads();

  int mrow = wm * 16 + (l & 15);
  int kblk = (l >> 4) * 8;
  int rbase = wm * 16 + (l >> 4) * 4;

  // ---- phase 3: agg1 = S' @ X (nt-split); stage W2t ----
  {
    s8v a4[4];
#pragma unroll
    for (int ks = 0; ks < 4; ++ks) a4[ks] = *(const s8v*)(sS + swz128(mrow, ks * 32 + kblk));
#pragma unroll
    for (int j = 0; j < 2; ++j) {
      int nt = wn * 2 + j;
      f32x4 acc = {0.f, 0.f, 0.f, 0.f};
      int cg = nt * 16 + (l & 15);
#pragma unroll
      for (int ks = 0; ks < 4; ++ks)
        acc = __builtin_amdgcn_mfma_f32_16x16x32_bf16(
            a4[ks], *(const s8v*)(sXt + swz128(cg, ks * 32 + kblk)), acc, 0, 0, 0);
#pragma unroll
      for (int rg = 0; rg < 4; ++rg) sAgg1[swz64(rbase + rg, cg)] = f2b(acc[rg]);
    }
  }
  for (int g = t; g < 2048; g += 1024) {
    int n = g >> 4, blk = g & 15;
    *(uint4*)(sW2t + n * 128 + ((blk ^ (n & 7)) << 3)) = ((const uint4*)w2t)[g];
  }
  __syncthreads();

  // ---- phase 4: h1 = relu(agg1 @ W1 + b1) -> h1^T (nt-split) ----
  {
    s8v a2[2];
#pragma unroll
    for (int ks = 0; ks < 2; ++ks) a2[ks] = *(const s8v*)(sAgg1 + swz64(mrow, ks * 32 + kblk));
#pragma unroll
    for (int j = 0; j < 4; ++j) {
      int nt = wn * 4 + j;
      int cg = nt * 16 + (l & 15);
      float bv = b1[cg];
      f32x4 acc = {bv, bv, bv, bv};
#pragma unroll
      for (int ks = 0; ks < 2; ++ks)
        acc = __builtin_amdgcn_mfma_f32_16x16x32_bf16(
            a2[ks], *(const s8v*)(sW1t + swz64(cg, ks * 32 + kblk)), acc, 0, 0, 0);
      u16 h0 = f2b(fmaxf(acc[0], 0.f)), h1v = f2b(fmaxf(acc[1], 0.f));
      u16 h2 = f2b(fmaxf(acc[2], 0.f)), h3 = f2b(fmaxf(acc[3], 0.f));
      uint2 pk;
      pk.x = (uint32_t)h0 | ((uint32_t)h1v << 16);
      pk.y = (uint32_t)h2 | ((uint32_t)h3 << 16);
      *(uint2*)(sB2 + swz128(cg, rbase)) = pk;
    }
  }
  __syncthreads();

  // ---- phase 5: agg2 = S' @ h1 (nt-split) ----
  {
    s8v a4[4];
#pragma unroll
    for (int ks = 0; ks < 4; ++ks) a4[ks] = *(const s8v*)(sS + swz128(mrow, ks * 32 + kblk));
#pragma unroll
    for (int j = 0; j < 4; ++j) {
      int nt = wn * 4 + j;
      f32x4 acc = {0.f, 0.f, 0.f, 0.f};
      int cg = nt * 16 + (l & 15);
#pragma unroll
      for (int ks = 0; ks < 4; ++ks)
        acc = __builtin_amdgcn_mfma_f32_16x16x32_bf16(
            a4[ks], *(const s8v*)(sB2 + swz128(cg, ks * 32 + kblk)), acc, 0, 0, 0);
#pragma unroll
      for (int rg = 0; rg < 4; ++rg) sAgg2[swz128(rbase + rg, cg)] = f2b(acc[rg]);
    }
  }
  __syncthreads();

  // ---- phase 6: poi = agg2 @ W2 + b2 -> sP + sPt (nt-split) ----
  {
    s8v a4[4];
#pragma unroll
    for (int ks = 0; ks < 4; ++ks) a4[ks] = *(const s8v*)(sAgg2 + swz128(mrow, ks * 32 + kblk));
#pragma unroll
    for (int j = 0; j < 4; ++j) {
      int nt = wn * 4 + j;
      int cg = nt * 16 + (l & 15);
      float bv = b2[cg];
      f32x4 acc = {bv, bv, bv, bv};
#pragma unroll
      for (int ks = 0; ks < 4; ++ks)
        acc = __builtin_amdgcn_mfma_f32_16x16x32_bf16(
            a4[ks], *(const s8v*)(sW2t + swz128(cg, ks * 32 + kblk)), acc, 0, 0, 0);
      u16 p0 = f2b(acc[0]), p1 = f2b(acc[1]), p2 = f2b(acc[2]), p3 = f2b(acc[3]);
#pragma unroll
      for (int rg = 0; rg < 4; ++rg)
        sP[swz128(rbase + rg, cg)] = (rg == 0) ? p0 : (rg == 1) ? p1 : (rg == 2) ? p2 : p3;
      uint2 pk;
      pk.x = (uint32_t)p0 | ((uint32_t)p1 << 16);
      pk.y = (uint32_t)p2 | ((uint32_t)p3 << 16);
      *(uint2*)(sPt + swz128(cg, rbase)) = pk;
    }
  }
  __syncthreads();

  // ---- tail: pool from Pt rows ----
  if (t < 128) {
    int c = t;
    float s = 0.f;
    const u16* rowp = sPt + c * 128;
    int sw = (c & 7) << 3;
#pragma unroll
    for (int k8 = 0; k8 < 16; ++k8) {
      s8v v = *(const s8v*)(rowp + ((k8 * 8) ^ sw));
#pragma unroll
      for (int j = 0; j < 8; ++j) s += b2f((u16)v[j]);
    }
    sPool[c] = s;
    poi_pool[b * 128 + c] = s * (1.0f / 128.0f);
  }
  if (t < 384) {
    int r = t & 127, h = t >> 7;
    int sw = (r & 7) << 3;
    const u16* rowp = sP + r * 128;
    const float* qh = &sQ[h * 128];
    float d = 0.f;
#pragma unroll
    for (int k8 = 0; k8 < 16; ++k8) {
      int c8 = (k8 * 8) ^ sw;
      s8v v = *(const s8v*)(rowp + c8);
#pragma unroll
      for (int j = 0; j < 8; ++j) d += b2f((u16)v[j]) * qh[c8 + j];
    }
    float e = d + sCh[h] + sEr[h];
    sAl[h * 128 + r] = (e > 0.f) ? e : 0.2f * e;
  }
  __syncthreads();

  if (t < 192) {
    int h = t >> 6, ll = t & 63;
    float v0 = sAl[h * 128 + ll], v1 = sAl[h * 128 + 64 + ll];
    float m = fmaxf(v0, v1);
    for (int off = 32; off > 0; off >>= 1) m = fmaxf(m, __shfl_xor(m, off));
    float x0 = __expf(v0 - m), x1 = __expf(v1 - m);
    float s = x0 + x1;
    for (int off = 32; off > 0; off >>= 1) s += __shfl_xor(s, off);
    float inv = 1.0f / s;
    sAl[h * 128 + ll] = x0 * inv;
    sAl[h * 128 + 64 + ll] = x1 * inv;
  }
  __syncthreads();

  if (t < 384) {
    int hh = t >> 7, c = t & 127;
    int sw = (c & 7) << 3;
    const u16* rowp = sPt + c * 128;
    const float* al = &sAl[hh * 128];
    float s = 0.f;
#pragma unroll
    for (int k8 = 0; k8 < 16; ++k8) {
      int r8 = (k8 * 8) ^ sw;
      s8v v = *(const s8v*)(rowp + r8);
#pragma unroll
      for (int j = 0; j < 8; ++j) s += b2f((u16)v[j]) * al[r8 + j];
    }
    pooled[((size_t)b * 3 + hh) * 128 + c] = s;
  }
  __syncthreads();

  // ---- fused mfn (bf16 out) ----
  float hv = 0.f, pv = 0.f;
  if (t < 128) {
    hv = hrs[base + t];
    pv = sPool[t] * (1.0f / 128.0f);
    sQ[t] = hv * hv + pv * pv;
  }
  __syncthreads();
  if (t < 64) {
    float v = sQ[t] + sQ[t + 64];
    for (int off = 32; off > 0; off >>= 1) v += __shfl_xor(v, off);
    if (t == 0) sQ[0] = rsqrtf(v);
  }
  __syncthreads();
  if (t < 128) {
    float rn = sQ[0];
    mfnb[b * 256 + t] = f2b(hv * rn);
    mfnb[b * 256 + 128 + t] = f2b(pv * rn);
  }
}

// ===================== med via MFMA: med = (mfn @ mfn^T + 1)/2 =====================
__global__ void __launch_bounds__(256) k_med(const u16* __restrict__ mfnb,
                                             float* __restrict__ med) {
  __shared__ u16 sA[32 * 256];
  __shared__ u16 sB[32 * 256];
  int bi = blockIdx.x >> 4, bj = blockIdx.x & 15;
  int t = threadIdx.x;
  const uint4* srcA = (const uint4*)(mfnb + (size_t)bi * 32 * 256);
  const uint4* srcB = (const uint4*)(mfnb + (size_t)bj * 32 * 256);
  for (int g = t; g < 1024; g += 256) {
    int r = g >> 5, blk = g & 31;
    int db = (blk & 24) | ((blk ^ (r & 7)) & 7);
    uint4 va = srcA[g];
    uint4 vb = srcB[g];
    *(uint4*)(sA + r * 256 + db * 8) = va;
    *(uint4*)(sB + r * 256 + db * 8) = vb;
  }
  __syncthreads();
  int l = t & 63, w = t >> 6;
  int wr = w >> 1, wc = w & 1;
  int arow = wr * 16 + (l & 15);
  int brow = wc * 16 + (l & 15);
  int kblk = (l >> 4) * 8;
  f32x4 acc = {0.f, 0.f, 0.f, 0.f};
#pragma unroll
  for (int ks = 0; ks < 8; ++ks) {
    int kc = ks * 32 + kblk;
    s8v a = *(const s8v*)(sA + arow * 256 + (kc ^ ((arow & 7) << 3)));
    s8v bb = *(const s8v*)(sB + brow * 256 + (kc ^ ((brow & 7) << 3)));
    acc = __builtin_amdgcn_mfma_f32_16x16x32_bf16(a, bb, acc, 0, 0, 0);
  }
  int row0 = bi * 32 + wr * 16 + (l >> 4) * 4;
  int col = bj * 32 + wc * 16 + (l & 15);
#pragma unroll
  for (int rg = 0; rg < 4; ++rg)
    med[(size_t)(row0 + rg) * 512 + col] = (acc[rg] + 1.0f) * 0.5f;
}

__global__ void k_rowsum(const float* __restrict__ med, const float* __restrict__ T0p,
                         float* __restrict__ dinv) {
  int r = blockIdx.x, l = threadIdx.x;
  float T0 = *T0p;
  float cnt = 0.f;
  for (int j = l; j < 512; j += 64) cnt += ((med[(size_t)r * 512 + j] >= T0) || (j == r)) ? 1.0f : 0.0f;
  for (int off = 32; off > 0; off >>= 1) cnt += __shfl_xor(cnt, off);
  if (l == 0) dinv[r] = rsqrtf(cnt);
}

// ===================== slim epilogue: sparse Aagg + folded 768->16 dot =====================
__global__ void __launch_bounds__(256) k_epilogue(
    const float* __restrict__ med, const float* __restrict__ T0p,
    const float* __restrict__ dinv, const float* __restrict__ hrs,
    const float* __restrict__ pool, const float* __restrict__ pooled,
    const float* __restrict__ Afold, const float* __restrict__ bias_out,
    float* __restrict__ out) {
  __shared__ float sMedRow[512];
  __shared__ float sIn[6][128];  // 0=hrs, 1=T1, 2=T2, 3..5=pooled_h
  __shared__ float sRed[16][16];
  __shared__ int sNbr[64];
  __shared__ float sDw[64];
  __shared__ int sNnz;
  int i = blockIdx.x, t = threadIdx.x;
  float T0 = *T0p;

  for (int j = t; j < 512; j += 256) sMedRow[j] = med[(size_t)i * 512 + j];
  if (t < 128) sIn[0][t] = hrs[i * 128 + t];
  for (int k = t; k < 384; k += 256) sIn[3 + (k >> 7)][k & 127] = pooled[(size_t)i * 384 + k];
  __syncthreads();

  if (t < 64) {
    int cnt = 0, flags = 0;
#pragma unroll
    for (int k = 0; k < 8; ++k) {
      int j = t * 8 + k;
      if (sMedRow[j] >= T0 || j == i) {
        flags |= 1 << k;
        ++cnt;
      }
    }
    int off = cnt;
    for (int d = 1; d < 64; d <<= 1) {
      int v = __shfl_up(off, d);
      if (t >= d) off += v;
    }
    off -= cnt;
    int pos = off;
#pragma unroll
    for (int k = 0; k < 8; ++k)
      if (flags & (1 << k)) {
        int j = t * 8 + k;
        if (pos < 64) {
          sNbr[pos] = j;
          sDw[pos] = dinv[j];
        }
        ++pos;
      }
    if (t == 63) sNnz = off + cnt;
  }
  __syncthreads();

  {
    int half = t >> 7, c = t & 127;
    float di = dinv[i];
    const float* srcm = half ? pool : hrs;
    float acc = 0.f;
    int nnz = sNnz;
    if (nnz <= 64) {
      for (int n = 0; n < nnz; ++n) acc += sDw[n] * srcm[sNbr[n] * 128 + c];
    } else {
      for (int j = 0; j < 512; ++j)
        if (sMedRow[j] >= T0 || j == i) acc += dinv[j] * srcm[j * 128 + c];
    }
    sIn[1 + half][c] = acc * di;
  }
  __syncthreads();

  {
    int o = t >> 4, chunk = t & 15;
    int c0 = chunk * 8;
    float acc = 0.f;
#pragma unroll
    for (int m = 0; m < 6; ++m) {
      const float* A = Afold + m * 2048;
      const float* xm = sIn[m];
#pragma unroll
      for (int k = 0; k < 8; ++k) acc += xm[c0 + k] * A[(c0 + k) * 16 + o];
    }
    sRed[o][chunk] = acc;
  }
  __syncthreads();
  if (t < 16) {
    float acc = bias_out[t];
#pragma unroll
    for (int j = 0; j < 16; ++j) acc += sRed[t][j];
    out[i * 16 + t] = acc;
  }
}

// ===================== host =====================
extern "C" void kernel_launch(void* const* d_in, const int* in_sizes, int n_in,
                              void* d_out, int out_size, void* d_ws, size_t ws_size,
                              hipStream_t stream) {
  const float* poi_x = (const float*)d_in[0];
  const float* img = (const float*)d_in[1];
  const int* edges = (const int*)d_in[2];
  const float* T0p = (const float*)d_in[4];
  const float* W1 = (const float*)d_in[5];
  const float* b1 = (const float*)d_in[6];
  const float* W2 = (const float*)d_in[7];
  const float* b2 = (const float*)d_in[8];
  const float* Whrs = (const float*)d_in[9];
  const float* bhrs = (const float*)d_in[10];
  const float* Wph = (const float*)d_in[11];
  const float* bph = (const float*)d_in[12];
  const float* Wpp = (const float*)d_in[13];
  const float* bpp = (const float*)d_in[14];
  const float* Wg_in = (const float*)d_in[15];
  const float* al_in = (const float*)d_in[16];
  const float* ar_in = (const float*)d_in[17];
  const float* bg_in = (const float*)d_in[18];
  const float* Wg_w = (const float*)d_in[19];
  const float* bg_w = (const float*)d_in[22];
  const float* Wh1 = (const float*)d_in[23];
  const float* bh1 = (const float*)d_in[24];
  const float* Wp1 = (const float*)d_in[25];
  const float* bp1 = (const float*)d_in[26];
  const float* Wfc = (const float*)d_in[27];
  const float* bfc = (const float*)d_in[28];

  const int* esrc = edges;
  const int* edst = edges + EE;

  char* ws = (char*)d_ws;
  size_t off = 0;
  auto alloc = [&](size_t nbytes) -> char* {
    char* p = ws + off;
    off += (nbytes + 255) & ~(size_t)255;
    return p;
  };
  uint8_t* Sg8 = (uint8_t*)alloc((size_t)NN * 128);
  u16* w1t = (u16*)alloc(8192 * 2);
  u16* w2t = (u16*)alloc(16384 * 2);
  float* hrs = (float*)alloc(512 * 128 * 4);
  float* er = (float*)alloc(512 * 3 * 4);
  float* wv = (float*)alloc(384 * 4);
  float* q = (float*)alloc(384 * 4);
  float* chv = (float*)alloc(16);
  float* B0 = (float*)alloc(2048 * 4);
  float* Chb = (float*)alloc(3 * 2048 * 4);
  float* D0 = (float*)alloc(128 * 4);
  float* Evec = (float*)alloc(128 * 4);
  float* Afold = (float*)alloc(6 * 2048 * 4);
  float* bias_out = (float*)alloc(16 * 4);
  float* pool = (float*)alloc(512 * 128 * 4);
  float* pooled = (float*)alloc((size_t)1536 * 128 * 4);
  u16* mfnb = (u16*)alloc(512 * 256 * 2);
  float* dinv = (float*)alloc(512 * 4);

  float* out = (float*)d_out;
  float* med = out + 512 * 16;

  hipMemsetAsync(Sg8, 0, (size_t)NN * 128, stream);

  size_t dynf = 152096;
  hipFuncSetAttribute((const void*)k_gcn_fused, hipFuncAttributeMaxDynamicSharedMemorySize,
                      (int)dynf);

  k_prep_graph<<<2179, 256, 0, stream>>>(esrc, edst, (uint32_t*)Sg8, W1, W2, Wg_in, al_in,
                                         ar_in, Wpp, bpp, w1t, w2t, wv, q, chv, Wg_w, Wfc, bph,
                                         bg_in, B0, Chb, D0, Evec);
  k_fold2<<<49, 256, 0, stream>>>(Wph, Wh1, Wp1, Wpp, Wfc, bfc, bh1, bp1, bg_w, B0, Chb, D0,
                                  Evec, Afold, bias_out);
  k_hrs<<<256, 1024, 0, stream>>>(img, Whrs, bhrs, Wph, bph, wv, hrs, er);
  k_gcn_fused<<<512, 1024, dynf, stream>>>(poi_x, b1, b2, Sg8, q, chv, er, hrs, w1t, w2t, pool,
                                           pooled, mfnb);
  k_med<<<256, 256, 0, stream>>>(mfnb, med);
  k_rowsum<<<512, 64, 0, stream>>>(med, T0p, dinv);
  k_epilogue<<<512, 256, 0, stream>>>(med, T0p, dinv, hrs, pool, pooled, Afold, bias_out, out);

  (void)in_sizes; (void)n_in; (void)out_size; (void)ws_size;
}

// Round 15
// 141.562 us; speedup vs baseline: 1.4915x; 1.0280x over previous
//
#include <hip/hip_runtime.h>
#include <stdint.h>

#define NN 65536
#define EE 524288
#define BB 512

typedef unsigned short u16;
typedef __attribute__((ext_vector_type(8))) short s8v;    // 8 bf16 (4 VGPRs)
typedef __attribute__((ext_vector_type(4))) float f32x4;  // MFMA acc

__device__ __forceinline__ u16 f2b(float f) {
  union { float f; uint32_t u; } a{f};
  uint32_t r = a.u + 0x7fff + ((a.u >> 16) & 1);
  return (u16)(r >> 16);
}
__device__ __forceinline__ float b2f(u16 v) {
  union { uint32_t u; float f; } a{(uint32_t)v << 16};
  return a.f;
}
__device__ __forceinline__ int swz128(int r, int c) { return r * 128 + (c ^ ((r & 7) << 3)); }
__device__ __forceinline__ int swz64(int r, int c) { return r * 64 + (c ^ ((r & 7) << 3)); }

// ===================== merged: scatterS + weight prep + fold1 + rowcnt zero =====================
__global__ void __launch_bounds__(256) k_prep_graph(
    const int* __restrict__ src, const int* __restrict__ dst, uint32_t* __restrict__ Sg,
    const float* __restrict__ W1, const float* __restrict__ W2,
    const float* __restrict__ Wg_in, const float* __restrict__ al_in,
    const float* __restrict__ ar_in, const float* __restrict__ Wpp,
    const float* __restrict__ bpp, u16* __restrict__ w1t, u16* __restrict__ w2t,
    float* __restrict__ wv, float* __restrict__ q, float* __restrict__ ch,
    const float* __restrict__ Wg_w, const float* __restrict__ Wfc,
    const float* __restrict__ bph, const float* __restrict__ bg_in,
    float* __restrict__ B0, float* __restrict__ Ch, float* __restrict__ D0,
    float* __restrict__ Evec, int* __restrict__ rowcnt) {
  int blk = blockIdx.x, t = threadIdx.x;
  if (blk < 2048) {
    int e = blk * 256 + t;
    int s = src[e] & 127, d = dst[e];
    atomicAdd(&Sg[((size_t)d * 128 + s) >> 2], 1u << ((s & 3) * 8));
  } else if (blk < 2144) {
    int i = (blk - 2048) * 256 + t;  // 24576
    if (i < 8192) {
      int n = i >> 6, k = i & 63;
      w1t[i] = f2b(W1[k * 128 + n]);
    } else {
      int j = i - 8192;
      int n = j >> 7, k = j & 127;
      w2t[j] = f2b(W2[k * 128 + n]);
    }
  } else if (blk == 2144) {
    __shared__ float su[384];
    for (int i = t; i < 384; i += 256) {
      int h = i >> 7, k = i & 127;
      float s = 0.f, sw = 0.f;
#pragma unroll 4
      for (int c = 0; c < 128; ++c) {
        float g = Wg_in[k * 384 + h * 128 + c];
        s += g * al_in[h * 128 + c];
        sw += g * ar_in[h * 128 + c];
      }
      su[i] = s;
      wv[i] = sw;
    }
    __syncthreads();
    for (int i = t; i < 384; i += 256) {
      int h = i >> 7, j = i & 127;
      float s = 0.f;
#pragma unroll 4
      for (int k = 0; k < 128; ++k) s += Wpp[j * 128 + k] * su[h * 128 + k];
      q[i] = s;
    }
    if (t < 3) {
      float s = 0.f;
#pragma unroll 4
      for (int k = 0; k < 128; ++k) s += bpp[k] * su[t * 128 + k];
      ch[t] = s;
    }
  } else if (blk < 2153) {
    int bb = blk - 2145;
    __shared__ float sW[2048];
    for (int i = t; i < 2048; i += 256) sW[i] = Wfc[i];
    __syncthreads();
    int m = bb * 16 + (t >> 4), o = t & 15;
    const float* wr = Wg_w + (size_t)m * 384;
    float acc = 0.f;
#pragma unroll 4
    for (int j = 0; j < 128; ++j) {
      float g = (wr[j] + wr[128 + j] + wr[256 + j]) * (1.0f / 3.0f);
      acc += g * sW[j * 16 + o];
    }
    B0[m * 16 + o] = acc;
  } else if (blk < 2177) {
    int bb = blk - 2153;
    int h = bb >> 3, rc = bb & 7;
    __shared__ float sW[2048];
    for (int i = t; i < 2048; i += 256) sW[i] = Wfc[256 * 16 + i];
    __syncthreads();
    int m = rc * 16 + (t >> 4), o = t & 15;
    const float* wr = Wg_in + (size_t)m * 384 + h * 128;
    float acc = 0.f;
#pragma unroll 4
    for (int c = 0; c < 128; ++c) acc += wr[c] * sW[c * 16 + o];
    Ch[((size_t)h * 128 + m) * 16 + o] = acc;
  } else if (blk == 2177) {
    __shared__ float sD[2][128];
    int j = t & 127, half = t >> 7;
    int k0 = half * 64;
    float acc = 0.f;
#pragma unroll 4
    for (int k = k0; k < k0 + 64; ++k) {
      float g = (Wg_w[k * 384 + j] + Wg_w[k * 384 + 128 + j] + Wg_w[k * 384 + 256 + j]) *
                (1.0f / 3.0f);
      acc += bph[k] * g;
    }
    sD[half][j] = acc;
    __syncthreads();
    if (t < 128) D0[t] = sD[0][t] + sD[1][t];
  } else if (blk == 2178) {
    __shared__ float sE[2][128];
    int j = t & 127, half = t >> 7;
    int m0 = half * 64;
    float e = 0.f;
    for (int h = 0; h < 3; ++h) {
#pragma unroll 4
      for (int m = m0; m < m0 + 64; ++m) e += bpp[m] * Wg_in[m * 384 + h * 128 + j];
    }
    sE[half][j] = e;
    __syncthreads();
    if (t < 128) {
      float g0in = (bg_in[t] + bg_in[128 + t] + bg_in[256 + t]) * (1.0f / 3.0f);
      Evec[t] = (sE[0][t] + sE[1][t]) * (1.0f / 3.0f) + g0in;
    }
  } else {
    if (t < 256) {
      rowcnt[t] = 0;
      rowcnt[t + 256] = 0;
    }
  }
}

// ===================== fold stage 2: Afold[6][128][16] + bias_out[16] =====================
__global__ void __launch_bounds__(256) k_fold2(
    const float* __restrict__ Wph, const float* __restrict__ Wh1,
    const float* __restrict__ Wp1, const float* __restrict__ Wpp,
    const float* __restrict__ Wfc, const float* __restrict__ bfc,
    const float* __restrict__ bh1, const float* __restrict__ bp1,
    const float* __restrict__ bg_w, const float* __restrict__ B0,
    const float* __restrict__ Ch, const float* __restrict__ D0,
    const float* __restrict__ Evec, float* __restrict__ Afold,
    float* __restrict__ bias_out) {
  int blk = blockIdx.x, t = threadIdx.x;
  if (blk < 48) {
    int mat = blk >> 3, rc = blk & 7;
    __shared__ float sW[2048];
    if (mat == 0)
      for (int i = t; i < 2048; i += 256) sW[i] = B0[i];
    else if (mat == 1)
      for (int i = t; i < 2048; i += 256) sW[i] = Wfc[384 * 16 + i];
    else if (mat == 2)
      for (int i = t; i < 2048; i += 256) sW[i] = Wfc[128 * 16 + i];
    else
      for (int i = t; i < 2048; i += 256) sW[i] = Ch[(size_t)(mat - 3) * 2048 + i];
    __syncthreads();
    int k = rc * 16 + (t >> 4), o = t & 15;
    const float* L = (mat == 0) ? Wph : (mat == 1) ? Wh1 : (mat == 2) ? Wp1 : Wpp;
    float scale = (mat >= 3) ? (1.0f / 3.0f) : 1.0f;
    const float* lr = L + (size_t)k * 128;
    float acc = 0.f;
#pragma unroll 4
    for (int m = 0; m < 128; ++m) acc += lr[m] * sW[m * 16 + o];
    Afold[(size_t)mat * 2048 + k * 16 + o] = acc * scale;
  } else {
    __shared__ float sRed[16][16];
    int o = t & 15, chunk = t >> 4;
    int j0 = chunk * 8;
    float acc = 0.f;
#pragma unroll
    for (int jj = 0; jj < 8; ++jj) {
      int j = j0 + jj;
      float g0w = (bg_w[j] + bg_w[128 + j] + bg_w[256 + j]) * (1.0f / 3.0f);
      acc += (D0[j] + g0w) * Wfc[j * 16 + o];
      acc += bp1[j] * Wfc[(128 + j) * 16 + o];
      acc += Evec[j] * Wfc[(256 + j) * 16 + o];
      acc += bh1[j] * Wfc[(384 + j) * 16 + o];
    }
    sRed[o][chunk] = acc;
    __syncthreads();
    if (t < 16) {
      float a = bfc[t];
#pragma unroll
      for (int c = 0; c < 16; ++c) a += sRed[t][c];
      bias_out[t] = a;
    }
  }
}

// ===================== hrs encoder + er: 1024 threads =====================
__global__ void __launch_bounds__(1024) k_hrs(const float* __restrict__ img,
                                              const float* __restrict__ Whrs,
                                              const float* __restrict__ bhrs,
                                              const float* __restrict__ Wph,
                                              const float* __restrict__ bph,
                                              const float* __restrict__ wv,
                                              float* __restrict__ hrs, float* __restrict__ er) {
  __shared__ float sI[4096];
  __shared__ float sRed[8][128];
  __shared__ float sHrs[2][128];
  __shared__ float sPh[2][128];
  int r0 = blockIdx.x * 2;
  int t = threadIdx.x;
  const float4* gsrc = (const float4*)(img + (size_t)r0 * 2048);
  float4* ldst = (float4*)sI;
  if (t < 1024) ldst[t] = gsrc[t];
  __syncthreads();
  int c = t & 127, g = t >> 7;
  int row = g & 1, ks = g >> 1;
  const float* s = sI + row * 2048 + ks * 512;
  const float* W = Whrs + (size_t)(ks * 512) * 128 + c;
  float a0 = 0.f, a1 = 0.f, a2 = 0.f, a3 = 0.f;
  for (int k = 0; k < 512; k += 4) {
    a0 += s[k] * W[(size_t)k * 128];
    a1 += s[k + 1] * W[(size_t)(k + 1) * 128];
    a2 += s[k + 2] * W[(size_t)(k + 2) * 128];
    a3 += s[k + 3] * W[(size_t)(k + 3) * 128];
  }
  sRed[g][c] = (a0 + a1) + (a2 + a3);
  __syncthreads();
  if (t < 256) {
    int rr = t >> 7, cc = t & 127;
    float v = sRed[rr][cc] + sRed[rr + 2][cc] + sRed[rr + 4][cc] + sRed[rr + 6][cc] + bhrs[cc];
    hrs[(r0 + rr) * 128 + cc] = v;
    sHrs[rr][cc] = v;
  }
  __syncthreads();
  if (t < 256) {
    int rr = t >> 7, cc = t & 127;
    float acc = bph[cc];
#pragma unroll 4
    for (int k = 0; k < 128; ++k) acc += sHrs[rr][k] * Wph[k * 128 + cc];
    sPh[rr][cc] = acc;
  }
  __syncthreads();
  if (t < 6) {
    int rr = t / 3, h = t % 3;
    float s2 = 0.f;
#pragma unroll 4
    for (int k = 0; k < 128; ++k) s2 += sPh[rr][k] * wv[h * 128 + k];
    er[(r0 + rr) * 3 + h] = s2;
  }
}

// ===================== FUSED GCN via dense S' + MFMA (1024 thr, single Sg read) ====
__global__ void __launch_bounds__(1024) k_gcn_fused(
    const float* __restrict__ x, const float* __restrict__ b1, const float* __restrict__ b2,
    const uint8_t* __restrict__ Sg8, const float* __restrict__ q, const float* __restrict__ ch,
    const float* __restrict__ er, const float* __restrict__ hrs,
    const u16* __restrict__ w1t, const u16* __restrict__ w2t, float* __restrict__ poi_pool,
    float* __restrict__ pooled, u16* __restrict__ mfnb) {
  extern __shared__ char sm[];
  u16* sS = (u16*)sm;
  u16* sB2 = (u16*)(sm + 32768);
  u16* sPt = (u16*)(sm + 32768);
  u16* sXt = (u16*)(sm + 65536);
  u16* sAgg1 = (u16*)(sm + 81920);
  u16* sW1t = (u16*)(sm + 98304);
  float* sXrm = (float*)(sm + 114688);
  u16* sW2t = (u16*)(sm + 114688);
  u16* sAgg2 = (u16*)(sm + 65536);
  u16* sP = (u16*)sm;
  float* sNorm = (float*)(sm + 147968);
  float* sQ = (float*)(sm + 148480);
  float* sAl = (float*)(sm + 150016);
  float* sPool = (float*)(sm + 151552);
  float* sEr = (float*)(sm + 152064);
  float* sCh = (float*)(sm + 152080);

  int b = blockIdx.x, t = threadIdx.x;
  int base = b << 7;
  int l = t & 63, w = t >> 6;
  int wm = w & 7, wn = w >> 3;
  const uint8_t* Sgb = Sg8 + (size_t)base * 128;

  // ---- phase 0: single Sg read (kept in regs) + shuffle row-sums -> norms; stage rest ----
  int rown = t >> 3, q8 = t & 7;
  uint4 cw = *(const uint4*)(Sgb + rown * 128 + q8 * 16);
  {
    uint32_t words[4] = {cw.x, cw.y, cw.z, cw.w};
    uint32_t bs = 0;
#pragma unroll
    for (int p = 0; p < 4; ++p)
      bs += (words[p] & 0xff) + ((words[p] >> 8) & 0xff) + ((words[p] >> 16) & 0xff) +
            (words[p] >> 24);
    bs += __shfl_xor((int)bs, 1);
    bs += __shfl_xor((int)bs, 2);
    bs += __shfl_xor((int)bs, 4);
    if ((t & 7) == 0) sNorm[rown] = rsqrtf((float)bs + 1.0f);
  }
  for (int i = t; i < 8192; i += 1024) {
    int s = i >> 6, f = i & 63;
    sXrm[s * 65 + f] = x[(size_t)(base + s) * 64 + f];
  }
  {
    int g = t;
    int n = g >> 3, blk = g & 7;
    *(uint4*)(sW1t + n * 64 + ((blk ^ (n & 7)) << 3)) = ((const uint4*)w1t)[g];
  }
  if (t < 384) sQ[t] = q[t];
  if (t < 3) {
    sEr[t] = er[b * 3 + t];
    sCh[t] = ch[t];
  }
  __syncthreads();

  // ---- phase 1: S' from retained counts + X transpose->bf16 ----
  {
    int r = rown;
    float nr = sNorm[r];
    int sw = (r & 7) << 3;
    uint32_t words[4] = {cw.x, cw.y, cw.z, cw.w};
#pragma unroll
    for (int qd = 0; qd < 4; ++qd) {
      uint32_t wd = words[qd];
#pragma unroll
      for (int p = 0; p < 4; p += 2) {
        int s0 = q8 * 16 + qd * 4 + p;
        float v0 = ((float)((wd >> (p * 8)) & 0xff) + (r == s0 ? 1.f : 0.f)) * nr * sNorm[s0];
        float v1 =
            ((float)((wd >> (p * 8 + 8)) & 0xff) + (r == s0 + 1 ? 1.f : 0.f)) * nr * sNorm[s0 + 1];
        uint32_t pk = (uint32_t)f2b(v0) | ((uint32_t)f2b(v1) << 16);
        *(uint32_t*)(sS + r * 128 + (s0 ^ sw)) = pk;
      }
    }
  }
  for (int i = t; i < 4096; i += 1024) {
    int f = i >> 6, s = (i & 63) * 2;
    float v0 = sXrm[s * 65 + f] * sNorm[s];
    float v1 = sXrm[(s + 1) * 65 + f] * sNorm[s + 1];
    uint32_t pk = (uint32_t)f2b(v0) | ((uint32_t)f2b(v1) << 16);
    *(uint32_t*)(sXt + (f * 128 + (s ^ ((f & 7) << 3)))) = pk;
  }
  __syncthreads();

  int mrow = wm * 16 + (l & 15);
  int kblk = (l >> 4) * 8;
  int rbase = wm * 16 + (l >> 4) * 4;

  // ---- phase 3: agg1 = S' @ X (nt-split); stage W2t ----
  {
    s8v a4[4];
#pragma unroll
    for (int ks = 0; ks < 4; ++ks) a4[ks] = *(const s8v*)(sS + swz128(mrow, ks * 32 + kblk));
#pragma unroll
    for (int j = 0; j < 2; ++j) {
      int nt = wn * 2 + j;
      f32x4 acc = {0.f, 0.f, 0.f, 0.f};
      int cg = nt * 16 + (l & 15);
#pragma unroll
      for (int ks = 0; ks < 4; ++ks)
        acc = __builtin_amdgcn_mfma_f32_16x16x32_bf16(
            a4[ks], *(const s8v*)(sXt + swz128(cg, ks * 32 + kblk)), acc, 0, 0, 0);
#pragma unroll
      for (int rg = 0; rg < 4; ++rg) sAgg1[swz64(rbase + rg, cg)] = f2b(acc[rg]);
    }
  }
  for (int g = t; g < 2048; g += 1024) {
    int n = g >> 4, blk = g & 15;
    *(uint4*)(sW2t + n * 128 + ((blk ^ (n & 7)) << 3)) = ((const uint4*)w2t)[g];
  }
  __syncthreads();

  // ---- phase 4: h1 = relu(agg1 @ W1 + b1) -> h1^T (nt-split) ----
  {
    s8v a2[2];
#pragma unroll
    for (int ks = 0; ks < 2; ++ks) a2[ks] = *(const s8v*)(sAgg1 + swz64(mrow, ks * 32 + kblk));
#pragma unroll
    for (int j = 0; j < 4; ++j) {
      int nt = wn * 4 + j;
      int cg = nt * 16 + (l & 15);
      float bv = b1[cg];
      f32x4 acc = {bv, bv, bv, bv};
#pragma unroll
      for (int ks = 0; ks < 2; ++ks)
        acc = __builtin_amdgcn_mfma_f32_16x16x32_bf16(
            a2[ks], *(const s8v*)(sW1t + swz64(cg, ks * 32 + kblk)), acc, 0, 0, 0);
      u16 h0 = f2b(fmaxf(acc[0], 0.f)), h1v = f2b(fmaxf(acc[1], 0.f));
      u16 h2 = f2b(fmaxf(acc[2], 0.f)), h3 = f2b(fmaxf(acc[3], 0.f));
      uint2 pk;
      pk.x = (uint32_t)h0 | ((uint32_t)h1v << 16);
      pk.y = (uint32_t)h2 | ((uint32_t)h3 << 16);
      *(uint2*)(sB2 + swz128(cg, rbase)) = pk;
    }
  }
  __syncthreads();

  // ---- phase 5: agg2 = S' @ h1 (nt-split) ----
  {
    s8v a4[4];
#pragma unroll
    for (int ks = 0; ks < 4; ++ks) a4[ks] = *(const s8v*)(sS + swz128(mrow, ks * 32 + kblk));
#pragma unroll
    for (int j = 0; j < 4; ++j) {
      int nt = wn * 4 + j;
      f32x4 acc = {0.f, 0.f, 0.f, 0.f};
      int cg = nt * 16 + (l & 15);
#pragma unroll
      for (int ks = 0; ks < 4; ++ks)
        acc = __builtin_amdgcn_mfma_f32_16x16x32_bf16(
            a4[ks], *(const s8v*)(sB2 + swz128(cg, ks * 32 + kblk)), acc, 0, 0, 0);
#pragma unroll
      for (int rg = 0; rg < 4; ++rg) sAgg2[swz128(rbase + rg, cg)] = f2b(acc[rg]);
    }
  }
  __syncthreads();

  // ---- phase 6: poi = agg2 @ W2 + b2 -> sP + sPt (nt-split) ----
  {
    s8v a4[4];
#pragma unroll
    for (int ks = 0; ks < 4; ++ks) a4[ks] = *(const s8v*)(sAgg2 + swz128(mrow, ks * 32 + kblk));
#pragma unroll
    for (int j = 0; j < 4; ++j) {
      int nt = wn * 4 + j;
      int cg = nt * 16 + (l & 15);
      float bv = b2[cg];
      f32x4 acc = {bv, bv, bv, bv};
#pragma unroll
      for (int ks = 0; ks < 4; ++ks)
        acc = __builtin_amdgcn_mfma_f32_16x16x32_bf16(
            a4[ks], *(const s8v*)(sW2t + swz128(cg, ks * 32 + kblk)), acc, 0, 0, 0);
      u16 p0 = f2b(acc[0]), p1 = f2b(acc[1]), p2 = f2b(acc[2]), p3 = f2b(acc[3]);
#pragma unroll
      for (int rg = 0; rg < 4; ++rg)
        sP[swz128(rbase + rg, cg)] = (rg == 0) ? p0 : (rg == 1) ? p1 : (rg == 2) ? p2 : p3;
      uint2 pk;
      pk.x = (uint32_t)p0 | ((uint32_t)p1 << 16);
      pk.y = (uint32_t)p2 | ((uint32_t)p3 << 16);
      *(uint2*)(sPt + swz128(cg, rbase)) = pk;
    }
  }
  __syncthreads();

  // ---- tail: pool from Pt rows ----
  if (t < 128) {
    int c = t;
    float s = 0.f;
    const u16* rowp = sPt + c * 128;
    int sw = (c & 7) << 3;
#pragma unroll
    for (int k8 = 0; k8 < 16; ++k8) {
      s8v v = *(const s8v*)(rowp + ((k8 * 8) ^ sw));
#pragma unroll
      for (int j = 0; j < 8; ++j) s += b2f((u16)v[j]);
    }
    sPool[c] = s;
    poi_pool[b * 128 + c] = s * (1.0f / 128.0f);
  }
  if (t < 384) {
    int r = t & 127, h = t >> 7;
    int sw = (r & 7) << 3;
    const u16* rowp = sP + r * 128;
    const float* qh = &sQ[h * 128];
    float d = 0.f;
#pragma unroll
    for (int k8 = 0; k8 < 16; ++k8) {
      int c8 = (k8 * 8) ^ sw;
      s8v v = *(const s8v*)(rowp + c8);
#pragma unroll
      for (int j = 0; j < 8; ++j) d += b2f((u16)v[j]) * qh[c8 + j];
    }
    float e = d + sCh[h] + sEr[h];
    sAl[h * 128 + r] = (e > 0.f) ? e : 0.2f * e;
  }
  __syncthreads();

  if (t < 192) {
    int h = t >> 6, ll = t & 63;
    float v0 = sAl[h * 128 + ll], v1 = sAl[h * 128 + 64 + ll];
    float m = fmaxf(v0, v1);
    for (int off = 32; off > 0; off >>= 1) m = fmaxf(m, __shfl_xor(m, off));
    float x0 = __expf(v0 - m), x1 = __expf(v1 - m);
    float s = x0 + x1;
    for (int off = 32; off > 0; off >>= 1) s += __shfl_xor(s, off);
    float inv = 1.0f / s;
    sAl[h * 128 + ll] = x0 * inv;
    sAl[h * 128 + 64 + ll] = x1 * inv;
  }
  __syncthreads();

  if (t < 384) {
    int hh = t >> 7, c = t & 127;
    int sw = (c & 7) << 3;
    const u16* rowp = sPt + c * 128;
    const float* al = &sAl[hh * 128];
    float s = 0.f;
#pragma unroll
    for (int k8 = 0; k8 < 16; ++k8) {
      int r8 = (k8 * 8) ^ sw;
      s8v v = *(const s8v*)(rowp + r8);
#pragma unroll
      for (int j = 0; j < 8; ++j) s += b2f((u16)v[j]) * al[r8 + j];
    }
    pooled[((size_t)b * 3 + hh) * 128 + c] = s;
  }
  __syncthreads();

  // ---- fused mfn (bf16 out) ----
  float hv = 0.f, pv = 0.f;
  if (t < 128) {
    hv = hrs[base + t];
    pv = sPool[t] * (1.0f / 128.0f);
    sQ[t] = hv * hv + pv * pv;
  }
  __syncthreads();
  if (t < 64) {
    float v = sQ[t] + sQ[t + 64];
    for (int off = 32; off > 0; off >>= 1) v += __shfl_xor(v, off);
    if (t == 0) sQ[0] = rsqrtf(v);
  }
  __syncthreads();
  if (t < 128) {
    float rn = sQ[0];
    mfnb[b * 256 + t] = f2b(hv * rn);
    mfnb[b * 256 + 128 + t] = f2b(pv * rn);
  }
}

// ===================== med via MFMA + fused row-count =====================
__global__ void __launch_bounds__(256) k_med(const u16* __restrict__ mfnb,
                                             const float* __restrict__ T0p,
                                             float* __restrict__ med,
                                             int* __restrict__ rowcnt) {
  __shared__ u16 sA[32 * 256];
  __shared__ u16 sB[32 * 256];
  int bi = blockIdx.x >> 4, bj = blockIdx.x & 15;
  int t = threadIdx.x;
  const uint4* srcA = (const uint4*)(mfnb + (size_t)bi * 32 * 256);
  const uint4* srcB = (const uint4*)(mfnb + (size_t)bj * 32 * 256);
  for (int g = t; g < 1024; g += 256) {
    int r = g >> 5, blk = g & 31;
    int db = (blk & 24) | ((blk ^ (r & 7)) & 7);
    uint4 va = srcA[g];
    uint4 vb = srcB[g];
    *(uint4*)(sA + r * 256 + db * 8) = va;
    *(uint4*)(sB + r * 256 + db * 8) = vb;
  }
  __syncthreads();
  int l = t & 63, w = t >> 6;
  int wr = w >> 1, wc = w & 1;
  int arow = wr * 16 + (l & 15);
  int brow = wc * 16 + (l & 15);
  int kblk = (l >> 4) * 8;
  f32x4 acc = {0.f, 0.f, 0.f, 0.f};
#pragma unroll
  for (int ks = 0; ks < 8; ++ks) {
    int kc = ks * 32 + kblk;
    s8v a = *(const s8v*)(sA + arow * 256 + (kc ^ ((arow & 7) << 3)));
    s8v bb = *(const s8v*)(sB + brow * 256 + (kc ^ ((brow & 7) << 3)));
    acc = __builtin_amdgcn_mfma_f32_16x16x32_bf16(a, bb, acc, 0, 0, 0);
  }
  int row0 = bi * 32 + wr * 16 + (l >> 4) * 4;
  int col = bj * 32 + wc * 16 + (l & 15);
  float T0 = *T0p;
  int cnt4[4];
#pragma unroll
  for (int rg = 0; rg < 4; ++rg) {
    float m = (acc[rg] + 1.0f) * 0.5f;
    med[(size_t)(row0 + rg) * 512 + col] = m;
    cnt4[rg] = (m >= T0 || (row0 + rg) == col) ? 1 : 0;
  }
#pragma unroll
  for (int off = 1; off < 16; off <<= 1) {
#pragma unroll
    for (int rg = 0; rg < 4; ++rg) cnt4[rg] += __shfl_xor(cnt4[rg], off);
  }
  if ((l & 15) == 0) {
#pragma unroll
    for (int rg = 0; rg < 4; ++rg) atomicAdd(&rowcnt[row0 + rg], cnt4[rg]);
  }
}

// ===================== slim epilogue: sparse Aagg + folded 768->16 dot =====================
__global__ void __launch_bounds__(256) k_epilogue(
    const float* __restrict__ med, const float* __restrict__ T0p,
    const int* __restrict__ rowcnt, const float* __restrict__ hrs,
    const float* __restrict__ pool, const float* __restrict__ pooled,
    const float* __restrict__ Afold, const float* __restrict__ bias_out,
    float* __restrict__ out) {
  __shared__ float sMedRow[512];
  __shared__ float sIn[6][128];
  __shared__ float sRed[16][16];
  __shared__ int sNbr[64];
  __shared__ float sDw[64];
  __shared__ int sNnz;
  int i = blockIdx.x, t = threadIdx.x;
  float T0 = *T0p;

  for (int j = t; j < 512; j += 256) sMedRow[j] = med[(size_t)i * 512 + j];
  if (t < 128) sIn[0][t] = hrs[i * 128 + t];
  for (int k = t; k < 384; k += 256) sIn[3 + (k >> 7)][k & 127] = pooled[(size_t)i * 384 + k];
  __syncthreads();

  if (t < 64) {
    int cnt = 0, flags = 0;
#pragma unroll
    for (int k = 0; k < 8; ++k) {
      int j = t * 8 + k;
      if (sMedRow[j] >= T0 || j == i) {
        flags |= 1 << k;
        ++cnt;
      }
    }
    int off = cnt;
    for (int d = 1; d < 64; d <<= 1) {
      int v = __shfl_up(off, d);
      if (t >= d) off += v;
    }
    off -= cnt;
    int pos = off;
#pragma unroll
    for (int k = 0; k < 8; ++k)
      if (flags & (1 << k)) {
        int j = t * 8 + k;
        if (pos < 64) {
          sNbr[pos] = j;
          sDw[pos] = rsqrtf((float)rowcnt[j]);
        }
        ++pos;
      }
    if (t == 63) sNnz = off + cnt;
  }
  __syncthreads();

  {
    int half = t >> 7, c = t & 127;
    float di = rsqrtf((float)rowcnt[i]);
    const float* srcm = half ? pool : hrs;
    float acc = 0.f;
    int nnz = sNnz;
    if (nnz <= 64) {
      for (int n = 0; n < nnz; ++n) acc += sDw[n] * srcm[sNbr[n] * 128 + c];
    } else {
      for (int j = 0; j < 512; ++j)
        if (sMedRow[j] >= T0 || j == i) acc += rsqrtf((float)rowcnt[j]) * srcm[j * 128 + c];
    }
    sIn[1 + half][c] = acc * di;
  }
  __syncthreads();

  {
    int o = t >> 4, chunk = t & 15;
    int c0 = chunk * 8;
    float acc = 0.f;
#pragma unroll
    for (int m = 0; m < 6; ++m) {
      const float* A = Afold + m * 2048;
      const float* xm = sIn[m];
#pragma unroll
      for (int k = 0; k < 8; ++k) acc += xm[c0 + k] * A[(c0 + k) * 16 + o];
    }
    sRed[o][chunk] = acc;
  }
  __syncthreads();
  if (t < 16) {
    float acc = bias_out[t];
#pragma unroll
    for (int j = 0; j < 16; ++j) acc += sRed[t][j];
    out[i * 16 + t] = acc;
  }
}

// ===================== host =====================
extern "C" void kernel_launch(void* const* d_in, const int* in_sizes, int n_in,
                              void* d_out, int out_size, void* d_ws, size_t ws_size,
                              hipStream_t stream) {
  const float* poi_x = (const float*)d_in[0];
  const float* img = (const float*)d_in[1];
  const int* edges = (const int*)d_in[2];
  const float* T0p = (const float*)d_in[4];
  const float* W1 = (const float*)d_in[5];
  const float* b1 = (const float*)d_in[6];
  const float* W2 = (const float*)d_in[7];
  const float* b2 = (const float*)d_in[8];
  const float* Whrs = (const float*)d_in[9];
  const float* bhrs = (const float*)d_in[10];
  const float* Wph = (const float*)d_in[11];
  const float* bph = (const float*)d_in[12];
  const float* Wpp = (const float*)d_in[13];
  const float* bpp = (const float*)d_in[14];
  const float* Wg_in = (const float*)d_in[15];
  const float* al_in = (const float*)d_in[16];
  const float* ar_in = (const float*)d_in[17];
  const float* bg_in = (const float*)d_in[18];
  const float* Wg_w = (const float*)d_in[19];
  const float* bg_w = (const float*)d_in[22];
  const float* Wh1 = (const float*)d_in[23];
  const float* bh1 = (const float*)d_in[24];
  const float* Wp1 = (const float*)d_in[25];
  const float* bp1 = (const float*)d_in[26];
  const float* Wfc = (const float*)d_in[27];
  const float* bfc = (const float*)d_in[28];

  const int* esrc = edges;
  const int* edst = edges + EE;

  char* ws = (char*)d_ws;
  size_t off = 0;
  auto alloc = [&](size_t nbytes) -> char* {
    char* p = ws + off;
    off += (nbytes + 255) & ~(size_t)255;
    return p;
  };
  uint8_t* Sg8 = (uint8_t*)alloc((size_t)NN * 128);
  u16* w1t = (u16*)alloc(8192 * 2);
  u16* w2t = (u16*)alloc(16384 * 2);
  float* hrs = (float*)alloc(512 * 128 * 4);
  float* er = (float*)alloc(512 * 3 * 4);
  float* wv = (float*)alloc(384 * 4);
  float* q = (float*)alloc(384 * 4);
  float* chv = (float*)alloc(16);
  float* B0 = (float*)alloc(2048 * 4);
  float* Chb = (float*)alloc(3 * 2048 * 4);
  float* D0 = (float*)alloc(128 * 4);
  float* Evec = (float*)alloc(128 * 4);
  float* Afold = (float*)alloc(6 * 2048 * 4);
  float* bias_out = (float*)alloc(16 * 4);
  float* pool = (float*)alloc(512 * 128 * 4);
  float* pooled = (float*)alloc((size_t)1536 * 128 * 4);
  u16* mfnb = (u16*)alloc(512 * 256 * 2);
  int* rowcnt = (int*)alloc(512 * 4);

  float* out = (float*)d_out;
  float* med = out + 512 * 16;

  hipMemsetAsync(Sg8, 0, (size_t)NN * 128, stream);

  size_t dynf = 152096;
  hipFuncSetAttribute((const void*)k_gcn_fused, hipFuncAttributeMaxDynamicSharedMemorySize,
                      (int)dynf);

  k_prep_graph<<<2180, 256, 0, stream>>>(esrc, edst, (uint32_t*)Sg8, W1, W2, Wg_in, al_in,
                                         ar_in, Wpp, bpp, w1t, w2t, wv, q, chv, Wg_w, Wfc, bph,
                                         bg_in, B0, Chb, D0, Evec, rowcnt);
  k_fold2<<<49, 256, 0, stream>>>(Wph, Wh1, Wp1, Wpp, Wfc, bfc, bh1, bp1, bg_w, B0, Chb, D0,
                                  Evec, Afold, bias_out);
  k_hrs<<<256, 1024, 0, stream>>>(img, Whrs, bhrs, Wph, bph, wv, hrs, er);
  k_gcn_fused<<<512, 1024, dynf, stream>>>(poi_x, b1, b2, Sg8, q, chv, er, hrs, w1t, w2t, pool,
                                           pooled, mfnb);
  k_med<<<256, 256, 0, stream>>>(mfnb, T0p, med, rowcnt);
  k_epilogue<<<512, 256, 0, stream>>>(med, T0p, rowcnt, hrs, pool, pooled, Afold, bias_out,
                                      out);

  (void)in_sizes; (void)n_in; (void)out_size; (void)ws_size;
}

// Round 16
// 137.320 us; speedup vs baseline: 1.5376x; 1.0309x over previous
//
#include <hip/hip_runtime.h>
#include <stdint.h>

#define NN 65536
#define EE 524288
#define BB 512

typedef unsigned short u16;
typedef __attribute__((ext_vector_type(8))) short s8v;    // 8 bf16 (4 VGPRs)
typedef __attribute__((ext_vector_type(4))) float f32x4;  // MFMA acc

__device__ __forceinline__ u16 f2b(float f) {
  union { float f; uint32_t u; } a{f};
  uint32_t r = a.u + 0x7fff + ((a.u >> 16) & 1);
  return (u16)(r >> 16);
}
__device__ __forceinline__ float b2f(u16 v) {
  union { uint32_t u; float f; } a{(uint32_t)v << 16};
  return a.f;
}
__device__ __forceinline__ int swz128(int r, int c) { return r * 128 + (c ^ ((r & 7) << 3)); }
__device__ __forceinline__ int swz64(int r, int c) { return r * 64 + (c ^ ((r & 7) << 3)); }

// ===================== merged: scatterS + weight prep + fold1 + rowcnt zero =====================
__global__ void __launch_bounds__(256) k_prep_graph(
    const int* __restrict__ src, const int* __restrict__ dst, uint32_t* __restrict__ Sg,
    const float* __restrict__ W1, const float* __restrict__ W2,
    const float* __restrict__ Wg_in, const float* __restrict__ al_in,
    const float* __restrict__ ar_in, const float* __restrict__ Wpp,
    const float* __restrict__ bpp, u16* __restrict__ w1t, u16* __restrict__ w2t,
    float* __restrict__ wv, float* __restrict__ q, float* __restrict__ ch,
    const float* __restrict__ Wg_w, const float* __restrict__ Wfc,
    const float* __restrict__ bph, const float* __restrict__ bg_in,
    float* __restrict__ B0, float* __restrict__ Ch, float* __restrict__ D0,
    float* __restrict__ Evec, int* __restrict__ rowcnt) {
  int blk = blockIdx.x, t = threadIdx.x;
  if (blk < 2048) {
    int e = blk * 256 + t;
    int s = src[e] & 127, d = dst[e];
    atomicAdd(&Sg[((size_t)d * 128 + s) >> 2], 1u << ((s & 3) * 8));
  } else if (blk < 2144) {
    int i = (blk - 2048) * 256 + t;  // 24576
    if (i < 8192) {
      int n = i >> 6, k = i & 63;
      w1t[i] = f2b(W1[k * 128 + n]);
    } else {
      int j = i - 8192;
      int n = j >> 7, k = j & 127;
      w2t[j] = f2b(W2[k * 128 + n]);
    }
  } else if (blk == 2144) {
    __shared__ float su[384];
    for (int i = t; i < 384; i += 256) {
      int h = i >> 7, k = i & 127;
      float s = 0.f, sw = 0.f;
#pragma unroll 4
      for (int c = 0; c < 128; ++c) {
        float g = Wg_in[k * 384 + h * 128 + c];
        s += g * al_in[h * 128 + c];
        sw += g * ar_in[h * 128 + c];
      }
      su[i] = s;
      wv[i] = sw;
    }
    __syncthreads();
    for (int i = t; i < 384; i += 256) {
      int h = i >> 7, j = i & 127;
      float s = 0.f;
#pragma unroll 4
      for (int k = 0; k < 128; ++k) s += Wpp[j * 128 + k] * su[h * 128 + k];
      q[i] = s;
    }
    if (t < 3) {
      float s = 0.f;
#pragma unroll 4
      for (int k = 0; k < 128; ++k) s += bpp[k] * su[t * 128 + k];
      ch[t] = s;
    }
  } else if (blk < 2153) {
    int bb = blk - 2145;
    __shared__ float sW[2048];
    for (int i = t; i < 2048; i += 256) sW[i] = Wfc[i];
    __syncthreads();
    int m = bb * 16 + (t >> 4), o = t & 15;
    const float* wr = Wg_w + (size_t)m * 384;
    float acc = 0.f;
#pragma unroll 4
    for (int j = 0; j < 128; ++j) {
      float g = (wr[j] + wr[128 + j] + wr[256 + j]) * (1.0f / 3.0f);
      acc += g * sW[j * 16 + o];
    }
    B0[m * 16 + o] = acc;
  } else if (blk < 2177) {
    int bb = blk - 2153;
    int h = bb >> 3, rc = bb & 7;
    __shared__ float sW[2048];
    for (int i = t; i < 2048; i += 256) sW[i] = Wfc[256 * 16 + i];
    __syncthreads();
    int m = rc * 16 + (t >> 4), o = t & 15;
    const float* wr = Wg_in + (size_t)m * 384 + h * 128;
    float acc = 0.f;
#pragma unroll 4
    for (int c = 0; c < 128; ++c) acc += wr[c] * sW[c * 16 + o];
    Ch[((size_t)h * 128 + m) * 16 + o] = acc;
  } else if (blk == 2177) {
    __shared__ float sD[2][128];
    int j = t & 127, half = t >> 7;
    int k0 = half * 64;
    float acc = 0.f;
#pragma unroll 4
    for (int k = k0; k < k0 + 64; ++k) {
      float g = (Wg_w[k * 384 + j] + Wg_w[k * 384 + 128 + j] + Wg_w[k * 384 + 256 + j]) *
                (1.0f / 3.0f);
      acc += bph[k] * g;
    }
    sD[half][j] = acc;
    __syncthreads();
    if (t < 128) D0[t] = sD[0][t] + sD[1][t];
  } else if (blk == 2178) {
    __shared__ float sE[2][128];
    int j = t & 127, half = t >> 7;
    int m0 = half * 64;
    float e = 0.f;
    for (int h = 0; h < 3; ++h) {
#pragma unroll 4
      for (int m = m0; m < m0 + 64; ++m) e += bpp[m] * Wg_in[m * 384 + h * 128 + j];
    }
    sE[half][j] = e;
    __syncthreads();
    if (t < 128) {
      float g0in = (bg_in[t] + bg_in[128 + t] + bg_in[256 + t]) * (1.0f / 3.0f);
      Evec[t] = (sE[0][t] + sE[1][t]) * (1.0f / 3.0f) + g0in;
    }
  } else {
    if (t < 256) {
      rowcnt[t] = 0;
      rowcnt[t + 256] = 0;
    }
  }
}

// ===================== hrs encoder + er (blocks 0..255) + fold2 (blocks 256..304) ===========
__global__ void __launch_bounds__(1024) k_hrsfold(
    const float* __restrict__ img, const float* __restrict__ Whrs,
    const float* __restrict__ bhrs, const float* __restrict__ Wph,
    const float* __restrict__ bph, const float* __restrict__ wv, float* __restrict__ hrs,
    float* __restrict__ er, const float* __restrict__ Wh1, const float* __restrict__ Wp1,
    const float* __restrict__ Wpp, const float* __restrict__ Wfc,
    const float* __restrict__ bfc, const float* __restrict__ bh1,
    const float* __restrict__ bp1, const float* __restrict__ bg_w,
    const float* __restrict__ B0, const float* __restrict__ Ch, const float* __restrict__ D0,
    const float* __restrict__ Evec, float* __restrict__ Afold, float* __restrict__ bias_out) {
  __shared__ float sI[4096];
  __shared__ float sRed[8][128];
  __shared__ float sHrs[2][128];
  __shared__ float sPh[2][128];
  __shared__ float sW[2048];
  __shared__ float sRed2[16][16];
  int t = threadIdx.x;
  if (blockIdx.x < 256) {
    // ---- hrs path ----
    int r0 = blockIdx.x * 2;
    const float4* gsrc = (const float4*)(img + (size_t)r0 * 2048);
    float4* ldst = (float4*)sI;
    ldst[t] = gsrc[t];
    __syncthreads();
    int c = t & 127, g = t >> 7;
    int row = g & 1, ks = g >> 1;
    const float* s = sI + row * 2048 + ks * 512;
    const float* W = Whrs + (size_t)(ks * 512) * 128 + c;
    float a0 = 0.f, a1 = 0.f, a2 = 0.f, a3 = 0.f;
    for (int k = 0; k < 512; k += 4) {
      a0 += s[k] * W[(size_t)k * 128];
      a1 += s[k + 1] * W[(size_t)(k + 1) * 128];
      a2 += s[k + 2] * W[(size_t)(k + 2) * 128];
      a3 += s[k + 3] * W[(size_t)(k + 3) * 128];
    }
    sRed[g][c] = (a0 + a1) + (a2 + a3);
    __syncthreads();
    if (t < 256) {
      int rr = t >> 7, cc = t & 127;
      float v = sRed[rr][cc] + sRed[rr + 2][cc] + sRed[rr + 4][cc] + sRed[rr + 6][cc] + bhrs[cc];
      hrs[(r0 + rr) * 128 + cc] = v;
      sHrs[rr][cc] = v;
    }
    __syncthreads();
    if (t < 256) {
      int rr = t >> 7, cc = t & 127;
      float acc = bph[cc];
#pragma unroll 4
      for (int k = 0; k < 128; ++k) acc += sHrs[rr][k] * Wph[k * 128 + cc];
      sPh[rr][cc] = acc;
    }
    __syncthreads();
    if (t < 6) {
      int rr = t / 3, h = t % 3;
      float s2 = 0.f;
#pragma unroll 4
      for (int k = 0; k < 128; ++k) s2 += sPh[rr][k] * wv[h * 128 + k];
      er[(r0 + rr) * 3 + h] = s2;
    }
  } else if (blockIdx.x < 304) {
    // ---- fold2 matrices ----
    int blk = blockIdx.x - 256;
    int mat = blk >> 3, rc = blk & 7;
    if (mat == 0)
      for (int i = t; i < 2048; i += 1024) sW[i] = B0[i];
    else if (mat == 1)
      for (int i = t; i < 2048; i += 1024) sW[i] = Wfc[384 * 16 + i];
    else if (mat == 2)
      for (int i = t; i < 2048; i += 1024) sW[i] = Wfc[128 * 16 + i];
    else
      for (int i = t; i < 2048; i += 1024) sW[i] = Ch[(size_t)(mat - 3) * 2048 + i];
    __syncthreads();
    if (t < 256) {
      int k = rc * 16 + (t >> 4), o = t & 15;
      const float* L = (mat == 0) ? Wph : (mat == 1) ? Wh1 : (mat == 2) ? Wp1 : Wpp;
      float scale = (mat >= 3) ? (1.0f / 3.0f) : 1.0f;
      const float* lr = L + (size_t)k * 128;
      float acc = 0.f;
#pragma unroll 4
      for (int m = 0; m < 128; ++m) acc += lr[m] * sW[m * 16 + o];
      Afold[(size_t)mat * 2048 + k * 16 + o] = acc * scale;
    }
  } else {
    // ---- fold2 bias ----
    if (t < 256) {
      int o = t & 15, chunk = t >> 4;
      int j0 = chunk * 8;
      float acc = 0.f;
#pragma unroll
      for (int jj = 0; jj < 8; ++jj) {
        int j = j0 + jj;
        float g0w = (bg_w[j] + bg_w[128 + j] + bg_w[256 + j]) * (1.0f / 3.0f);
        acc += (D0[j] + g0w) * Wfc[j * 16 + o];
        acc += bp1[j] * Wfc[(128 + j) * 16 + o];
        acc += Evec[j] * Wfc[(256 + j) * 16 + o];
        acc += bh1[j] * Wfc[(384 + j) * 16 + o];
      }
      sRed2[o][chunk] = acc;
    }
    __syncthreads();
    if (t < 16) {
      float a = bfc[t];
#pragma unroll
      for (int c = 0; c < 16; ++c) a += sRed2[t][c];
      bias_out[t] = a;
    }
  }
}

// ===================== FUSED GCN via dense S' + MFMA (1024 thr, parallel tails) ====
__global__ void __launch_bounds__(1024) k_gcn_fused(
    const float* __restrict__ x, const float* __restrict__ b1, const float* __restrict__ b2,
    const uint8_t* __restrict__ Sg8, const float* __restrict__ q, const float* __restrict__ ch,
    const float* __restrict__ er, const float* __restrict__ hrs,
    const u16* __restrict__ w1t, const u16* __restrict__ w2t, float* __restrict__ poi_pool,
    float* __restrict__ pooled, u16* __restrict__ mfnb) {
  extern __shared__ char sm[];
  u16* sS = (u16*)sm;
  u16* sB2 = (u16*)(sm + 32768);
  u16* sPt = (u16*)(sm + 32768);
  u16* sXt = (u16*)(sm + 65536);
  u16* sAgg1 = (u16*)(sm + 81920);
  u16* sW1t = (u16*)(sm + 98304);
  float* sXrm = (float*)(sm + 114688);
  u16* sW2t = (u16*)(sm + 114688);
  u16* sAgg2 = (u16*)(sm + 65536);
  u16* sP = (u16*)sm;
  float* sNorm = (float*)(sm + 147968);
  float* sQ = (float*)(sm + 148480);
  float* sAl = (float*)(sm + 150016);
  float* sPool = (float*)(sm + 151552);
  float* sEr = (float*)(sm + 152064);
  float* sCh = (float*)(sm + 152080);
  float* sElp = (float*)(sm + 152320);    // [6][128] partials (el, then pooled)
  float* sPoolp = (float*)(sm + 155392);  // [2][128] pool partials

  int b = blockIdx.x, t = threadIdx.x;
  int base = b << 7;
  int l = t & 63, w = t >> 6;
  int wm = w & 7, wn = w >> 3;
  const uint8_t* Sgb = Sg8 + (size_t)base * 128;

  // ---- phase 0: single Sg read (kept in regs) + shuffle row-sums -> norms; stage rest ----
  int rown = t >> 3, q8 = t & 7;
  uint4 cw = *(const uint4*)(Sgb + rown * 128 + q8 * 16);
  {
    uint32_t words[4] = {cw.x, cw.y, cw.z, cw.w};
    uint32_t bs = 0;
#pragma unroll
    for (int p = 0; p < 4; ++p)
      bs += (words[p] & 0xff) + ((words[p] >> 8) & 0xff) + ((words[p] >> 16) & 0xff) +
            (words[p] >> 24);
    bs += __shfl_xor((int)bs, 1);
    bs += __shfl_xor((int)bs, 2);
    bs += __shfl_xor((int)bs, 4);
    if ((t & 7) == 0) sNorm[rown] = rsqrtf((float)bs + 1.0f);
  }
  for (int i = t; i < 8192; i += 1024) {
    int s = i >> 6, f = i & 63;
    sXrm[s * 65 + f] = x[(size_t)(base + s) * 64 + f];
  }
  {
    int n = t >> 3, blk = t & 7;
    *(uint4*)(sW1t + n * 64 + ((blk ^ (n & 7)) << 3)) = ((const uint4*)w1t)[t];
  }
  if (t < 384) sQ[t] = q[t];
  if (t < 3) {
    sEr[t] = er[b * 3 + t];
    sCh[t] = ch[t];
  }
  __syncthreads();

  // ---- phase 1: S' from retained counts + X transpose->bf16 ----
  {
    int r = rown;
    float nr = sNorm[r];
    int sw = (r & 7) << 3;
    uint32_t words[4] = {cw.x, cw.y, cw.z, cw.w};
#pragma unroll
    for (int qd = 0; qd < 4; ++qd) {
      uint32_t wd = words[qd];
#pragma unroll
      for (int p = 0; p < 4; p += 2) {
        int s0 = q8 * 16 + qd * 4 + p;
        float v0 = ((float)((wd >> (p * 8)) & 0xff) + (r == s0 ? 1.f : 0.f)) * nr * sNorm[s0];
        float v1 =
            ((float)((wd >> (p * 8 + 8)) & 0xff) + (r == s0 + 1 ? 1.f : 0.f)) * nr * sNorm[s0 + 1];
        uint32_t pk = (uint32_t)f2b(v0) | ((uint32_t)f2b(v1) << 16);
        *(uint32_t*)(sS + r * 128 + (s0 ^ sw)) = pk;
      }
    }
  }
  for (int i = t; i < 4096; i += 1024) {
    int f = i >> 6, s = (i & 63) * 2;
    float v0 = sXrm[s * 65 + f] * sNorm[s];
    float v1 = sXrm[(s + 1) * 65 + f] * sNorm[s + 1];
    uint32_t pk = (uint32_t)f2b(v0) | ((uint32_t)f2b(v1) << 16);
    *(uint32_t*)(sXt + (f * 128 + (s ^ ((f & 7) << 3)))) = pk;
  }
  __syncthreads();

  int mrow = wm * 16 + (l & 15);
  int kblk = (l >> 4) * 8;
  int rbase = wm * 16 + (l >> 4) * 4;

  // ---- phase 3: agg1 = S' @ X (nt-split); stage W2t ----
  {
    s8v a4[4];
#pragma unroll
    for (int ks = 0; ks < 4; ++ks) a4[ks] = *(const s8v*)(sS + swz128(mrow, ks * 32 + kblk));
#pragma unroll
    for (int j = 0; j < 2; ++j) {
      int nt = wn * 2 + j;
      f32x4 acc = {0.f, 0.f, 0.f, 0.f};
      int cg = nt * 16 + (l & 15);
#pragma unroll
      for (int ks = 0; ks < 4; ++ks)
        acc = __builtin_amdgcn_mfma_f32_16x16x32_bf16(
            a4[ks], *(const s8v*)(sXt + swz128(cg, ks * 32 + kblk)), acc, 0, 0, 0);
#pragma unroll
      for (int rg = 0; rg < 4; ++rg) sAgg1[swz64(rbase + rg, cg)] = f2b(acc[rg]);
    }
  }
  for (int g = t; g < 2048; g += 1024) {
    int n = g >> 4, blk = g & 15;
    *(uint4*)(sW2t + n * 128 + ((blk ^ (n & 7)) << 3)) = ((const uint4*)w2t)[g];
  }
  __syncthreads();

  // ---- phase 4: h1 = relu(agg1 @ W1 + b1) -> h1^T (nt-split) ----
  {
    s8v a2[2];
#pragma unroll
    for (int ks = 0; ks < 2; ++ks) a2[ks] = *(const s8v*)(sAgg1 + swz64(mrow, ks * 32 + kblk));
#pragma unroll
    for (int j = 0; j < 4; ++j) {
      int nt = wn * 4 + j;
      int cg = nt * 16 + (l & 15);
      float bv = b1[cg];
      f32x4 acc = {bv, bv, bv, bv};
#pragma unroll
      for (int ks = 0; ks < 2; ++ks)
        acc = __builtin_amdgcn_mfma_f32_16x16x32_bf16(
            a2[ks], *(const s8v*)(sW1t + swz64(cg, ks * 32 + kblk)), acc, 0, 0, 0);
      u16 h0 = f2b(fmaxf(acc[0], 0.f)), h1v = f2b(fmaxf(acc[1], 0.f));
      u16 h2 = f2b(fmaxf(acc[2], 0.f)), h3 = f2b(fmaxf(acc[3], 0.f));
      uint2 pk;
      pk.x = (uint32_t)h0 | ((uint32_t)h1v << 16);
      pk.y = (uint32_t)h2 | ((uint32_t)h3 << 16);
      *(uint2*)(sB2 + swz128(cg, rbase)) = pk;
    }
  }
  __syncthreads();

  // ---- phase 5: agg2 = S' @ h1 (nt-split) ----
  {
    s8v a4[4];
#pragma unroll
    for (int ks = 0; ks < 4; ++ks) a4[ks] = *(const s8v*)(sS + swz128(mrow, ks * 32 + kblk));
#pragma unroll
    for (int j = 0; j < 4; ++j) {
      int nt = wn * 4 + j;
      f32x4 acc = {0.f, 0.f, 0.f, 0.f};
      int cg = nt * 16 + (l & 15);
#pragma unroll
      for (int ks = 0; ks < 4; ++ks)
        acc = __builtin_amdgcn_mfma_f32_16x16x32_bf16(
            a4[ks], *(const s8v*)(sB2 + swz128(cg, ks * 32 + kblk)), acc, 0, 0, 0);
#pragma unroll
      for (int rg = 0; rg < 4; ++rg) sAgg2[swz128(rbase + rg, cg)] = f2b(acc[rg]);
    }
  }
  __syncthreads();

  // ---- phase 6: poi = agg2 @ W2 + b2 -> sP + sPt (nt-split) ----
  {
    s8v a4[4];
#pragma unroll
    for (int ks = 0; ks < 4; ++ks) a4[ks] = *(const s8v*)(sAgg2 + swz128(mrow, ks * 32 + kblk));
#pragma unroll
    for (int j = 0; j < 4; ++j) {
      int nt = wn * 4 + j;
      int cg = nt * 16 + (l & 15);
      float bv = b2[cg];
      f32x4 acc = {bv, bv, bv, bv};
#pragma unroll
      for (int ks = 0; ks < 4; ++ks)
        acc = __builtin_amdgcn_mfma_f32_16x16x32_bf16(
            a4[ks], *(const s8v*)(sW2t + swz128(cg, ks * 32 + kblk)), acc, 0, 0, 0);
      u16 p0 = f2b(acc[0]), p1 = f2b(acc[1]), p2 = f2b(acc[2]), p3 = f2b(acc[3]);
#pragma unroll
      for (int rg = 0; rg < 4; ++rg)
        sP[swz128(rbase + rg, cg)] = (rg == 0) ? p0 : (rg == 1) ? p1 : (rg == 2) ? p2 : p3;
      uint2 pk;
      pk.x = (uint32_t)p0 | ((uint32_t)p1 << 16);
      pk.y = (uint32_t)p2 | ((uint32_t)p3 << 16);
      *(uint2*)(sPt + swz128(cg, rbase)) = pk;
    }
  }
  __syncthreads();

  // ---- tail A: pool partials (t<256) || el partials (t in 256..1023, 768 tasks) ----
  if (t < 256) {
    int c = t & 127, kh = t >> 7;
    float s = 0.f;
    const u16* rowp = sPt + c * 128;
    int sw = (c & 7) << 3;
#pragma unroll
    for (int k8 = kh * 8; k8 < kh * 8 + 8; ++k8) {
      s8v v = *(const s8v*)(rowp + ((k8 * 8) ^ sw));
#pragma unroll
      for (int j = 0; j < 8; ++j) s += b2f((u16)v[j]);
    }
    sPoolp[kh * 128 + c] = s;
  } else {
    int task = t - 256;
    int r = task & 127, hk = task >> 7;  // hk 0..5
    int h = hk >> 1, kh = hk & 1;
    int sw = (r & 7) << 3;
    const u16* rowp = sP + r * 128;
    const float* qh = &sQ[h * 128];
    float d = 0.f;
#pragma unroll
    for (int k8 = kh * 8; k8 < kh * 8 + 8; ++k8) {
      int c8 = (k8 * 8) ^ sw;
      s8v v = *(const s8v*)(rowp + c8);
#pragma unroll
      for (int j = 0; j < 8; ++j) d += b2f((u16)v[j]) * qh[c8 + j];
    }
    sElp[hk * 128 + r] = d;
  }
  __syncthreads();

  // ---- tail B: combine pool + el; softmax prep ----
  if (t < 128) {
    float s = sPoolp[t] + sPoolp[128 + t];
    sPool[t] = s;
    poi_pool[b * 128 + t] = s * (1.0f / 128.0f);
  }
  if (t >= 512 && t < 896) {
    int tt = t - 512;
    int h = tt >> 7, r = tt & 127;
    float e = sElp[h * 256 + r] + sElp[h * 256 + 128 + r] + sCh[h] + sEr[h];
    sAl[h * 128 + r] = (e > 0.f) ? e : 0.2f * e;
  }
  __syncthreads();

  if (t < 192) {
    int h = t >> 6, ll = t & 63;
    float v0 = sAl[h * 128 + ll], v1 = sAl[h * 128 + 64 + ll];
    float m = fmaxf(v0, v1);
    for (int off = 32; off > 0; off >>= 1) m = fmaxf(m, __shfl_xor(m, off));
    float x0 = __expf(v0 - m), x1 = __expf(v1 - m);
    float s = x0 + x1;
    for (int off = 32; off > 0; off >>= 1) s += __shfl_xor(s, off);
    float inv = 1.0f / s;
    sAl[h * 128 + ll] = x0 * inv;
    sAl[h * 128 + 64 + ll] = x1 * inv;
  }
  __syncthreads();

  // ---- tail C: pooled partials (768 tasks) ----
  if (t < 768) {
    int c = t & 127, hk = t >> 7;  // hk 0..5
    int hh = hk >> 1, kh = hk & 1;
    int sw = (c & 7) << 3;
    const u16* rowp = sPt + c * 128;
    const float* al = &sAl[hh * 128];
    float s = 0.f;
#pragma unroll
    for (int k8 = kh * 8; k8 < kh * 8 + 8; ++k8) {
      int r8 = (k8 * 8) ^ sw;
      s8v v = *(const s8v*)(rowp + r8);
#pragma unroll
      for (int j = 0; j < 8; ++j) s += b2f((u16)v[j]) * al[r8 + j];
    }
    sElp[hk * 128 + c] = s;
  }
  __syncthreads();

  if (t < 384) {
    int hh = t >> 7, c = t & 127;
    pooled[((size_t)b * 3 + hh) * 128 + c] = sElp[hh * 256 + c] + sElp[hh * 256 + 128 + c];
  }
  __syncthreads();

  // ---- fused mfn (bf16 out) ----
  float hv = 0.f, pv = 0.f;
  if (t < 128) {
    hv = hrs[base + t];
    pv = sPool[t] * (1.0f / 128.0f);
    sQ[t] = hv * hv + pv * pv;
  }
  __syncthreads();
  if (t < 64) {
    float v = sQ[t] + sQ[t + 64];
    for (int off = 32; off > 0; off >>= 1) v += __shfl_xor(v, off);
    if (t == 0) sQ[0] = rsqrtf(v);
  }
  __syncthreads();
  if (t < 128) {
    float rn = sQ[0];
    mfnb[b * 256 + t] = f2b(hv * rn);
    mfnb[b * 256 + 128 + t] = f2b(pv * rn);
  }
}

// ===================== med via MFMA + fused row-count =====================
__global__ void __launch_bounds__(256) k_med(const u16* __restrict__ mfnb,
                                             const float* __restrict__ T0p,
                                             float* __restrict__ med,
                                             int* __restrict__ rowcnt) {
  __shared__ u16 sA[32 * 256];
  __shared__ u16 sB[32 * 256];
  int bi = blockIdx.x >> 4, bj = blockIdx.x & 15;
  int t = threadIdx.x;
  const uint4* srcA = (const uint4*)(mfnb + (size_t)bi * 32 * 256);
  const uint4* srcB = (const uint4*)(mfnb + (size_t)bj * 32 * 256);
  for (int g = t; g < 1024; g += 256) {
    int r = g >> 5, blk = g & 31;
    int db = (blk & 24) | ((blk ^ (r & 7)) & 7);
    uint4 va = srcA[g];
    uint4 vb = srcB[g];
    *(uint4*)(sA + r * 256 + db * 8) = va;
    *(uint4*)(sB + r * 256 + db * 8) = vb;
  }
  __syncthreads();
  int l = t & 63, w = t >> 6;
  int wr = w >> 1, wc = w & 1;
  int arow = wr * 16 + (l & 15);
  int brow = wc * 16 + (l & 15);
  int kblk = (l >> 4) * 8;
  f32x4 acc = {0.f, 0.f, 0.f, 0.f};
#pragma unroll
  for (int ks = 0; ks < 8; ++ks) {
    int kc = ks * 32 + kblk;
    s8v a = *(const s8v*)(sA + arow * 256 + (kc ^ ((arow & 7) << 3)));
    s8v bb = *(const s8v*)(sB + brow * 256 + (kc ^ ((brow & 7) << 3)));
    acc = __builtin_amdgcn_mfma_f32_16x16x32_bf16(a, bb, acc, 0, 0, 0);
  }
  int row0 = bi * 32 + wr * 16 + (l >> 4) * 4;
  int col = bj * 32 + wc * 16 + (l & 15);
  float T0 = *T0p;
  int cnt4[4];
#pragma unroll
  for (int rg = 0; rg < 4; ++rg) {
    float m = (acc[rg] + 1.0f) * 0.5f;
    med[(size_t)(row0 + rg) * 512 + col] = m;
    cnt4[rg] = (m >= T0 || (row0 + rg) == col) ? 1 : 0;
  }
#pragma unroll
  for (int off = 1; off < 16; off <<= 1) {
#pragma unroll
    for (int rg = 0; rg < 4; ++rg) cnt4[rg] += __shfl_xor(cnt4[rg], off);
  }
  if ((l & 15) == 0) {
#pragma unroll
    for (int rg = 0; rg < 4; ++rg) atomicAdd(&rowcnt[row0 + rg], cnt4[rg]);
  }
}

// ===================== slim epilogue: sparse Aagg + folded 768->16 dot =====================
__global__ void __launch_bounds__(256) k_epilogue(
    const float* __restrict__ med, const float* __restrict__ T0p,
    const int* __restrict__ rowcnt, const float* __restrict__ hrs,
    const float* __restrict__ pool, const float* __restrict__ pooled,
    const float* __restrict__ Afold, const float* __restrict__ bias_out,
    float* __restrict__ out) {
  __shared__ float sMedRow[512];
  __shared__ float sIn[6][128];
  __shared__ float sRed[16][16];
  __shared__ int sNbr[64];
  __shared__ float sDw[64];
  __shared__ int sNnz;
  int i = blockIdx.x, t = threadIdx.x;
  float T0 = *T0p;

  for (int j = t; j < 512; j += 256) sMedRow[j] = med[(size_t)i * 512 + j];
  if (t < 128) sIn[0][t] = hrs[i * 128 + t];
  for (int k = t; k < 384; k += 256) sIn[3 + (k >> 7)][k & 127] = pooled[(size_t)i * 384 + k];
  __syncthreads();

  if (t < 64) {
    int cnt = 0, flags = 0;
#pragma unroll
    for (int k = 0; k < 8; ++k) {
      int j = t * 8 + k;
      if (sMedRow[j] >= T0 || j == i) {
        flags |= 1 << k;
        ++cnt;
      }
    }
    int off = cnt;
    for (int d = 1; d < 64; d <<= 1) {
      int v = __shfl_up(off, d);
      if (t >= d) off += v;
    }
    off -= cnt;
    int pos = off;
#pragma unroll
    for (int k = 0; k < 8; ++k)
      if (flags & (1 << k)) {
        int j = t * 8 + k;
        if (pos < 64) {
          sNbr[pos] = j;
          sDw[pos] = rsqrtf((float)rowcnt[j]);
        }
        ++pos;
      }
    if (t == 63) sNnz = off + cnt;
  }
  __syncthreads();

  {
    int half = t >> 7, c = t & 127;
    float di = rsqrtf((float)rowcnt[i]);
    const float* srcm = half ? pool : hrs;
    float acc = 0.f;
    int nnz = sNnz;
    if (nnz <= 64) {
      for (int n = 0; n < nnz; ++n) acc += sDw[n] * srcm[sNbr[n] * 128 + c];
    } else {
      for (int j = 0; j < 512; ++j)
        if (sMedRow[j] >= T0 || j == i) acc += rsqrtf((float)rowcnt[j]) * srcm[j * 128 + c];
    }
    sIn[1 + half][c] = acc * di;
  }
  __syncthreads();

  {
    int o = t >> 4, chunk = t & 15;
    int c0 = chunk * 8;
    float acc = 0.f;
#pragma unroll
    for (int m = 0; m < 6; ++m) {
      const float* A = Afold + m * 2048;
      const float* xm = sIn[m];
#pragma unroll
      for (int k = 0; k < 8; ++k) acc += xm[c0 + k] * A[(c0 + k) * 16 + o];
    }
    sRed[o][chunk] = acc;
  }
  __syncthreads();
  if (t < 16) {
    float acc = bias_out[t];
#pragma unroll
    for (int j = 0; j < 16; ++j) acc += sRed[t][j];
    out[i * 16 + t] = acc;
  }
}

// ===================== host =====================
extern "C" void kernel_launch(void* const* d_in, const int* in_sizes, int n_in,
                              void* d_out, int out_size, void* d_ws, size_t ws_size,
                              hipStream_t stream) {
  const float* poi_x = (const float*)d_in[0];
  const float* img = (const float*)d_in[1];
  const int* edges = (const int*)d_in[2];
  const float* T0p = (const float*)d_in[4];
  const float* W1 = (const float*)d_in[5];
  const float* b1 = (const float*)d_in[6];
  const float* W2 = (const float*)d_in[7];
  const float* b2 = (const float*)d_in[8];
  const float* Whrs = (const float*)d_in[9];
  const float* bhrs = (const float*)d_in[10];
  const float* Wph = (const float*)d_in[11];
  const float* bph = (const float*)d_in[12];
  const float* Wpp = (const float*)d_in[13];
  const float* bpp = (const float*)d_in[14];
  const float* Wg_in = (const float*)d_in[15];
  const float* al_in = (const float*)d_in[16];
  const float* ar_in = (const float*)d_in[17];
  const float* bg_in = (const float*)d_in[18];
  const float* Wg_w = (const float*)d_in[19];
  const float* bg_w = (const float*)d_in[22];
  const float* Wh1 = (const float*)d_in[23];
  const float* bh1 = (const float*)d_in[24];
  const float* Wp1 = (const float*)d_in[25];
  const float* bp1 = (const float*)d_in[26];
  const float* Wfc = (const float*)d_in[27];
  const float* bfc = (const float*)d_in[28];

  const int* esrc = edges;
  const int* edst = edges + EE;

  char* ws = (char*)d_ws;
  size_t off = 0;
  auto alloc = [&](size_t nbytes) -> char* {
    char* p = ws + off;
    off += (nbytes + 255) & ~(size_t)255;
    return p;
  };
  uint8_t* Sg8 = (uint8_t*)alloc((size_t)NN * 128);
  u16* w1t = (u16*)alloc(8192 * 2);
  u16* w2t = (u16*)alloc(16384 * 2);
  float* hrs = (float*)alloc(512 * 128 * 4);
  float* er = (float*)alloc(512 * 3 * 4);
  float* wv = (float*)alloc(384 * 4);
  float* q = (float*)alloc(384 * 4);
  float* chv = (float*)alloc(16);
  float* B0 = (float*)alloc(2048 * 4);
  float* Chb = (float*)alloc(3 * 2048 * 4);
  float* D0 = (float*)alloc(128 * 4);
  float* Evec = (float*)alloc(128 * 4);
  float* Afold = (float*)alloc(6 * 2048 * 4);
  float* bias_out = (float*)alloc(16 * 4);
  float* pool = (float*)alloc(512 * 128 * 4);
  float* pooled = (float*)alloc((size_t)1536 * 128 * 4);
  u16* mfnb = (u16*)alloc(512 * 256 * 2);
  int* rowcnt = (int*)alloc(512 * 4);

  float* out = (float*)d_out;
  float* med = out + 512 * 16;

  hipMemsetAsync(Sg8, 0, (size_t)NN * 128, stream);

  size_t dynf = 156416;
  hipFuncSetAttribute((const void*)k_gcn_fused, hipFuncAttributeMaxDynamicSharedMemorySize,
                      (int)dynf);

  k_prep_graph<<<2180, 256, 0, stream>>>(esrc, edst, (uint32_t*)Sg8, W1, W2, Wg_in, al_in,
                                         ar_in, Wpp, bpp, w1t, w2t, wv, q, chv, Wg_w, Wfc, bph,
                                         bg_in, B0, Chb, D0, Evec, rowcnt);
  k_hrsfold<<<305, 1024, 0, stream>>>(img, Whrs, bhrs, Wph, bph, wv, hrs, er, Wh1, Wp1, Wpp,
                                      Wfc, bfc, bh1, bp1, bg_w, B0, Chb, D0, Evec, Afold,
                                      bias_out);
  k_gcn_fused<<<512, 1024, dynf, stream>>>(poi_x, b1, b2, Sg8, q, chv, er, hrs, w1t, w2t, pool,
                                           pooled, mfnb);
  k_med<<<256, 256, 0, stream>>>(mfnb, T0p, med, rowcnt);
  k_epilogue<<<512, 256, 0, stream>>>(med, T0p, rowcnt, hrs, pool, pooled, Afold, bias_out,
                                      out);

  (void)in_sizes; (void)n_in; (void)out_size; (void)ws_size;
}

// Round 17
// 136.305 us; speedup vs baseline: 1.5490x; 1.0074x over previous
//
#include <hip/hip_runtime.h>
#include <stdint.h>

#define NN 65536
#define EE 524288
#define BB 512

typedef unsigned short u16;
typedef __attribute__((ext_vector_type(8))) short s8v;    // 8 bf16 (4 VGPRs)
typedef __attribute__((ext_vector_type(4))) float f32x4;  // MFMA acc

__device__ __forceinline__ u16 f2b(float f) {
  union { float f; uint32_t u; } a{f};
  uint32_t r = a.u + 0x7fff + ((a.u >> 16) & 1);
  return (u16)(r >> 16);
}
__device__ __forceinline__ float b2f(u16 v) {
  union { uint32_t u; float f; } a{(uint32_t)v << 16};
  return a.f;
}
__device__ __forceinline__ int swz128(int r, int c) { return r * 128 + (c ^ ((r & 7) << 3)); }
__device__ __forceinline__ int swz64(int r, int c) { return r * 64 + (c ^ ((r & 7) << 3)); }

// ===================== k_front: hrs (0..255) | scatter (256..767) | transposes (768..791)
//                       | wv/q/ch (792) | Afold (793..798) | bias (799) | rowcnt0 (800) ====
__global__ void __launch_bounds__(1024) k_front(
    const int* __restrict__ src, const int* __restrict__ dst, uint32_t* __restrict__ Sg,
    const float* __restrict__ W1, const float* __restrict__ W2,
    const float* __restrict__ Wg_in, const float* __restrict__ al_in,
    const float* __restrict__ ar_in, const float* __restrict__ Wpp,
    const float* __restrict__ bpp, u16* __restrict__ w1t, u16* __restrict__ w2t,
    float* __restrict__ wv, float* __restrict__ q, float* __restrict__ ch,
    const float* __restrict__ Wg_w, const float* __restrict__ Wfc,
    const float* __restrict__ bph, const float* __restrict__ bg_in,
    int* __restrict__ rowcnt, const float* __restrict__ img, const float* __restrict__ Whrs,
    const float* __restrict__ bhrs, const float* __restrict__ Wph, float* __restrict__ hrs,
    float* __restrict__ er, const float* __restrict__ Wh1, const float* __restrict__ Wp1,
    const float* __restrict__ bfc, const float* __restrict__ bh1,
    const float* __restrict__ bp1, const float* __restrict__ bg_w,
    float* __restrict__ Afold, float* __restrict__ bias_out) {
  __shared__ char smem[23040];
  int blk = blockIdx.x, t = threadIdx.x;

  if (blk < 256) {
    // ---- hrs + er (heavy compute; dispatched first) ----
    float* sI = (float*)smem;                     // 4096 f
    float(*sRed)[128] = (float(*)[128])(smem + 16384);  // [8][128]
    float(*sHrs)[128] = (float(*)[128])(smem + 20480);  // [2][128]
    float(*sPh)[128] = (float(*)[128])(smem + 21504);   // [2][128]
    int r0 = blk * 2;
    const float4* gsrc = (const float4*)(img + (size_t)r0 * 2048);
    ((float4*)sI)[t] = gsrc[t];
    __syncthreads();
    int c = t & 127, g = t >> 7;
    int row = g & 1, ks = g >> 1;
    const float* s = sI + row * 2048 + ks * 512;
    const float* W = Whrs + (size_t)(ks * 512) * 128 + c;
    float a0 = 0.f, a1 = 0.f, a2 = 0.f, a3 = 0.f;
    for (int k = 0; k < 512; k += 4) {
      a0 += s[k] * W[(size_t)k * 128];
      a1 += s[k + 1] * W[(size_t)(k + 1) * 128];
      a2 += s[k + 2] * W[(size_t)(k + 2) * 128];
      a3 += s[k + 3] * W[(size_t)(k + 3) * 128];
    }
    sRed[g][c] = (a0 + a1) + (a2 + a3);
    __syncthreads();
    if (t < 256) {
      int rr = t >> 7, cc = t & 127;
      float v = sRed[rr][cc] + sRed[rr + 2][cc] + sRed[rr + 4][cc] + sRed[rr + 6][cc] + bhrs[cc];
      hrs[(r0 + rr) * 128 + cc] = v;
      sHrs[rr][cc] = v;
    }
    __syncthreads();
    if (t < 256) {
      int rr = t >> 7, cc = t & 127;
      float acc = bph[cc];
#pragma unroll 4
      for (int k = 0; k < 128; ++k) acc += sHrs[rr][k] * Wph[k * 128 + cc];
      sPh[rr][cc] = acc;
    }
    __syncthreads();
    if (t < 6) {
      int rr = t / 3, h = t % 3;
      float s2 = 0.f;
#pragma unroll 4
      for (int k = 0; k < 128; ++k) s2 += sPh[rr][k] * wv[h * 128 + k];
      er[(r0 + rr) * 3 + h] = s2;
    }
  } else if (blk < 768) {
    // ---- edge scatter: 1024 edges per block ----
    int e = (blk - 256) * 1024 + t;
    int s = src[e] & 127, d = dst[e];
    atomicAdd(&Sg[((size_t)d * 128 + s) >> 2], 1u << ((s & 3) * 8));
  } else if (blk < 792) {
    // ---- W1/W2 transpose -> bf16 ----
    int i = (blk - 768) * 1024 + t;  // 24576
    if (i < 8192) {
      int n = i >> 6, k = i & 63;
      w1t[i] = f2b(W1[k * 128 + n]);
    } else {
      int j = i - 8192;
      int n = j >> 7, k = j & 127;
      w2t[j] = f2b(W2[k * 128 + n]);
    }
  } else if (blk == 792) {
    // ---- wv / q / ch ----
    float* su = (float*)smem;  // 384
    for (int i = t; i < 384; i += 1024) {
      int h = i >> 7, k = i & 127;
      float s = 0.f, sw = 0.f;
#pragma unroll 4
      for (int c = 0; c < 128; ++c) {
        float g = Wg_in[k * 384 + h * 128 + c];
        s += g * al_in[h * 128 + c];
        sw += g * ar_in[h * 128 + c];
      }
      su[i] = s;
      wv[i] = sw;
    }
    __syncthreads();
    for (int i = t; i < 384; i += 1024) {
      int h = i >> 7, j = i & 127;
      float s = 0.f;
#pragma unroll 4
      for (int k = 0; k < 128; ++k) s += Wpp[j * 128 + k] * su[h * 128 + k];
      q[i] = s;
    }
    if (t < 3) {
      float s = 0.f;
#pragma unroll 4
      for (int k = 0; k < 128; ++k) s += bpp[k] * su[t * 128 + k];
      ch[t] = s;
    }
  } else if (blk == 793) {
    // ---- A_hrs = Wph @ (G @ Wfc_s0), two stages in-block ----
    float* sW = (float*)smem;            // 2048
    float* sB = (float*)(smem + 8192);   // 2048
    for (int i = t; i < 2048; i += 1024) sW[i] = Wfc[i];
    __syncthreads();
    for (int i = t; i < 2048; i += 1024) {
      int m = i >> 4, o = i & 15;
      const float* wr = Wg_w + (size_t)m * 384;
      float acc = 0.f;
#pragma unroll 4
      for (int j = 0; j < 128; ++j) {
        float g = (wr[j] + wr[128 + j] + wr[256 + j]) * (1.0f / 3.0f);
        acc += g * sW[j * 16 + o];
      }
      sB[i] = acc;
    }
    __syncthreads();
    for (int i = t; i < 2048; i += 1024) {
      int k = i >> 4, o = i & 15;
      const float* lr = Wph + (size_t)k * 128;
      float acc = 0.f;
#pragma unroll 4
      for (int m = 0; m < 128; ++m) acc += lr[m] * sB[m * 16 + o];
      Afold[i] = acc;
    }
  } else if (blk == 794 || blk == 795) {
    // ---- A_T1 (Wh1 @ Wfc_s3) / A_T2 (Wp1 @ Wfc_s1) ----
    float* sW = (float*)smem;
    int mat = blk - 793;  // 1 or 2
    const float* src_w = (mat == 1) ? (Wfc + 384 * 16) : (Wfc + 128 * 16);
    for (int i = t; i < 2048; i += 1024) sW[i] = src_w[i];
    __syncthreads();
    const float* L = (mat == 1) ? Wh1 : Wp1;
    for (int i = t; i < 2048; i += 1024) {
      int k = i >> 4, o = i & 15;
      const float* lr = L + (size_t)k * 128;
      float acc = 0.f;
#pragma unroll 4
      for (int m = 0; m < 128; ++m) acc += lr[m] * sW[m * 16 + o];
      Afold[(size_t)mat * 2048 + i] = acc;
    }
  } else if (blk < 799) {
    // ---- A_pld_h = (1/3) Wpp @ (Wg_in_h @ Wfc_s2) ----
    int h = blk - 796;
    float* sW = (float*)smem;
    float* sB = (float*)(smem + 8192);
    for (int i = t; i < 2048; i += 1024) sW[i] = Wfc[256 * 16 + i];
    __syncthreads();
    for (int i = t; i < 2048; i += 1024) {
      int m = i >> 4, o = i & 15;
      const float* wr = Wg_in + (size_t)m * 384 + h * 128;
      float acc = 0.f;
#pragma unroll 4
      for (int c = 0; c < 128; ++c) acc += wr[c] * sW[c * 16 + o];
      sB[i] = acc;
    }
    __syncthreads();
    for (int i = t; i < 2048; i += 1024) {
      int k = i >> 4, o = i & 15;
      const float* lr = Wpp + (size_t)k * 128;
      float acc = 0.f;
#pragma unroll 4
      for (int m = 0; m < 128; ++m) acc += lr[m] * sB[m * 16 + o];
      Afold[(size_t)(3 + h) * 2048 + i] = acc * (1.0f / 3.0f);
    }
  } else if (blk == 799) {
    // ---- bias_out: D0/Evec in-block (8-way k-slices) then fold ----
    float(*sD)[128] = (float(*)[128])smem;            // [8][128]
    float(*sE)[128] = (float(*)[128])(smem + 4096);   // [8][128]
    float* sDv = (float*)(smem + 8192);               // 128
    float* sEv = (float*)(smem + 8704);               // 128
    float(*sRed2)[16] = (float(*)[16])(smem + 9216);  // [16][16]
    int j = t & 127, ks = t >> 7;  // 8 slices of 16
    {
      float acc = 0.f;
#pragma unroll
      for (int k = ks * 16; k < ks * 16 + 16; ++k) {
        float g = (Wg_w[k * 384 + j] + Wg_w[k * 384 + 128 + j] + Wg_w[k * 384 + 256 + j]) *
                  (1.0f / 3.0f);
        acc += bph[k] * g;
      }
      sD[ks][j] = acc;
      float e = 0.f;
      for (int h = 0; h < 3; ++h) {
#pragma unroll
        for (int m = ks * 16; m < ks * 16 + 16; ++m) e += bpp[m] * Wg_in[m * 384 + h * 128 + j];
      }
      sE[ks][j] = e;
    }
    __syncthreads();
    if (t < 128) {
      float d = 0.f, ev = 0.f;
#pragma unroll
      for (int s = 0; s < 8; ++s) {
        d += sD[s][t];
        ev += sE[s][t];
      }
      sDv[t] = d;
      float g0in = (bg_in[t] + bg_in[128 + t] + bg_in[256 + t]) * (1.0f / 3.0f);
      sEv[t] = ev * (1.0f / 3.0f) + g0in;
    }
    __syncthreads();
    if (t < 256) {
      int o = t & 15, chunk = t >> 4;
      int j0 = chunk * 8;
      float acc = 0.f;
#pragma unroll
      for (int jj = 0; jj < 8; ++jj) {
        int jx = j0 + jj;
        float g0w = (bg_w[jx] + bg_w[128 + jx] + bg_w[256 + jx]) * (1.0f / 3.0f);
        acc += (sDv[jx] + g0w) * Wfc[jx * 16 + o];
        acc += bp1[jx] * Wfc[(128 + jx) * 16 + o];
        acc += sEv[jx] * Wfc[(256 + jx) * 16 + o];
        acc += bh1[jx] * Wfc[(384 + jx) * 16 + o];
      }
      sRed2[o][chunk] = acc;
    }
    __syncthreads();
    if (t < 16) {
      float a = bfc[t];
#pragma unroll
      for (int c = 0; c < 16; ++c) a += sRed2[t][c];
      bias_out[t] = a;
    }
  } else {
    if (t < 512) rowcnt[t] = 0;
  }
}

// ===================== FUSED GCN via dense S' + MFMA (1024 thr, parallel tails) ====
__global__ void __launch_bounds__(1024) k_gcn_fused(
    const float* __restrict__ x, const float* __restrict__ b1, const float* __restrict__ b2,
    const uint8_t* __restrict__ Sg8, const float* __restrict__ q, const float* __restrict__ ch,
    const float* __restrict__ er, const float* __restrict__ hrs,
    const u16* __restrict__ w1t, const u16* __restrict__ w2t, float* __restrict__ poi_pool,
    float* __restrict__ pooled, u16* __restrict__ mfnb) {
  extern __shared__ char sm[];
  u16* sS = (u16*)sm;
  u16* sB2 = (u16*)(sm + 32768);
  u16* sPt = (u16*)(sm + 32768);
  u16* sXt = (u16*)(sm + 65536);
  u16* sAgg1 = (u16*)(sm + 81920);
  u16* sW1t = (u16*)(sm + 98304);
  float* sXrm = (float*)(sm + 114688);
  u16* sW2t = (u16*)(sm + 114688);
  u16* sAgg2 = (u16*)(sm + 65536);
  u16* sP = (u16*)sm;
  float* sNorm = (float*)(sm + 147968);
  float* sQ = (float*)(sm + 148480);
  float* sAl = (float*)(sm + 150016);
  float* sPool = (float*)(sm + 151552);
  float* sEr = (float*)(sm + 152064);
  float* sCh = (float*)(sm + 152080);
  float* sElp = (float*)(sm + 152320);    // [6][128]
  float* sPoolp = (float*)(sm + 155392);  // [2][128]

  int b = blockIdx.x, t = threadIdx.x;
  int base = b << 7;
  int l = t & 63, w = t >> 6;
  int wm = w & 7, wn = w >> 3;
  const uint8_t* Sgb = Sg8 + (size_t)base * 128;

  // ---- phase 0: single Sg read + shuffle row-sums -> norms; stage rest ----
  int rown = t >> 3, q8 = t & 7;
  uint4 cw = *(const uint4*)(Sgb + rown * 128 + q8 * 16);
  {
    uint32_t words[4] = {cw.x, cw.y, cw.z, cw.w};
    uint32_t bs = 0;
#pragma unroll
    for (int p = 0; p < 4; ++p)
      bs += (words[p] & 0xff) + ((words[p] >> 8) & 0xff) + ((words[p] >> 16) & 0xff) +
            (words[p] >> 24);
    bs += __shfl_xor((int)bs, 1);
    bs += __shfl_xor((int)bs, 2);
    bs += __shfl_xor((int)bs, 4);
    if ((t & 7) == 0) sNorm[rown] = rsqrtf((float)bs + 1.0f);
  }
  for (int i = t; i < 8192; i += 1024) {
    int s = i >> 6, f = i & 63;
    sXrm[s * 65 + f] = x[(size_t)(base + s) * 64 + f];
  }
  {
    int n = t >> 3, blk = t & 7;
    *(uint4*)(sW1t + n * 64 + ((blk ^ (n & 7)) << 3)) = ((const uint4*)w1t)[t];
  }
  if (t < 384) sQ[t] = q[t];
  if (t < 3) {
    sEr[t] = er[b * 3 + t];
    sCh[t] = ch[t];
  }
  __syncthreads();

  // ---- phase 1: S' from retained counts + X transpose->bf16 ----
  {
    int r = rown;
    float nr = sNorm[r];
    int sw = (r & 7) << 3;
    uint32_t words[4] = {cw.x, cw.y, cw.z, cw.w};
#pragma unroll
    for (int qd = 0; qd < 4; ++qd) {
      uint32_t wd = words[qd];
#pragma unroll
      for (int p = 0; p < 4; p += 2) {
        int s0 = q8 * 16 + qd * 4 + p;
        float v0 = ((float)((wd >> (p * 8)) & 0xff) + (r == s0 ? 1.f : 0.f)) * nr * sNorm[s0];
        float v1 =
            ((float)((wd >> (p * 8 + 8)) & 0xff) + (r == s0 + 1 ? 1.f : 0.f)) * nr * sNorm[s0 + 1];
        uint32_t pk = (uint32_t)f2b(v0) | ((uint32_t)f2b(v1) << 16);
        *(uint32_t*)(sS + r * 128 + (s0 ^ sw)) = pk;
      }
    }
  }
  for (int i = t; i < 4096; i += 1024) {
    int f = i >> 6, s = (i & 63) * 2;
    float v0 = sXrm[s * 65 + f] * sNorm[s];
    float v1 = sXrm[(s + 1) * 65 + f] * sNorm[s + 1];
    uint32_t pk = (uint32_t)f2b(v0) | ((uint32_t)f2b(v1) << 16);
    *(uint32_t*)(sXt + (f * 128 + (s ^ ((f & 7) << 3)))) = pk;
  }
  __syncthreads();

  int mrow = wm * 16 + (l & 15);
  int kblk = (l >> 4) * 8;
  int rbase = wm * 16 + (l >> 4) * 4;

  // ---- phase 3: agg1 = S' @ X (nt-split); stage W2t ----
  {
    s8v a4[4];
#pragma unroll
    for (int ks = 0; ks < 4; ++ks) a4[ks] = *(const s8v*)(sS + swz128(mrow, ks * 32 + kblk));
#pragma unroll
    for (int j = 0; j < 2; ++j) {
      int nt = wn * 2 + j;
      f32x4 acc = {0.f, 0.f, 0.f, 0.f};
      int cg = nt * 16 + (l & 15);
#pragma unroll
      for (int ks = 0; ks < 4; ++ks)
        acc = __builtin_amdgcn_mfma_f32_16x16x32_bf16(
            a4[ks], *(const s8v*)(sXt + swz128(cg, ks * 32 + kblk)), acc, 0, 0, 0);
#pragma unroll
      for (int rg = 0; rg < 4; ++rg) sAgg1[swz64(rbase + rg, cg)] = f2b(acc[rg]);
    }
  }
  for (int g = t; g < 2048; g += 1024) {
    int n = g >> 4, blk = g & 15;
    *(uint4*)(sW2t + n * 128 + ((blk ^ (n & 7)) << 3)) = ((const uint4*)w2t)[g];
  }
  __syncthreads();

  // ---- phase 4: h1 = relu(agg1 @ W1 + b1) -> h1^T (nt-split) ----
  {
    s8v a2[2];
#pragma unroll
    for (int ks = 0; ks < 2; ++ks) a2[ks] = *(const s8v*)(sAgg1 + swz64(mrow, ks * 32 + kblk));
#pragma unroll
    for (int j = 0; j < 4; ++j) {
      int nt = wn * 4 + j;
      int cg = nt * 16 + (l & 15);
      float bv = b1[cg];
      f32x4 acc = {bv, bv, bv, bv};
#pragma unroll
      for (int ks = 0; ks < 2; ++ks)
        acc = __builtin_amdgcn_mfma_f32_16x16x32_bf16(
            a2[ks], *(const s8v*)(sW1t + swz64(cg, ks * 32 + kblk)), acc, 0, 0, 0);
      u16 h0 = f2b(fmaxf(acc[0], 0.f)), h1v = f2b(fmaxf(acc[1], 0.f));
      u16 h2 = f2b(fmaxf(acc[2], 0.f)), h3 = f2b(fmaxf(acc[3], 0.f));
      uint2 pk;
      pk.x = (uint32_t)h0 | ((uint32_t)h1v << 16);
      pk.y = (uint32_t)h2 | ((uint32_t)h3 << 16);
      *(uint2*)(sB2 + swz128(cg, rbase)) = pk;
    }
  }
  __syncthreads();

  // ---- phase 5: agg2 = S' @ h1 (nt-split) ----
  {
    s8v a4[4];
#pragma unroll
    for (int ks = 0; ks < 4; ++ks) a4[ks] = *(const s8v*)(sS + swz128(mrow, ks * 32 + kblk));
#pragma unroll
    for (int j = 0; j < 4; ++j) {
      int nt = wn * 4 + j;
      f32x4 acc = {0.f, 0.f, 0.f, 0.f};
      int cg = nt * 16 + (l & 15);
#pragma unroll
      for (int ks = 0; ks < 4; ++ks)
        acc = __builtin_amdgcn_mfma_f32_16x16x32_bf16(
            a4[ks], *(const s8v*)(sB2 + swz128(cg, ks * 32 + kblk)), acc, 0, 0, 0);
#pragma unroll
      for (int rg = 0; rg < 4; ++rg) sAgg2[swz128(rbase + rg, cg)] = f2b(acc[rg]);
    }
  }
  __syncthreads();

  // ---- phase 6: poi = agg2 @ W2 + b2 -> sP + sPt (nt-split) ----
  {
    s8v a4[4];
#pragma unroll
    for (int ks = 0; ks < 4; ++ks) a4[ks] = *(const s8v*)(sAgg2 + swz128(mrow, ks * 32 + kblk));
#pragma unroll
    for (int j = 0; j < 4; ++j) {
      int nt = wn * 4 + j;
      int cg = nt * 16 + (l & 15);
      float bv = b2[cg];
      f32x4 acc = {bv, bv, bv, bv};
#pragma unroll
      for (int ks = 0; ks < 4; ++ks)
        acc = __builtin_amdgcn_mfma_f32_16x16x32_bf16(
            a4[ks], *(const s8v*)(sW2t + swz128(cg, ks * 32 + kblk)), acc, 0, 0, 0);
      u16 p0 = f2b(acc[0]), p1 = f2b(acc[1]), p2 = f2b(acc[2]), p3 = f2b(acc[3]);
#pragma unroll
      for (int rg = 0; rg < 4; ++rg)
        sP[swz128(rbase + rg, cg)] = (rg == 0) ? p0 : (rg == 1) ? p1 : (rg == 2) ? p2 : p3;
      uint2 pk;
      pk.x = (uint32_t)p0 | ((uint32_t)p1 << 16);
      pk.y = (uint32_t)p2 | ((uint32_t)p3 << 16);
      *(uint2*)(sPt + swz128(cg, rbase)) = pk;
    }
  }
  __syncthreads();

  // ---- tail A: pool partials (t<256) || el partials (256..1023) ----
  if (t < 256) {
    int c = t & 127, kh = t >> 7;
    float s = 0.f;
    const u16* rowp = sPt + c * 128;
    int sw = (c & 7) << 3;
#pragma unroll
    for (int k8 = kh * 8; k8 < kh * 8 + 8; ++k8) {
      s8v v = *(const s8v*)(rowp + ((k8 * 8) ^ sw));
#pragma unroll
      for (int j = 0; j < 8; ++j) s += b2f((u16)v[j]);
    }
    sPoolp[kh * 128 + c] = s;
  } else {
    int task = t - 256;
    int r = task & 127, hk = task >> 7;
    int h = hk >> 1, kh = hk & 1;
    int sw = (r & 7) << 3;
    const u16* rowp = sP + r * 128;
    const float* qh = &sQ[h * 128];
    float d = 0.f;
#pragma unroll
    for (int k8 = kh * 8; k8 < kh * 8 + 8; ++k8) {
      int c8 = (k8 * 8) ^ sw;
      s8v v = *(const s8v*)(rowp + c8);
#pragma unroll
      for (int j = 0; j < 8; ++j) d += b2f((u16)v[j]) * qh[c8 + j];
    }
    sElp[hk * 128 + r] = d;
  }
  __syncthreads();

  if (t < 128) {
    float s = sPoolp[t] + sPoolp[128 + t];
    sPool[t] = s;
    poi_pool[b * 128 + t] = s * (1.0f / 128.0f);
  }
  if (t >= 512 && t < 896) {
    int tt = t - 512;
    int h = tt >> 7, r = tt & 127;
    float e = sElp[h * 256 + r] + sElp[h * 256 + 128 + r] + sCh[h] + sEr[h];
    sAl[h * 128 + r] = (e > 0.f) ? e : 0.2f * e;
  }
  __syncthreads();

  if (t < 192) {
    int h = t >> 6, ll = t & 63;
    float v0 = sAl[h * 128 + ll], v1 = sAl[h * 128 + 64 + ll];
    float m = fmaxf(v0, v1);
    for (int off = 32; off > 0; off >>= 1) m = fmaxf(m, __shfl_xor(m, off));
    float x0 = __expf(v0 - m), x1 = __expf(v1 - m);
    float s = x0 + x1;
    for (int off = 32; off > 0; off >>= 1) s += __shfl_xor(s, off);
    float inv = 1.0f / s;
    sAl[h * 128 + ll] = x0 * inv;
    sAl[h * 128 + 64 + ll] = x1 * inv;
  }
  __syncthreads();

  if (t < 768) {
    int c = t & 127, hk = t >> 7;
    int hh = hk >> 1, kh = hk & 1;
    int sw = (c & 7) << 3;
    const u16* rowp = sPt + c * 128;
    const float* al = &sAl[hh * 128];
    float s = 0.f;
#pragma unroll
    for (int k8 = kh * 8; k8 < kh * 8 + 8; ++k8) {
      int r8 = (k8 * 8) ^ sw;
      s8v v = *(const s8v*)(rowp + r8);
#pragma unroll
      for (int j = 0; j < 8; ++j) s += b2f((u16)v[j]) * al[r8 + j];
    }
    sElp[hk * 128 + c] = s;
  }
  __syncthreads();

  if (t < 384) {
    int hh = t >> 7, c = t & 127;
    pooled[((size_t)b * 3 + hh) * 128 + c] = sElp[hh * 256 + c] + sElp[hh * 256 + 128 + c];
  }
  __syncthreads();

  float hv = 0.f, pv = 0.f;
  if (t < 128) {
    hv = hrs[base + t];
    pv = sPool[t] * (1.0f / 128.0f);
    sQ[t] = hv * hv + pv * pv;
  }
  __syncthreads();
  if (t < 64) {
    float v = sQ[t] + sQ[t + 64];
    for (int off = 32; off > 0; off >>= 1) v += __shfl_xor(v, off);
    if (t == 0) sQ[0] = rsqrtf(v);
  }
  __syncthreads();
  if (t < 128) {
    float rn = sQ[0];
    mfnb[b * 256 + t] = f2b(hv * rn);
    mfnb[b * 256 + 128 + t] = f2b(pv * rn);
  }
}

// ===================== med via MFMA + fused row-count =====================
__global__ void __launch_bounds__(256) k_med(const u16* __restrict__ mfnb,
                                             const float* __restrict__ T0p,
                                             float* __restrict__ med,
                                             int* __restrict__ rowcnt) {
  __shared__ u16 sA[32 * 256];
  __shared__ u16 sB[32 * 256];
  int bi = blockIdx.x >> 4, bj = blockIdx.x & 15;
  int t = threadIdx.x;
  const uint4* srcA = (const uint4*)(mfnb + (size_t)bi * 32 * 256);
  const uint4* srcB = (const uint4*)(mfnb + (size_t)bj * 32 * 256);
  for (int g = t; g < 1024; g += 256) {
    int r = g >> 5, blk = g & 31;
    int db = (blk & 24) | ((blk ^ (r & 7)) & 7);
    uint4 va = srcA[g];
    uint4 vb = srcB[g];
    *(uint4*)(sA + r * 256 + db * 8) = va;
    *(uint4*)(sB + r * 256 + db * 8) = vb;
  }
  __syncthreads();
  int l = t & 63, w = t >> 6;
  int wr = w >> 1, wc = w & 1;
  int arow = wr * 16 + (l & 15);
  int brow = wc * 16 + (l & 15);
  int kblk = (l >> 4) * 8;
  f32x4 acc = {0.f, 0.f, 0.f, 0.f};
#pragma unroll
  for (int ks = 0; ks < 8; ++ks) {
    int kc = ks * 32 + kblk;
    s8v a = *(const s8v*)(sA + arow * 256 + (kc ^ ((arow & 7) << 3)));
    s8v bb = *(const s8v*)(sB + brow * 256 + (kc ^ ((brow & 7) << 3)));
    acc = __builtin_amdgcn_mfma_f32_16x16x32_bf16(a, bb, acc, 0, 0, 0);
  }
  int row0 = bi * 32 + wr * 16 + (l >> 4) * 4;
  int col = bj * 32 + wc * 16 + (l & 15);
  float T0 = *T0p;
  int cnt4[4];
#pragma unroll
  for (int rg = 0; rg < 4; ++rg) {
    float m = (acc[rg] + 1.0f) * 0.5f;
    med[(size_t)(row0 + rg) * 512 + col] = m;
    cnt4[rg] = (m >= T0 || (row0 + rg) == col) ? 1 : 0;
  }
#pragma unroll
  for (int off = 1; off < 16; off <<= 1) {
#pragma unroll
    for (int rg = 0; rg < 4; ++rg) cnt4[rg] += __shfl_xor(cnt4[rg], off);
  }
  if ((l & 15) == 0) {
#pragma unroll
    for (int rg = 0; rg < 4; ++rg) atomicAdd(&rowcnt[row0 + rg], cnt4[rg]);
  }
}

// ===================== slim epilogue: sparse Aagg + folded 768->16 dot =====================
__global__ void __launch_bounds__(256) k_epilogue(
    const float* __restrict__ med, const float* __restrict__ T0p,
    const int* __restrict__ rowcnt, const float* __restrict__ hrs,
    const float* __restrict__ pool, const float* __restrict__ pooled,
    const float* __restrict__ Afold, const float* __restrict__ bias_out,
    float* __restrict__ out) {
  __shared__ float sMedRow[512];
  __shared__ float sIn[6][128];
  __shared__ float sRed[16][16];
  __shared__ int sNbr[64];
  __shared__ float sDw[64];
  __shared__ int sNnz;
  int i = blockIdx.x, t = threadIdx.x;
  float T0 = *T0p;

  for (int j = t; j < 512; j += 256) sMedRow[j] = med[(size_t)i * 512 + j];
  if (t < 128) sIn[0][t] = hrs[i * 128 + t];
  for (int k = t; k < 384; k += 256) sIn[3 + (k >> 7)][k & 127] = pooled[(size_t)i * 384 + k];
  __syncthreads();

  if (t < 64) {
    int cnt = 0, flags = 0;
#pragma unroll
    for (int k = 0; k < 8; ++k) {
      int j = t * 8 + k;
      if (sMedRow[j] >= T0 || j == i) {
        flags |= 1 << k;
        ++cnt;
      }
    }
    int off = cnt;
    for (int d = 1; d < 64; d <<= 1) {
      int v = __shfl_up(off, d);
      if (t >= d) off += v;
    }
    off -= cnt;
    int pos = off;
#pragma unroll
    for (int k = 0; k < 8; ++k)
      if (flags & (1 << k)) {
        int j = t * 8 + k;
        if (pos < 64) {
          sNbr[pos] = j;
          sDw[pos] = rsqrtf((float)rowcnt[j]);
        }
        ++pos;
      }
    if (t == 63) sNnz = off + cnt;
  }
  __syncthreads();

  {
    int half = t >> 7, c = t & 127;
    float di = rsqrtf((float)rowcnt[i]);
    const float* srcm = half ? pool : hrs;
    float acc = 0.f;
    int nnz = sNnz;
    if (nnz <= 64) {
      for (int n = 0; n < nnz; ++n) acc += sDw[n] * srcm[sNbr[n] * 128 + c];
    } else {
      for (int j = 0; j < 512; ++j)
        if (sMedRow[j] >= T0 || j == i) acc += rsqrtf((float)rowcnt[j]) * srcm[j * 128 + c];
    }
    sIn[1 + half][c] = acc * di;
  }
  __syncthreads();

  {
    int o = t >> 4, chunk = t & 15;
    int c0 = chunk * 8;
    float acc = 0.f;
#pragma unroll
    for (int m = 0; m < 6; ++m) {
      const float* A = Afold + m * 2048;
      const float* xm = sIn[m];
#pragma unroll
      for (int k = 0; k < 8; ++k) acc += xm[c0 + k] * A[(c0 + k) * 16 + o];
    }
    sRed[o][chunk] = acc;
  }
  __syncthreads();
  if (t < 16) {
    float acc = bias_out[t];
#pragma unroll
    for (int j = 0; j < 16; ++j) acc += sRed[t][j];
    out[i * 16 + t] = acc;
  }
}

// ===================== host =====================
extern "C" void kernel_launch(void* const* d_in, const int* in_sizes, int n_in,
                              void* d_out, int out_size, void* d_ws, size_t ws_size,
                              hipStream_t stream) {
  const float* poi_x = (const float*)d_in[0];
  const float* img = (const float*)d_in[1];
  const int* edges = (const int*)d_in[2];
  const float* T0p = (const float*)d_in[4];
  const float* W1 = (const float*)d_in[5];
  const float* b1 = (const float*)d_in[6];
  const float* W2 = (const float*)d_in[7];
  const float* b2 = (const float*)d_in[8];
  const float* Whrs = (const float*)d_in[9];
  const float* bhrs = (const float*)d_in[10];
  const float* Wph = (const float*)d_in[11];
  const float* bph = (const float*)d_in[12];
  const float* Wpp = (const float*)d_in[13];
  const float* bpp = (const float*)d_in[14];
  const float* Wg_in = (const float*)d_in[15];
  const float* al_in = (const float*)d_in[16];
  const float* ar_in = (const float*)d_in[17];
  const float* bg_in = (const float*)d_in[18];
  const float* Wg_w = (const float*)d_in[19];
  const float* bg_w = (const float*)d_in[22];
  const float* Wh1 = (const float*)d_in[23];
  const float* bh1 = (const float*)d_in[24];
  const float* Wp1 = (const float*)d_in[25];
  const float* bp1 = (const float*)d_in[26];
  const float* Wfc = (const float*)d_in[27];
  const float* bfc = (const float*)d_in[28];

  const int* esrc = edges;
  const int* edst = edges + EE;

  char* ws = (char*)d_ws;
  size_t off = 0;
  auto alloc = [&](size_t nbytes) -> char* {
    char* p = ws + off;
    off += (nbytes + 255) & ~(size_t)255;
    return p;
  };
  uint8_t* Sg8 = (uint8_t*)alloc((size_t)NN * 128);
  u16* w1t = (u16*)alloc(8192 * 2);
  u16* w2t = (u16*)alloc(16384 * 2);
  float* hrs = (float*)alloc(512 * 128 * 4);
  float* er = (float*)alloc(512 * 3 * 4);
  float* wv = (float*)alloc(384 * 4);
  float* q = (float*)alloc(384 * 4);
  float* chv = (float*)alloc(16);
  float* Afold = (float*)alloc(6 * 2048 * 4);
  float* bias_out = (float*)alloc(16 * 4);
  float* pool = (float*)alloc(512 * 128 * 4);
  float* pooled = (float*)alloc((size_t)1536 * 128 * 4);
  u16* mfnb = (u16*)alloc(512 * 256 * 2);
  int* rowcnt = (int*)alloc(512 * 4);

  float* out = (float*)d_out;
  float* med = out + 512 * 16;

  hipMemsetAsync(Sg8, 0, (size_t)NN * 128, stream);

  size_t dynf = 156416;
  hipFuncSetAttribute((const void*)k_gcn_fused, hipFuncAttributeMaxDynamicSharedMemorySize,
                      (int)dynf);

  k_front<<<801, 1024, 0, stream>>>(esrc, edst, (uint32_t*)Sg8, W1, W2, Wg_in, al_in, ar_in,
                                    Wpp, bpp, w1t, w2t, wv, q, chv, Wg_w, Wfc, bph, bg_in,
                                    rowcnt, img, Whrs, bhrs, Wph, hrs, er, Wh1, Wp1, bfc, bh1,
                                    bp1, bg_w, Afold, bias_out);
  k_gcn_fused<<<512, 1024, dynf, stream>>>(poi_x, b1, b2, Sg8, q, chv, er, hrs, w1t, w2t, pool,
                                           pooled, mfnb);
  k_med<<<256, 256, 0, stream>>>(mfnb, T0p, med, rowcnt);
  k_epilogue<<<512, 256, 0, stream>>>(med, T0p, rowcnt, hrs, pool, pooled, Afold, bias_out,
                                      out);

  (void)in_sizes; (void)n_in; (void)out_size; (void)ws_size;
}

// Round 18
// 135.944 us; speedup vs baseline: 1.5531x; 1.0027x over previous
//
#include <hip/hip_runtime.h>
#include <stdint.h>

#define NN 65536
#define EE 524288
#define BB 512

typedef unsigned short u16;
typedef __attribute__((ext_vector_type(8))) short s8v;    // 8 bf16 (4 VGPRs)
typedef __attribute__((ext_vector_type(4))) float f32x4;  // MFMA acc

__device__ __forceinline__ u16 f2b(float f) {
  union { float f; uint32_t u; } a{f};
  uint32_t r = a.u + 0x7fff + ((a.u >> 16) & 1);
  return (u16)(r >> 16);
}
__device__ __forceinline__ float b2f(u16 v) {
  union { uint32_t u; float f; } a{(uint32_t)v << 16};
  return a.f;
}
__device__ __forceinline__ int swz128(int r, int c) { return r * 128 + (c ^ ((r & 7) << 3)); }
__device__ __forceinline__ int swz64(int r, int c) { return r * 64 + (c ^ ((r & 7) << 3)); }

// ===================== k_front: hrs (0..255) | scatter (256..767) | transposes (768..791)
//                       | wv/q/ch (792) | Afold (793..798) | bias (799) | rowcnt0 (800) ====
// Sg is a 4-bit count table: slot idx = d*128 + (s&127); word = idx>>3, nibble = idx&7.
__global__ void __launch_bounds__(1024) k_front(
    const int* __restrict__ src, const int* __restrict__ dst, uint32_t* __restrict__ Sg,
    const float* __restrict__ W1, const float* __restrict__ W2,
    const float* __restrict__ Wg_in, const float* __restrict__ al_in,
    const float* __restrict__ ar_in, const float* __restrict__ Wpp,
    const float* __restrict__ bpp, u16* __restrict__ w1t, u16* __restrict__ w2t,
    float* __restrict__ wv, float* __restrict__ q, float* __restrict__ ch,
    const float* __restrict__ Wg_w, const float* __restrict__ Wfc,
    const float* __restrict__ bph, const float* __restrict__ bg_in,
    int* __restrict__ rowcnt, const float* __restrict__ img, const float* __restrict__ Whrs,
    const float* __restrict__ bhrs, const float* __restrict__ Wph, float* __restrict__ hrs,
    float* __restrict__ er, const float* __restrict__ Wh1, const float* __restrict__ Wp1,
    const float* __restrict__ bfc, const float* __restrict__ bh1,
    const float* __restrict__ bp1, const float* __restrict__ bg_w,
    float* __restrict__ Afold, float* __restrict__ bias_out) {
  __shared__ char smem[23040];
  int blk = blockIdx.x, t = threadIdx.x;

  if (blk < 256) {
    // ---- hrs + er ----
    float* sI = (float*)smem;
    float(*sRed)[128] = (float(*)[128])(smem + 16384);
    float(*sHrs)[128] = (float(*)[128])(smem + 20480);
    float(*sPh)[128] = (float(*)[128])(smem + 21504);
    int r0 = blk * 2;
    const float4* gsrc = (const float4*)(img + (size_t)r0 * 2048);
    ((float4*)sI)[t] = gsrc[t];
    __syncthreads();
    int c = t & 127, g = t >> 7;
    int row = g & 1, ks = g >> 1;
    const float* s = sI + row * 2048 + ks * 512;
    const float* W = Whrs + (size_t)(ks * 512) * 128 + c;
    float a0 = 0.f, a1 = 0.f, a2 = 0.f, a3 = 0.f;
    for (int k = 0; k < 512; k += 4) {
      a0 += s[k] * W[(size_t)k * 128];
      a1 += s[k + 1] * W[(size_t)(k + 1) * 128];
      a2 += s[k + 2] * W[(size_t)(k + 2) * 128];
      a3 += s[k + 3] * W[(size_t)(k + 3) * 128];
    }
    sRed[g][c] = (a0 + a1) + (a2 + a3);
    __syncthreads();
    if (t < 256) {
      int rr = t >> 7, cc = t & 127;
      float v = sRed[rr][cc] + sRed[rr + 2][cc] + sRed[rr + 4][cc] + sRed[rr + 6][cc] + bhrs[cc];
      hrs[(r0 + rr) * 128 + cc] = v;
      sHrs[rr][cc] = v;
    }
    __syncthreads();
    if (t < 256) {
      int rr = t >> 7, cc = t & 127;
      float acc = bph[cc];
#pragma unroll 4
      for (int k = 0; k < 128; ++k) acc += sHrs[rr][k] * Wph[k * 128 + cc];
      sPh[rr][cc] = acc;
    }
    __syncthreads();
    if (t < 6) {
      int rr = t / 3, h = t % 3;
      float s2 = 0.f;
#pragma unroll 4
      for (int k = 0; k < 128; ++k) s2 += sPh[rr][k] * wv[h * 128 + k];
      er[(r0 + rr) * 3 + h] = s2;
    }
  } else if (blk < 768) {
    // ---- edge scatter into 4-bit counts ----
    int e = (blk - 256) * 1024 + t;
    int s = src[e] & 127, d = dst[e];
    size_t idx = (size_t)d * 128 + s;
    atomicAdd(&Sg[idx >> 3], 1u << ((idx & 7) * 4));
  } else if (blk < 792) {
    // ---- W1/W2 transpose -> bf16 ----
    int i = (blk - 768) * 1024 + t;  // 24576
    if (i < 8192) {
      int n = i >> 6, k = i & 63;
      w1t[i] = f2b(W1[k * 128 + n]);
    } else {
      int j = i - 8192;
      int n = j >> 7, k = j & 127;
      w2t[j] = f2b(W2[k * 128 + n]);
    }
  } else if (blk == 792) {
    // ---- wv / q / ch ----
    float* su = (float*)smem;
    for (int i = t; i < 384; i += 1024) {
      int h = i >> 7, k = i & 127;
      float s = 0.f, sw = 0.f;
#pragma unroll 4
      for (int c = 0; c < 128; ++c) {
        float g = Wg_in[k * 384 + h * 128 + c];
        s += g * al_in[h * 128 + c];
        sw += g * ar_in[h * 128 + c];
      }
      su[i] = s;
      wv[i] = sw;
    }
    __syncthreads();
    for (int i = t; i < 384; i += 1024) {
      int h = i >> 7, j = i & 127;
      float s = 0.f;
#pragma unroll 4
      for (int k = 0; k < 128; ++k) s += Wpp[j * 128 + k] * su[h * 128 + k];
      q[i] = s;
    }
    if (t < 3) {
      float s = 0.f;
#pragma unroll 4
      for (int k = 0; k < 128; ++k) s += bpp[k] * su[t * 128 + k];
      ch[t] = s;
    }
  } else if (blk == 793) {
    float* sW = (float*)smem;
    float* sB = (float*)(smem + 8192);
    for (int i = t; i < 2048; i += 1024) sW[i] = Wfc[i];
    __syncthreads();
    for (int i = t; i < 2048; i += 1024) {
      int m = i >> 4, o = i & 15;
      const float* wr = Wg_w + (size_t)m * 384;
      float acc = 0.f;
#pragma unroll 4
      for (int j = 0; j < 128; ++j) {
        float g = (wr[j] + wr[128 + j] + wr[256 + j]) * (1.0f / 3.0f);
        acc += g * sW[j * 16 + o];
      }
      sB[i] = acc;
    }
    __syncthreads();
    for (int i = t; i < 2048; i += 1024) {
      int k = i >> 4, o = i & 15;
      const float* lr = Wph + (size_t)k * 128;
      float acc = 0.f;
#pragma unroll 4
      for (int m = 0; m < 128; ++m) acc += lr[m] * sB[m * 16 + o];
      Afold[i] = acc;
    }
  } else if (blk == 794 || blk == 795) {
    float* sW = (float*)smem;
    int mat = blk - 793;
    const float* src_w = (mat == 1) ? (Wfc + 384 * 16) : (Wfc + 128 * 16);
    for (int i = t; i < 2048; i += 1024) sW[i] = src_w[i];
    __syncthreads();
    const float* L = (mat == 1) ? Wh1 : Wp1;
    for (int i = t; i < 2048; i += 1024) {
      int k = i >> 4, o = i & 15;
      const float* lr = L + (size_t)k * 128;
      float acc = 0.f;
#pragma unroll 4
      for (int m = 0; m < 128; ++m) acc += lr[m] * sW[m * 16 + o];
      Afold[(size_t)mat * 2048 + i] = acc;
    }
  } else if (blk < 799) {
    int h = blk - 796;
    float* sW = (float*)smem;
    float* sB = (float*)(smem + 8192);
    for (int i = t; i < 2048; i += 1024) sW[i] = Wfc[256 * 16 + i];
    __syncthreads();
    for (int i = t; i < 2048; i += 1024) {
      int m = i >> 4, o = i & 15;
      const float* wr = Wg_in + (size_t)m * 384 + h * 128;
      float acc = 0.f;
#pragma unroll 4
      for (int c = 0; c < 128; ++c) acc += wr[c] * sW[c * 16 + o];
      sB[i] = acc;
    }
    __syncthreads();
    for (int i = t; i < 2048; i += 1024) {
      int k = i >> 4, o = i & 15;
      const float* lr = Wpp + (size_t)k * 128;
      float acc = 0.f;
#pragma unroll 4
      for (int m = 0; m < 128; ++m) acc += lr[m] * sB[m * 16 + o];
      Afold[(size_t)(3 + h) * 2048 + i] = acc * (1.0f / 3.0f);
    }
  } else if (blk == 799) {
    float(*sD)[128] = (float(*)[128])smem;
    float(*sE)[128] = (float(*)[128])(smem + 4096);
    float* sDv = (float*)(smem + 8192);
    float* sEv = (float*)(smem + 8704);
    float(*sRed2)[16] = (float(*)[16])(smem + 9216);
    int j = t & 127, ks = t >> 7;
    {
      float acc = 0.f;
#pragma unroll
      for (int k = ks * 16; k < ks * 16 + 16; ++k) {
        float g = (Wg_w[k * 384 + j] + Wg_w[k * 384 + 128 + j] + Wg_w[k * 384 + 256 + j]) *
                  (1.0f / 3.0f);
        acc += bph[k] * g;
      }
      sD[ks][j] = acc;
      float e = 0.f;
      for (int h = 0; h < 3; ++h) {
#pragma unroll
        for (int m = ks * 16; m < ks * 16 + 16; ++m) e += bpp[m] * Wg_in[m * 384 + h * 128 + j];
      }
      sE[ks][j] = e;
    }
    __syncthreads();
    if (t < 128) {
      float d = 0.f, ev = 0.f;
#pragma unroll
      for (int s = 0; s < 8; ++s) {
        d += sD[s][t];
        ev += sE[s][t];
      }
      sDv[t] = d;
      float g0in = (bg_in[t] + bg_in[128 + t] + bg_in[256 + t]) * (1.0f / 3.0f);
      sEv[t] = ev * (1.0f / 3.0f) + g0in;
    }
    __syncthreads();
    if (t < 256) {
      int o = t & 15, chunk = t >> 4;
      int j0 = chunk * 8;
      float acc = 0.f;
#pragma unroll
      for (int jj = 0; jj < 8; ++jj) {
        int jx = j0 + jj;
        float g0w = (bg_w[jx] + bg_w[128 + jx] + bg_w[256 + jx]) * (1.0f / 3.0f);
        acc += (sDv[jx] + g0w) * Wfc[jx * 16 + o];
        acc += bp1[jx] * Wfc[(128 + jx) * 16 + o];
        acc += sEv[jx] * Wfc[(256 + jx) * 16 + o];
        acc += bh1[jx] * Wfc[(384 + jx) * 16 + o];
      }
      sRed2[o][chunk] = acc;
    }
    __syncthreads();
    if (t < 16) {
      float a = bfc[t];
#pragma unroll
      for (int c = 0; c < 16; ++c) a += sRed2[t][c];
      bias_out[t] = a;
    }
  } else {
    if (t < 512) rowcnt[t] = 0;
  }
}

// ===================== FUSED GCN via dense S' + MFMA (u4 counts, 1024 thr) ====
__global__ void __launch_bounds__(1024) k_gcn_fused(
    const float* __restrict__ x, const float* __restrict__ b1, const float* __restrict__ b2,
    const uint8_t* __restrict__ Sg4, const float* __restrict__ q, const float* __restrict__ ch,
    const float* __restrict__ er, const float* __restrict__ hrs,
    const u16* __restrict__ w1t, const u16* __restrict__ w2t, float* __restrict__ poi_pool,
    float* __restrict__ pooled, u16* __restrict__ mfnb) {
  extern __shared__ char sm[];
  u16* sS = (u16*)sm;
  u16* sB2 = (u16*)(sm + 32768);
  u16* sPt = (u16*)(sm + 32768);
  u16* sXt = (u16*)(sm + 65536);
  u16* sAgg1 = (u16*)(sm + 81920);
  u16* sW1t = (u16*)(sm + 98304);
  float* sXrm = (float*)(sm + 114688);
  u16* sW2t = (u16*)(sm + 114688);
  u16* sAgg2 = (u16*)(sm + 65536);
  u16* sP = (u16*)sm;
  float* sNorm = (float*)(sm + 147968);
  float* sQ = (float*)(sm + 148480);
  float* sAl = (float*)(sm + 150016);
  float* sPool = (float*)(sm + 151552);
  float* sEr = (float*)(sm + 152064);
  float* sCh = (float*)(sm + 152080);
  float* sElp = (float*)(sm + 152320);    // [6][128]
  float* sPoolp = (float*)(sm + 155392);  // [2][128]

  int b = blockIdx.x, t = threadIdx.x;
  int base = b << 7;
  int l = t & 63, w = t >> 6;
  int wm = w & 7, wn = w >> 3;
  const uint8_t* Sgb = Sg4 + (size_t)base * 64;  // 64 B per row (128 nibbles)

  // ---- phase 0: single u4 read (kept in regs) + shuffle row-sums -> norms ----
  int rown = t >> 3, q8 = t & 7;
  uint2 cw = *(const uint2*)(Sgb + rown * 64 + q8 * 8);  // 16 counts
  {
    uint32_t words[2] = {cw.x, cw.y};
    uint32_t bs = 0;
#pragma unroll
    for (int p = 0; p < 2; ++p) {
      uint32_t wd = words[p];
#pragma unroll
      for (int nb = 0; nb < 8; ++nb) bs += (wd >> (nb * 4)) & 0xF;
    }
    bs += __shfl_xor((int)bs, 1);
    bs += __shfl_xor((int)bs, 2);
    bs += __shfl_xor((int)bs, 4);
    if ((t & 7) == 0) sNorm[rown] = rsqrtf((float)bs + 1.0f);
  }
  for (int i = t; i < 8192; i += 1024) {
    int s = i >> 6, f = i & 63;
    sXrm[s * 65 + f] = x[(size_t)(base + s) * 64 + f];
  }
  {
    int n = t >> 3, blk = t & 7;
    *(uint4*)(sW1t + n * 64 + ((blk ^ (n & 7)) << 3)) = ((const uint4*)w1t)[t];
  }
  if (t < 384) sQ[t] = q[t];
  if (t < 3) {
    sEr[t] = er[b * 3 + t];
    sCh[t] = ch[t];
  }
  __syncthreads();

  // ---- phase 1: S' from retained nibble counts + X transpose->bf16 ----
  {
    int r = rown;
    float nr = sNorm[r];
    int sw = (r & 7) << 3;
    uint32_t words[2] = {cw.x, cw.y};
#pragma unroll
    for (int wd_i = 0; wd_i < 2; ++wd_i) {
      uint32_t wd = words[wd_i];
#pragma unroll
      for (int p = 0; p < 8; p += 2) {
        int s0 = q8 * 16 + wd_i * 8 + p;
        float v0 = ((float)((wd >> (p * 4)) & 0xF) + (r == s0 ? 1.f : 0.f)) * nr * sNorm[s0];
        float v1 =
            ((float)((wd >> (p * 4 + 4)) & 0xF) + (r == s0 + 1 ? 1.f : 0.f)) * nr * sNorm[s0 + 1];
        uint32_t pk = (uint32_t)f2b(v0) | ((uint32_t)f2b(v1) << 16);
        *(uint32_t*)(sS + r * 128 + (s0 ^ sw)) = pk;
      }
    }
  }
  for (int i = t; i < 4096; i += 1024) {
    int f = i >> 6, s = (i & 63) * 2;
    float v0 = sXrm[s * 65 + f] * sNorm[s];
    float v1 = sXrm[(s + 1) * 65 + f] * sNorm[s + 1];
    uint32_t pk = (uint32_t)f2b(v0) | ((uint32_t)f2b(v1) << 16);
    *(uint32_t*)(sXt + (f * 128 + (s ^ ((f & 7) << 3)))) = pk;
  }
  __syncthreads();

  int mrow = wm * 16 + (l & 15);
  int kblk = (l >> 4) * 8;
  int rbase = wm * 16 + (l >> 4) * 4;

  // ---- phase 3: agg1 = S' @ X (nt-split); stage W2t ----
  {
    s8v a4[4];
#pragma unroll
    for (int ks = 0; ks < 4; ++ks) a4[ks] = *(const s8v*)(sS + swz128(mrow, ks * 32 + kblk));
#pragma unroll
    for (int j = 0; j < 2; ++j) {
      int nt = wn * 2 + j;
      f32x4 acc = {0.f, 0.f, 0.f, 0.f};
      int cg = nt * 16 + (l & 15);
#pragma unroll
      for (int ks = 0; ks < 4; ++ks)
        acc = __builtin_amdgcn_mfma_f32_16x16x32_bf16(
            a4[ks], *(const s8v*)(sXt + swz128(cg, ks * 32 + kblk)), acc, 0, 0, 0);
#pragma unroll
      for (int rg = 0; rg < 4; ++rg) sAgg1[swz64(rbase + rg, cg)] = f2b(acc[rg]);
    }
  }
  for (int g = t; g < 2048; g += 1024) {
    int n = g >> 4, blk = g & 15;
    *(uint4*)(sW2t + n * 128 + ((blk ^ (n & 7)) << 3)) = ((const uint4*)w2t)[g];
  }
  __syncthreads();

  // ---- phase 4: h1 = relu(agg1 @ W1 + b1) -> h1^T (nt-split) ----
  {
    s8v a2[2];
#pragma unroll
    for (int ks = 0; ks < 2; ++ks) a2[ks] = *(const s8v*)(sAgg1 + swz64(mrow, ks * 32 + kblk));
#pragma unroll
    for (int j = 0; j < 4; ++j) {
      int nt = wn * 4 + j;
      int cg = nt * 16 + (l & 15);
      float bv = b1[cg];
      f32x4 acc = {bv, bv, bv, bv};
#pragma unroll
      for (int ks = 0; ks < 2; ++ks)
        acc = __builtin_amdgcn_mfma_f32_16x16x32_bf16(
            a2[ks], *(const s8v*)(sW1t + swz64(cg, ks * 32 + kblk)), acc, 0, 0, 0);
      u16 h0 = f2b(fmaxf(acc[0], 0.f)), h1v = f2b(fmaxf(acc[1], 0.f));
      u16 h2 = f2b(fmaxf(acc[2], 0.f)), h3 = f2b(fmaxf(acc[3], 0.f));
      uint2 pk;
      pk.x = (uint32_t)h0 | ((uint32_t)h1v << 16);
      pk.y = (uint32_t)h2 | ((uint32_t)h3 << 16);
      *(uint2*)(sB2 + swz128(cg, rbase)) = pk;
    }
  }
  __syncthreads();

  // ---- phase 5: agg2 = S' @ h1 (nt-split) ----
  {
    s8v a4[4];
#pragma unroll
    for (int ks = 0; ks < 4; ++ks) a4[ks] = *(const s8v*)(sS + swz128(mrow, ks * 32 + kblk));
#pragma unroll
    for (int j = 0; j < 4; ++j) {
      int nt = wn * 4 + j;
      f32x4 acc = {0.f, 0.f, 0.f, 0.f};
      int cg = nt * 16 + (l & 15);
#pragma unroll
      for (int ks = 0; ks < 4; ++ks)
        acc = __builtin_amdgcn_mfma_f32_16x16x32_bf16(
            a4[ks], *(const s8v*)(sB2 + swz128(cg, ks * 32 + kblk)), acc, 0, 0, 0);
#pragma unroll
      for (int rg = 0; rg < 4; ++rg) sAgg2[swz128(rbase + rg, cg)] = f2b(acc[rg]);
    }
  }
  __syncthreads();

  // ---- phase 6: poi = agg2 @ W2 + b2 -> sP + sPt (nt-split) ----
  {
    s8v a4[4];
#pragma unroll
    for (int ks = 0; ks < 4; ++ks) a4[ks] = *(const s8v*)(sAgg2 + swz128(mrow, ks * 32 + kblk));
#pragma unroll
    for (int j = 0; j < 4; ++j) {
      int nt = wn * 4 + j;
      int cg = nt * 16 + (l & 15);
      float bv = b2[cg];
      f32x4 acc = {bv, bv, bv, bv};
#pragma unroll
      for (int ks = 0; ks < 4; ++ks)
        acc = __builtin_amdgcn_mfma_f32_16x16x32_bf16(
            a4[ks], *(const s8v*)(sW2t + swz128(cg, ks * 32 + kblk)), acc, 0, 0, 0);
      u16 p0 = f2b(acc[0]), p1 = f2b(acc[1]), p2 = f2b(acc[2]), p3 = f2b(acc[3]);
#pragma unroll
      for (int rg = 0; rg < 4; ++rg)
        sP[swz128(rbase + rg, cg)] = (rg == 0) ? p0 : (rg == 1) ? p1 : (rg == 2) ? p2 : p3;
      uint2 pk;
      pk.x = (uint32_t)p0 | ((uint32_t)p1 << 16);
      pk.y = (uint32_t)p2 | ((uint32_t)p3 << 16);
      *(uint2*)(sPt + swz128(cg, rbase)) = pk;
    }
  }
  __syncthreads();

  // ---- tail A: pool partials (t<256) || el partials (256..1023) ----
  if (t < 256) {
    int c = t & 127, kh = t >> 7;
    float s = 0.f;
    const u16* rowp = sPt + c * 128;
    int sw = (c & 7) << 3;
#pragma unroll
    for (int k8 = kh * 8; k8 < kh * 8 + 8; ++k8) {
      s8v v = *(const s8v*)(rowp + ((k8 * 8) ^ sw));
#pragma unroll
      for (int j = 0; j < 8; ++j) s += b2f((u16)v[j]);
    }
    sPoolp[kh * 128 + c] = s;
  } else {
    int task = t - 256;
    int r = task & 127, hk = task >> 7;
    int h = hk >> 1, kh = hk & 1;
    int sw = (r & 7) << 3;
    const u16* rowp = sP + r * 128;
    const float* qh = &sQ[h * 128];
    float d = 0.f;
#pragma unroll
    for (int k8 = kh * 8; k8 < kh * 8 + 8; ++k8) {
      int c8 = (k8 * 8) ^ sw;
      s8v v = *(const s8v*)(rowp + c8);
#pragma unroll
      for (int j = 0; j < 8; ++j) d += b2f((u16)v[j]) * qh[c8 + j];
    }
    sElp[hk * 128 + r] = d;
  }
  __syncthreads();

  if (t < 128) {
    float s = sPoolp[t] + sPoolp[128 + t];
    sPool[t] = s;
    poi_pool[b * 128 + t] = s * (1.0f / 128.0f);
  }
  if (t >= 512 && t < 896) {
    int tt = t - 512;
    int h = tt >> 7, r = tt & 127;
    float e = sElp[h * 256 + r] + sElp[h * 256 + 128 + r] + sCh[h] + sEr[h];
    sAl[h * 128 + r] = (e > 0.f) ? e : 0.2f * e;
  }
  __syncthreads();

  if (t < 192) {
    int h = t >> 6, ll = t & 63;
    float v0 = sAl[h * 128 + ll], v1 = sAl[h * 128 + 64 + ll];
    float m = fmaxf(v0, v1);
    for (int off = 32; off > 0; off >>= 1) m = fmaxf(m, __shfl_xor(m, off));
    float x0 = __expf(v0 - m), x1 = __expf(v1 - m);
    float s = x0 + x1;
    for (int off = 32; off > 0; off >>= 1) s += __shfl_xor(s, off);
    float inv = 1.0f / s;
    sAl[h * 128 + ll] = x0 * inv;
    sAl[h * 128 + 64 + ll] = x1 * inv;
  }
  __syncthreads();

  if (t < 768) {
    int c = t & 127, hk = t >> 7;
    int hh = hk >> 1, kh = hk & 1;
    int sw = (c & 7) << 3;
    const u16* rowp = sPt + c * 128;
    const float* al = &sAl[hh * 128];
    float s = 0.f;
#pragma unroll
    for (int k8 = kh * 8; k8 < kh * 8 + 8; ++k8) {
      int r8 = (k8 * 8) ^ sw;
      s8v v = *(const s8v*)(rowp + r8);
#pragma unroll
      for (int j = 0; j < 8; ++j) s += b2f((u16)v[j]) * al[r8 + j];
    }
    sElp[hk * 128 + c] = s;
  }
  __syncthreads();

  if (t < 384) {
    int hh = t >> 7, c = t & 127;
    pooled[((size_t)b * 3 + hh) * 128 + c] = sElp[hh * 256 + c] + sElp[hh * 256 + 128 + c];
  }
  __syncthreads();

  float hv = 0.f, pv = 0.f;
  if (t < 128) {
    hv = hrs[base + t];
    pv = sPool[t] * (1.0f / 128.0f);
    sQ[t] = hv * hv + pv * pv;
  }
  __syncthreads();
  if (t < 64) {
    float v = sQ[t] + sQ[t + 64];
    for (int off = 32; off > 0; off >>= 1) v += __shfl_xor(v, off);
    if (t == 0) sQ[0] = rsqrtf(v);
  }
  __syncthreads();
  if (t < 128) {
    float rn = sQ[0];
    mfnb[b * 256 + t] = f2b(hv * rn);
    mfnb[b * 256 + 128 + t] = f2b(pv * rn);
  }
}

// ===================== med via MFMA + fused row-count =====================
__global__ void __launch_bounds__(256) k_med(const u16* __restrict__ mfnb,
                                             const float* __restrict__ T0p,
                                             float* __restrict__ med,
                                             int* __restrict__ rowcnt) {
  __shared__ u16 sA[32 * 256];
  __shared__ u16 sB[32 * 256];
  int bi = blockIdx.x >> 4, bj = blockIdx.x & 15;
  int t = threadIdx.x;
  const uint4* srcA = (const uint4*)(mfnb + (size_t)bi * 32 * 256);
  const uint4* srcB = (const uint4*)(mfnb + (size_t)bj * 32 * 256);
  for (int g = t; g < 1024; g += 256) {
    int r = g >> 5, blk = g & 31;
    int db = (blk & 24) | ((blk ^ (r & 7)) & 7);
    uint4 va = srcA[g];
    uint4 vb = srcB[g];
    *(uint4*)(sA + r * 256 + db * 8) = va;
    *(uint4*)(sB + r * 256 + db * 8) = vb;
  }
  __syncthreads();
  int l = t & 63, w = t >> 6;
  int wr = w >> 1, wc = w & 1;
  int arow = wr * 16 + (l & 15);
  int brow = wc * 16 + (l & 15);
  int kblk = (l >> 4) * 8;
  f32x4 acc = {0.f, 0.f, 0.f, 0.f};
#pragma unroll
  for (int ks = 0; ks < 8; ++ks) {
    int kc = ks * 32 + kblk;
    s8v a = *(const s8v*)(sA + arow * 256 + (kc ^ ((arow & 7) << 3)));
    s8v bb = *(const s8v*)(sB + brow * 256 + (kc ^ ((brow & 7) << 3)));
    acc = __builtin_amdgcn_mfma_f32_16x16x32_bf16(a, bb, acc, 0, 0, 0);
  }
  int row0 = bi * 32 + wr * 16 + (l >> 4) * 4;
  int col = bj * 32 + wc * 16 + (l & 15);
  float T0 = *T0p;
  int cnt4[4];
#pragma unroll
  for (int rg = 0; rg < 4; ++rg) {
    float m = (acc[rg] + 1.0f) * 0.5f;
    med[(size_t)(row0 + rg) * 512 + col] = m;
    cnt4[rg] = (m >= T0 || (row0 + rg) == col) ? 1 : 0;
  }
#pragma unroll
  for (int off = 1; off < 16; off <<= 1) {
#pragma unroll
    for (int rg = 0; rg < 4; ++rg) cnt4[rg] += __shfl_xor(cnt4[rg], off);
  }
  if ((l & 15) == 0) {
#pragma unroll
    for (int rg = 0; rg < 4; ++rg) atomicAdd(&rowcnt[row0 + rg], cnt4[rg]);
  }
}

// ===================== slim epilogue: sparse Aagg + folded 768->16 dot =====================
__global__ void __launch_bounds__(256) k_epilogue(
    const float* __restrict__ med, const float* __restrict__ T0p,
    const int* __restrict__ rowcnt, const float* __restrict__ hrs,
    const float* __restrict__ pool, const float* __restrict__ pooled,
    const float* __restrict__ Afold, const float* __restrict__ bias_out,
    float* __restrict__ out) {
  __shared__ float sMedRow[512];
  __shared__ float sIn[6][128];
  __shared__ float sRed[16][16];
  __shared__ int sNbr[64];
  __shared__ float sDw[64];
  __shared__ int sNnz;
  int i = blockIdx.x, t = threadIdx.x;
  float T0 = *T0p;

  for (int j = t; j < 512; j += 256) sMedRow[j] = med[(size_t)i * 512 + j];
  if (t < 128) sIn[0][t] = hrs[i * 128 + t];
  for (int k = t; k < 384; k += 256) sIn[3 + (k >> 7)][k & 127] = pooled[(size_t)i * 384 + k];
  __syncthreads();

  if (t < 64) {
    int cnt = 0, flags = 0;
#pragma unroll
    for (int k = 0; k < 8; ++k) {
      int j = t * 8 + k;
      if (sMedRow[j] >= T0 || j == i) {
        flags |= 1 << k;
        ++cnt;
      }
    }
    int off = cnt;
    for (int d = 1; d < 64; d <<= 1) {
      int v = __shfl_up(off, d);
      if (t >= d) off += v;
    }
    off -= cnt;
    int pos = off;
#pragma unroll
    for (int k = 0; k < 8; ++k)
      if (flags & (1 << k)) {
        int j = t * 8 + k;
        if (pos < 64) {
          sNbr[pos] = j;
          sDw[pos] = rsqrtf((float)rowcnt[j]);
        }
        ++pos;
      }
    if (t == 63) sNnz = off + cnt;
  }
  __syncthreads();

  {
    int half = t >> 7, c = t & 127;
    float di = rsqrtf((float)rowcnt[i]);
    const float* srcm = half ? pool : hrs;
    float acc = 0.f;
    int nnz = sNnz;
    if (nnz <= 64) {
      for (int n = 0; n < nnz; ++n) acc += sDw[n] * srcm[sNbr[n] * 128 + c];
    } else {
      for (int j = 0; j < 512; ++j)
        if (sMedRow[j] >= T0 || j == i) acc += rsqrtf((float)rowcnt[j]) * srcm[j * 128 + c];
    }
    sIn[1 + half][c] = acc * di;
  }
  __syncthreads();

  {
    int o = t >> 4, chunk = t & 15;
    int c0 = chunk * 8;
    float acc = 0.f;
#pragma unroll
    for (int m = 0; m < 6; ++m) {
      const float* A = Afold + m * 2048;
      const float* xm = sIn[m];
#pragma unroll
      for (int k = 0; k < 8; ++k) acc += xm[c0 + k] * A[(c0 + k) * 16 + o];
    }
    sRed[o][chunk] = acc;
  }
  __syncthreads();
  if (t < 16) {
    float acc = bias_out[t];
#pragma unroll
    for (int j = 0; j < 16; ++j) acc += sRed[t][j];
    out[i * 16 + t] = acc;
  }
}

// ===================== host =====================
extern "C" void kernel_launch(void* const* d_in, const int* in_sizes, int n_in,
                              void* d_out, int out_size, void* d_ws, size_t ws_size,
                              hipStream_t stream) {
  const float* poi_x = (const float*)d_in[0];
  const float* img = (const float*)d_in[1];
  const int* edges = (const int*)d_in[2];
  const float* T0p = (const float*)d_in[4];
  const float* W1 = (const float*)d_in[5];
  const float* b1 = (const float*)d_in[6];
  const float* W2 = (const float*)d_in[7];
  const float* b2 = (const float*)d_in[8];
  const float* Whrs = (const float*)d_in[9];
  const float* bhrs = (const float*)d_in[10];
  const float* Wph = (const float*)d_in[11];
  const float* bph = (const float*)d_in[12];
  const float* Wpp = (const float*)d_in[13];
  const float* bpp = (const float*)d_in[14];
  const float* Wg_in = (const float*)d_in[15];
  const float* al_in = (const float*)d_in[16];
  const float* ar_in = (const float*)d_in[17];
  const float* bg_in = (const float*)d_in[18];
  const float* Wg_w = (const float*)d_in[19];
  const float* bg_w = (const float*)d_in[22];
  const float* Wh1 = (const float*)d_in[23];
  const float* bh1 = (const float*)d_in[24];
  const float* Wp1 = (const float*)d_in[25];
  const float* bp1 = (const float*)d_in[26];
  const float* Wfc = (const float*)d_in[27];
  const float* bfc = (const float*)d_in[28];

  const int* esrc = edges;
  const int* edst = edges + EE;

  char* ws = (char*)d_ws;
  size_t off = 0;
  auto alloc = [&](size_t nbytes) -> char* {
    char* p = ws + off;
    off += (nbytes + 255) & ~(size_t)255;
    return p;
  };
  uint8_t* Sg4 = (uint8_t*)alloc((size_t)NN * 64);  // 4.2 MB nibble count table
  u16* w1t = (u16*)alloc(8192 * 2);
  u16* w2t = (u16*)alloc(16384 * 2);
  float* hrs = (float*)alloc(512 * 128 * 4);
  float* er = (float*)alloc(512 * 3 * 4);
  float* wv = (float*)alloc(384 * 4);
  float* q = (float*)alloc(384 * 4);
  float* chv = (float*)alloc(16);
  float* Afold = (float*)alloc(6 * 2048 * 4);
  float* bias_out = (float*)alloc(16 * 4);
  float* pool = (float*)alloc(512 * 128 * 4);
  float* pooled = (float*)alloc((size_t)1536 * 128 * 4);
  u16* mfnb = (u16*)alloc(512 * 256 * 2);
  int* rowcnt = (int*)alloc(512 * 4);

  float* out = (float*)d_out;
  float* med = out + 512 * 16;

  hipMemsetAsync(Sg4, 0, (size_t)NN * 64, stream);

  size_t dynf = 156416;
  hipFuncSetAttribute((const void*)k_gcn_fused, hipFuncAttributeMaxDynamicSharedMemorySize,
                      (int)dynf);

  k_front<<<801, 1024, 0, stream>>>(esrc, edst, (uint32_t*)Sg4, W1, W2, Wg_in, al_in, ar_in,
                                    Wpp, bpp, w1t, w2t, wv, q, chv, Wg_w, Wfc, bph, bg_in,
                                    rowcnt, img, Whrs, bhrs, Wph, hrs, er, Wh1, Wp1, bfc, bh1,
                                    bp1, bg_w, Afold, bias_out);
  k_gcn_fused<<<512, 1024, dynf, stream>>>(poi_x, b1, b2, Sg4, q, chv, er, hrs, w1t, w2t, pool,
                                           pooled, mfnb);
  k_med<<<256, 256, 0, stream>>>(mfnb, T0p, med, rowcnt);
  k_epilogue<<<512, 256, 0, stream>>>(med, T0p, rowcnt, hrs, pool, pooled, Afold, bias_out,
                                      out);

  (void)in_sizes; (void)n_in; (void)out_size; (void)ws_size;
}

// Round 19
// 121.789 us; speedup vs baseline: 1.7337x; 1.1162x over previous
//
#include <hip/hip_runtime.h>
#include <stdint.h>

#define NN 65536
#define EE 524288
#define BB 512

typedef unsigned short u16;
typedef __attribute__((ext_vector_type(8))) short s8v;    // 8 bf16 (4 VGPRs)
typedef __attribute__((ext_vector_type(4))) float f32x4;  // MFMA acc

__device__ __forceinline__ u16 f2b(float f) {
  union { float f; uint32_t u; } a{f};
  uint32_t r = a.u + 0x7fff + ((a.u >> 16) & 1);
  return (u16)(r >> 16);
}
__device__ __forceinline__ float b2f(u16 v) {
  union { uint32_t u; float f; } a{(uint32_t)v << 16};
  return a.f;
}
__device__ __forceinline__ int swz128(int r, int c) { return r * 128 + (c ^ ((r & 7) << 3)); }
__device__ __forceinline__ int swz64(int r, int c) { return r * 64 + (c ^ ((r & 7) << 3)); }

// ===================== k_front: hrs (0..255) | scatter x4 (256..383) | transposes (384..407)
//            | wv/q/ch (408) | A_hrs (409) | A_T (410,411) | A_pld (412..414) | bias (415)
//            | rowcnt0 (416) ====
// Sg is a 4-bit count table: slot idx = d*128 + (s&127); word = idx>>3, nibble = idx&7.
__global__ void __launch_bounds__(1024) k_front(
    const int* __restrict__ src, const int* __restrict__ dst, uint32_t* __restrict__ Sg,
    const float* __restrict__ W1, const float* __restrict__ W2,
    const float* __restrict__ Wg_in, const float* __restrict__ al_in,
    const float* __restrict__ ar_in, const float* __restrict__ Wpp,
    const float* __restrict__ bpp, u16* __restrict__ w1t, u16* __restrict__ w2t,
    float* __restrict__ wv, float* __restrict__ q, float* __restrict__ ch,
    const float* __restrict__ Wg_w, const float* __restrict__ Wfc,
    const float* __restrict__ bph, const float* __restrict__ bg_in,
    int* __restrict__ rowcnt, const float* __restrict__ img, const float* __restrict__ Whrs,
    const float* __restrict__ bhrs, const float* __restrict__ Wph, float* __restrict__ hrs,
    float* __restrict__ er, const float* __restrict__ Wh1, const float* __restrict__ Wp1,
    const float* __restrict__ bfc, const float* __restrict__ bh1,
    const float* __restrict__ bp1, const float* __restrict__ bg_w,
    float* __restrict__ Afold, float* __restrict__ bias_out) {
  __shared__ char smem[23040];
  int blk = blockIdx.x, t = threadIdx.x;

  if (blk < 256) {
    // ---- hrs + er ----
    float* sI = (float*)smem;
    float(*sRed)[128] = (float(*)[128])(smem + 16384);
    float(*sHrs)[128] = (float(*)[128])(smem + 20480);
    float(*sPh)[128] = (float(*)[128])(smem + 21504);
    int r0 = blk * 2;
    const float4* gsrc = (const float4*)(img + (size_t)r0 * 2048);
    ((float4*)sI)[t] = gsrc[t];
    __syncthreads();
    int c = t & 127, g = t >> 7;
    int row = g & 1, ks = g >> 1;
    const float* s = sI + row * 2048 + ks * 512;
    const float* W = Whrs + (size_t)(ks * 512) * 128 + c;
    float a0 = 0.f, a1 = 0.f, a2 = 0.f, a3 = 0.f;
    for (int k = 0; k < 512; k += 4) {
      a0 += s[k] * W[(size_t)k * 128];
      a1 += s[k + 1] * W[(size_t)(k + 1) * 128];
      a2 += s[k + 2] * W[(size_t)(k + 2) * 128];
      a3 += s[k + 3] * W[(size_t)(k + 3) * 128];
    }
    sRed[g][c] = (a0 + a1) + (a2 + a3);
    __syncthreads();
    if (t < 256) {
      int rr = t >> 7, cc = t & 127;
      float v = sRed[rr][cc] + sRed[rr + 2][cc] + sRed[rr + 4][cc] + sRed[rr + 6][cc] + bhrs[cc];
      hrs[(r0 + rr) * 128 + cc] = v;
      sHrs[rr][cc] = v;
    }
    __syncthreads();
    if (t < 256) {
      int rr = t >> 7, cc = t & 127;
      float acc = bph[cc];
#pragma unroll 4
      for (int k = 0; k < 128; ++k) acc += sHrs[rr][k] * Wph[k * 128 + cc];
      sPh[rr][cc] = acc;
    }
    __syncthreads();
    if (t < 6) {
      int rr = t / 3, h = t % 3;
      float s2 = 0.f;
#pragma unroll 4
      for (int k = 0; k < 128; ++k) s2 += sPh[rr][k] * wv[h * 128 + k];
      er[(r0 + rr) * 3 + h] = s2;
    }
  } else if (blk < 384) {
    // ---- edge scatter: 4 edges/thread (int4 loads, 4 independent atomics in flight) ----
    int e4 = (blk - 256) * 1024 + t;
    int4 s4 = ((const int4*)src)[e4];
    int4 d4 = ((const int4*)dst)[e4];
    size_t i0 = (size_t)d4.x * 128 + (s4.x & 127);
    size_t i1 = (size_t)d4.y * 128 + (s4.y & 127);
    size_t i2 = (size_t)d4.z * 128 + (s4.z & 127);
    size_t i3 = (size_t)d4.w * 128 + (s4.w & 127);
    atomicAdd(&Sg[i0 >> 3], 1u << ((i0 & 7) * 4));
    atomicAdd(&Sg[i1 >> 3], 1u << ((i1 & 7) * 4));
    atomicAdd(&Sg[i2 >> 3], 1u << ((i2 & 7) * 4));
    atomicAdd(&Sg[i3 >> 3], 1u << ((i3 & 7) * 4));
  } else if (blk < 408) {
    // ---- W1/W2 transpose -> bf16 ----
    int i = (blk - 384) * 1024 + t;  // 24576
    if (i < 8192) {
      int n = i >> 6, k = i & 63;
      w1t[i] = f2b(W1[k * 128 + n]);
    } else {
      int j = i - 8192;
      int n = j >> 7, k = j & 127;
      w2t[j] = f2b(W2[k * 128 + n]);
    }
  } else if (blk == 408) {
    // ---- wv / q / ch ----
    float* su = (float*)smem;
    for (int i = t; i < 384; i += 1024) {
      int h = i >> 7, k = i & 127;
      float s = 0.f, sw = 0.f;
#pragma unroll 4
      for (int c = 0; c < 128; ++c) {
        float g = Wg_in[k * 384 + h * 128 + c];
        s += g * al_in[h * 128 + c];
        sw += g * ar_in[h * 128 + c];
      }
      su[i] = s;
      wv[i] = sw;
    }
    __syncthreads();
    for (int i = t; i < 384; i += 1024) {
      int h = i >> 7, j = i & 127;
      float s = 0.f;
#pragma unroll 4
      for (int k = 0; k < 128; ++k) s += Wpp[j * 128 + k] * su[h * 128 + k];
      q[i] = s;
    }
    if (t < 3) {
      float s = 0.f;
#pragma unroll 4
      for (int k = 0; k < 128; ++k) s += bpp[k] * su[t * 128 + k];
      ch[t] = s;
    }
  } else if (blk == 409) {
    float* sW = (float*)smem;
    float* sB = (float*)(smem + 8192);
    for (int i = t; i < 2048; i += 1024) sW[i] = Wfc[i];
    __syncthreads();
    for (int i = t; i < 2048; i += 1024) {
      int m = i >> 4, o = i & 15;
      const float* wr = Wg_w + (size_t)m * 384;
      float acc = 0.f;
#pragma unroll 4
      for (int j = 0; j < 128; ++j) {
        float g = (wr[j] + wr[128 + j] + wr[256 + j]) * (1.0f / 3.0f);
        acc += g * sW[j * 16 + o];
      }
      sB[i] = acc;
    }
    __syncthreads();
    for (int i = t; i < 2048; i += 1024) {
      int k = i >> 4, o = i & 15;
      const float* lr = Wph + (size_t)k * 128;
      float acc = 0.f;
#pragma unroll 4
      for (int m = 0; m < 128; ++m) acc += lr[m] * sB[m * 16 + o];
      Afold[i] = acc;
    }
  } else if (blk == 410 || blk == 411) {
    float* sW = (float*)smem;
    int mat = blk - 409;
    const float* src_w = (mat == 1) ? (Wfc + 384 * 16) : (Wfc + 128 * 16);
    for (int i = t; i < 2048; i += 1024) sW[i] = src_w[i];
    __syncthreads();
    const float* L = (mat == 1) ? Wh1 : Wp1;
    for (int i = t; i < 2048; i += 1024) {
      int k = i >> 4, o = i & 15;
      const float* lr = L + (size_t)k * 128;
      float acc = 0.f;
#pragma unroll 4
      for (int m = 0; m < 128; ++m) acc += lr[m] * sW[m * 16 + o];
      Afold[(size_t)mat * 2048 + i] = acc;
    }
  } else if (blk < 415) {
    int h = blk - 412;
    float* sW = (float*)smem;
    float* sB = (float*)(smem + 8192);
    for (int i = t; i < 2048; i += 1024) sW[i] = Wfc[256 * 16 + i];
    __syncthreads();
    for (int i = t; i < 2048; i += 1024) {
      int m = i >> 4, o = i & 15;
      const float* wr = Wg_in + (size_t)m * 384 + h * 128;
      float acc = 0.f;
#pragma unroll 4
      for (int c = 0; c < 128; ++c) acc += wr[c] * sW[c * 16 + o];
      sB[i] = acc;
    }
    __syncthreads();
    for (int i = t; i < 2048; i += 1024) {
      int k = i >> 4, o = i & 15;
      const float* lr = Wpp + (size_t)k * 128;
      float acc = 0.f;
#pragma unroll 4
      for (int m = 0; m < 128; ++m) acc += lr[m] * sB[m * 16 + o];
      Afold[(size_t)(3 + h) * 2048 + i] = acc * (1.0f / 3.0f);
    }
  } else if (blk == 415) {
    float(*sD)[128] = (float(*)[128])smem;
    float(*sE)[128] = (float(*)[128])(smem + 4096);
    float* sDv = (float*)(smem + 8192);
    float* sEv = (float*)(smem + 8704);
    float(*sRed2)[16] = (float(*)[16])(smem + 9216);
    int j = t & 127, ks = t >> 7;
    {
      float acc = 0.f;
#pragma unroll
      for (int k = ks * 16; k < ks * 16 + 16; ++k) {
        float g = (Wg_w[k * 384 + j] + Wg_w[k * 384 + 128 + j] + Wg_w[k * 384 + 256 + j]) *
                  (1.0f / 3.0f);
        acc += bph[k] * g;
      }
      sD[ks][j] = acc;
      float e = 0.f;
      for (int h = 0; h < 3; ++h) {
#pragma unroll
        for (int m = ks * 16; m < ks * 16 + 16; ++m) e += bpp[m] * Wg_in[m * 384 + h * 128 + j];
      }
      sE[ks][j] = e;
    }
    __syncthreads();
    if (t < 128) {
      float d = 0.f, ev = 0.f;
#pragma unroll
      for (int s = 0; s < 8; ++s) {
        d += sD[s][t];
        ev += sE[s][t];
      }
      sDv[t] = d;
      float g0in = (bg_in[t] + bg_in[128 + t] + bg_in[256 + t]) * (1.0f / 3.0f);
      sEv[t] = ev * (1.0f / 3.0f) + g0in;
    }
    __syncthreads();
    if (t < 256) {
      int o = t & 15, chunk = t >> 4;
      int j0 = chunk * 8;
      float acc = 0.f;
#pragma unroll
      for (int jj = 0; jj < 8; ++jj) {
        int jx = j0 + jj;
        float g0w = (bg_w[jx] + bg_w[128 + jx] + bg_w[256 + jx]) * (1.0f / 3.0f);
        acc += (sDv[jx] + g0w) * Wfc[jx * 16 + o];
        acc += bp1[jx] * Wfc[(128 + jx) * 16 + o];
        acc += sEv[jx] * Wfc[(256 + jx) * 16 + o];
        acc += bh1[jx] * Wfc[(384 + jx) * 16 + o];
      }
      sRed2[o][chunk] = acc;
    }
    __syncthreads();
    if (t < 16) {
      float a = bfc[t];
#pragma unroll
      for (int c = 0; c < 16; ++c) a += sRed2[t][c];
      bias_out[t] = a;
    }
  } else {
    if (t < 512) rowcnt[t] = 0;
  }
}

// ===================== FUSED GCN via dense S' + MFMA (u4 counts, 1024 thr) ====
__global__ void __launch_bounds__(1024) k_gcn_fused(
    const float* __restrict__ x, const float* __restrict__ b1, const float* __restrict__ b2,
    const uint8_t* __restrict__ Sg4, const float* __restrict__ q, const float* __restrict__ ch,
    const float* __restrict__ er, const float* __restrict__ hrs,
    const u16* __restrict__ w1t, const u16* __restrict__ w2t, float* __restrict__ poi_pool,
    float* __restrict__ pooled, u16* __restrict__ mfnb) {
  extern __shared__ char sm[];
  u16* sS = (u16*)sm;
  u16* sB2 = (u16*)(sm + 32768);
  u16* sPt = (u16*)(sm + 32768);
  u16* sXt = (u16*)(sm + 65536);
  u16* sAgg1 = (u16*)(sm + 81920);
  u16* sW1t = (u16*)(sm + 98304);
  float* sXrm = (float*)(sm + 114688);
  u16* sW2t = (u16*)(sm + 114688);
  u16* sAgg2 = (u16*)(sm + 65536);
  u16* sP = (u16*)sm;
  float* sNorm = (float*)(sm + 147968);
  float* sQ = (float*)(sm + 148480);
  float* sAl = (float*)(sm + 150016);
  float* sPool = (float*)(sm + 151552);
  float* sEr = (float*)(sm + 152064);
  float* sCh = (float*)(sm + 152080);
  float* sElp = (float*)(sm + 152320);    // [6][128]
  float* sPoolp = (float*)(sm + 155392);  // [2][128]

  int b = blockIdx.x, t = threadIdx.x;
  int base = b << 7;
  int l = t & 63, w = t >> 6;
  int wm = w & 7, wn = w >> 3;
  const uint8_t* Sgb = Sg4 + (size_t)base * 64;  // 64 B per row (128 nibbles)

  // ---- phase 0: single u4 read (kept in regs) + shuffle row-sums -> norms ----
  int rown = t >> 3, q8 = t & 7;
  uint2 cw = *(const uint2*)(Sgb + rown * 64 + q8 * 8);  // 16 counts
  {
    uint32_t words[2] = {cw.x, cw.y};
    uint32_t bs = 0;
#pragma unroll
    for (int p = 0; p < 2; ++p) {
      uint32_t wd = words[p];
#pragma unroll
      for (int nb = 0; nb < 8; ++nb) bs += (wd >> (nb * 4)) & 0xF;
    }
    bs += __shfl_xor((int)bs, 1);
    bs += __shfl_xor((int)bs, 2);
    bs += __shfl_xor((int)bs, 4);
    if ((t & 7) == 0) sNorm[rown] = rsqrtf((float)bs + 1.0f);
  }
  for (int i = t; i < 8192; i += 1024) {
    int s = i >> 6, f = i & 63;
    sXrm[s * 65 + f] = x[(size_t)(base + s) * 64 + f];
  }
  {
    int n = t >> 3, blk = t & 7;
    *(uint4*)(sW1t + n * 64 + ((blk ^ (n & 7)) << 3)) = ((const uint4*)w1t)[t];
  }
  if (t < 384) sQ[t] = q[t];
  if (t < 3) {
    sEr[t] = er[b * 3 + t];
    sCh[t] = ch[t];
  }
  __syncthreads();

  // ---- phase 1: S' from retained nibble counts + X transpose->bf16 ----
  {
    int r = rown;
    float nr = sNorm[r];
    int sw = (r & 7) << 3;
    uint32_t words[2] = {cw.x, cw.y};
#pragma unroll
    for (int wd_i = 0; wd_i < 2; ++wd_i) {
      uint32_t wd = words[wd_i];
#pragma unroll
      for (int p = 0; p < 8; p += 2) {
        int s0 = q8 * 16 + wd_i * 8 + p;
        float v0 = ((float)((wd >> (p * 4)) & 0xF) + (r == s0 ? 1.f : 0.f)) * nr * sNorm[s0];
        float v1 =
            ((float)((wd >> (p * 4 + 4)) & 0xF) + (r == s0 + 1 ? 1.f : 0.f)) * nr * sNorm[s0 + 1];
        uint32_t pk = (uint32_t)f2b(v0) | ((uint32_t)f2b(v1) << 16);
        *(uint32_t*)(sS + r * 128 + (s0 ^ sw)) = pk;
      }
    }
  }
  for (int i = t; i < 4096; i += 1024) {
    int f = i >> 6, s = (i & 63) * 2;
    float v0 = sXrm[s * 65 + f] * sNorm[s];
    float v1 = sXrm[(s + 1) * 65 + f] * sNorm[s + 1];
    uint32_t pk = (uint32_t)f2b(v0) | ((uint32_t)f2b(v1) << 16);
    *(uint32_t*)(sXt + (f * 128 + (s ^ ((f & 7) << 3)))) = pk;
  }
  __syncthreads();

  int mrow = wm * 16 + (l & 15);
  int kblk = (l >> 4) * 8;
  int rbase = wm * 16 + (l >> 4) * 4;

  // ---- phase 3: agg1 = S' @ X (nt-split); stage W2t ----
  {
    s8v a4[4];
#pragma unroll
    for (int ks = 0; ks < 4; ++ks) a4[ks] = *(const s8v*)(sS + swz128(mrow, ks * 32 + kblk));
#pragma unroll
    for (int j = 0; j < 2; ++j) {
      int nt = wn * 2 + j;
      f32x4 acc = {0.f, 0.f, 0.f, 0.f};
      int cg = nt * 16 + (l & 15);
#pragma unroll
      for (int ks = 0; ks < 4; ++ks)
        acc = __builtin_amdgcn_mfma_f32_16x16x32_bf16(
            a4[ks], *(const s8v*)(sXt + swz128(cg, ks * 32 + kblk)), acc, 0, 0, 0);
#pragma unroll
      for (int rg = 0; rg < 4; ++rg) sAgg1[swz64(rbase + rg, cg)] = f2b(acc[rg]);
    }
  }
  for (int g = t; g < 2048; g += 1024) {
    int n = g >> 4, blk = g & 15;
    *(uint4*)(sW2t + n * 128 + ((blk ^ (n & 7)) << 3)) = ((const uint4*)w2t)[g];
  }
  __syncthreads();

  // ---- phase 4: h1 = relu(agg1 @ W1 + b1) -> h1^T (nt-split) ----
  {
    s8v a2[2];
#pragma unroll
    for (int ks = 0; ks < 2; ++ks) a2[ks] = *(const s8v*)(sAgg1 + swz64(mrow, ks * 32 + kblk));
#pragma unroll
    for (int j = 0; j < 4; ++j) {
      int nt = wn * 4 + j;
      int cg = nt * 16 + (l & 15);
      float bv = b1[cg];
      f32x4 acc = {bv, bv, bv, bv};
#pragma unroll
      for (int ks = 0; ks < 2; ++ks)
        acc = __builtin_amdgcn_mfma_f32_16x16x32_bf16(
            a2[ks], *(const s8v*)(sW1t + swz64(cg, ks * 32 + kblk)), acc, 0, 0, 0);
      u16 h0 = f2b(fmaxf(acc[0], 0.f)), h1v = f2b(fmaxf(acc[1], 0.f));
      u16 h2 = f2b(fmaxf(acc[2], 0.f)), h3 = f2b(fmaxf(acc[3], 0.f));
      uint2 pk;
      pk.x = (uint32_t)h0 | ((uint32_t)h1v << 16);
      pk.y = (uint32_t)h2 | ((uint32_t)h3 << 16);
      *(uint2*)(sB2 + swz128(cg, rbase)) = pk;
    }
  }
  __syncthreads();

  // ---- phase 5: agg2 = S' @ h1 (nt-split) ----
  {
    s8v a4[4];
#pragma unroll
    for (int ks = 0; ks < 4; ++ks) a4[ks] = *(const s8v*)(sS + swz128(mrow, ks * 32 + kblk));
#pragma unroll
    for (int j = 0; j < 4; ++j) {
      int nt = wn * 4 + j;
      f32x4 acc = {0.f, 0.f, 0.f, 0.f};
      int cg = nt * 16 + (l & 15);
#pragma unroll
      for (int ks = 0; ks < 4; ++ks)
        acc = __builtin_amdgcn_mfma_f32_16x16x32_bf16(
            a4[ks], *(const s8v*)(sB2 + swz128(cg, ks * 32 + kblk)), acc, 0, 0, 0);
#pragma unroll
      for (int rg = 0; rg < 4; ++rg) sAgg2[swz128(rbase + rg, cg)] = f2b(acc[rg]);
    }
  }
  __syncthreads();

  // ---- phase 6: poi = agg2 @ W2 + b2 -> sP + sPt (nt-split) ----
  {
    s8v a4[4];
#pragma unroll
    for (int ks = 0; ks < 4; ++ks) a4[ks] = *(const s8v*)(sAgg2 + swz128(mrow, ks * 32 + kblk));
#pragma unroll
    for (int j = 0; j < 4; ++j) {
      int nt = wn * 4 + j;
      int cg = nt * 16 + (l & 15);
      float bv = b2[cg];
      f32x4 acc = {bv, bv, bv, bv};
#pragma unroll
      for (int ks = 0; ks < 4; ++ks)
        acc = __builtin_amdgcn_mfma_f32_16x16x32_bf16(
            a4[ks], *(const s8v*)(sW2t + swz128(cg, ks * 32 + kblk)), acc, 0, 0, 0);
      u16 p0 = f2b(acc[0]), p1 = f2b(acc[1]), p2 = f2b(acc[2]), p3 = f2b(acc[3]);
#pragma unroll
      for (int rg = 0; rg < 4; ++rg)
        sP[swz128(rbase + rg, cg)] = (rg == 0) ? p0 : (rg == 1) ? p1 : (rg == 2) ? p2 : p3;
      uint2 pk;
      pk.x = (uint32_t)p0 | ((uint32_t)p1 << 16);
      pk.y = (uint32_t)p2 | ((uint32_t)p3 << 16);
      *(uint2*)(sPt + swz128(cg, rbase)) = pk;
    }
  }
  __syncthreads();

  // ---- tail A: pool partials (t<256) || el partials (256..1023) ----
  if (t < 256) {
    int c = t & 127, kh = t >> 7;
    float s = 0.f;
    const u16* rowp = sPt + c * 128;
    int sw = (c & 7) << 3;
#pragma unroll
    for (int k8 = kh * 8; k8 < kh * 8 + 8; ++k8) {
      s8v v = *(const s8v*)(rowp + ((k8 * 8) ^ sw));
#pragma unroll
      for (int j = 0; j < 8; ++j) s += b2f((u16)v[j]);
    }
    sPoolp[kh * 128 + c] = s;
  } else {
    int task = t - 256;
    int r = task & 127, hk = task >> 7;
    int h = hk >> 1, kh = hk & 1;
    int sw = (r & 7) << 3;
    const u16* rowp = sP + r * 128;
    const float* qh = &sQ[h * 128];
    float d = 0.f;
#pragma unroll
    for (int k8 = kh * 8; k8 < kh * 8 + 8; ++k8) {
      int c8 = (k8 * 8) ^ sw;
      s8v v = *(const s8v*)(rowp + c8);
#pragma unroll
      for (int j = 0; j < 8; ++j) d += b2f((u16)v[j]) * qh[c8 + j];
    }
    sElp[hk * 128 + r] = d;
  }
  __syncthreads();

  if (t < 128) {
    float s = sPoolp[t] + sPoolp[128 + t];
    sPool[t] = s;
    poi_pool[b * 128 + t] = s * (1.0f / 128.0f);
  }
  if (t >= 512 && t < 896) {
    int tt = t - 512;
    int h = tt >> 7, r = tt & 127;
    float e = sElp[h * 256 + r] + sElp[h * 256 + 128 + r] + sCh[h] + sEr[h];
    sAl[h * 128 + r] = (e > 0.f) ? e : 0.2f * e;
  }
  __syncthreads();

  if (t < 192) {
    int h = t >> 6, ll = t & 63;
    float v0 = sAl[h * 128 + ll], v1 = sAl[h * 128 + 64 + ll];
    float m = fmaxf(v0, v1);
    for (int off = 32; off > 0; off >>= 1) m = fmaxf(m, __shfl_xor(m, off));
    float x0 = __expf(v0 - m), x1 = __expf(v1 - m);
    float s = x0 + x1;
    for (int off = 32; off > 0; off >>= 1) s += __shfl_xor(s, off);
    float inv = 1.0f / s;
    sAl[h * 128 + ll] = x0 * inv;
    sAl[h * 128 + 64 + ll] = x1 * inv;
  }
  __syncthreads();

  if (t < 768) {
    int c = t & 127, hk = t >> 7;
    int hh = hk >> 1, kh = hk & 1;
    int sw = (c & 7) << 3;
    const u16* rowp = sPt + c * 128;
    const float* al = &sAl[hh * 128];
    float s = 0.f;
#pragma unroll
    for (int k8 = kh * 8; k8 < kh * 8 + 8; ++k8) {
      int r8 = (k8 * 8) ^ sw;
      s8v v = *(const s8v*)(rowp + r8);
#pragma unroll
      for (int j = 0; j < 8; ++j) s += b2f((u16)v[j]) * al[r8 + j];
    }
    sElp[hk * 128 + c] = s;
  }
  __syncthreads();

  if (t < 384) {
    int hh = t >> 7, c = t & 127;
    pooled[((size_t)b * 3 + hh) * 128 + c] = sElp[hh * 256 + c] + sElp[hh * 256 + 128 + c];
  }
  __syncthreads();

  float hv = 0.f, pv = 0.f;
  if (t < 128) {
    hv = hrs[base + t];
    pv = sPool[t] * (1.0f / 128.0f);
    sQ[t] = hv * hv + pv * pv;
  }
  __syncthreads();
  if (t < 64) {
    float v = sQ[t] + sQ[t + 64];
    for (int off = 32; off > 0; off >>= 1) v += __shfl_xor(v, off);
    if (t == 0) sQ[0] = rsqrtf(v);
  }
  __syncthreads();
  if (t < 128) {
    float rn = sQ[0];
    mfnb[b * 256 + t] = f2b(hv * rn);
    mfnb[b * 256 + 128 + t] = f2b(pv * rn);
  }
}

// ===================== med via MFMA + fused row-count =====================
__global__ void __launch_bounds__(256) k_med(const u16* __restrict__ mfnb,
                                             const float* __restrict__ T0p,
                                             float* __restrict__ med,
                                             int* __restrict__ rowcnt) {
  __shared__ u16 sA[32 * 256];
  __shared__ u16 sB[32 * 256];
  int bi = blockIdx.x >> 4, bj = blockIdx.x & 15;
  int t = threadIdx.x;
  const uint4* srcA = (const uint4*)(mfnb + (size_t)bi * 32 * 256);
  const uint4* srcB = (const uint4*)(mfnb + (size_t)bj * 32 * 256);
  for (int g = t; g < 1024; g += 256) {
    int r = g >> 5, blk = g & 31;
    int db = (blk & 24) | ((blk ^ (r & 7)) & 7);
    uint4 va = srcA[g];
    uint4 vb = srcB[g];
    *(uint4*)(sA + r * 256 + db * 8) = va;
    *(uint4*)(sB + r * 256 + db * 8) = vb;
  }
  __syncthreads();
  int l = t & 63, w = t >> 6;
  int wr = w >> 1, wc = w & 1;
  int arow = wr * 16 + (l & 15);
  int brow = wc * 16 + (l & 15);
  int kblk = (l >> 4) * 8;
  f32x4 acc = {0.f, 0.f, 0.f, 0.f};
#pragma unroll
  for (int ks = 0; ks < 8; ++ks) {
    int kc = ks * 32 + kblk;
    s8v a = *(const s8v*)(sA + arow * 256 + (kc ^ ((arow & 7) << 3)));
    s8v bb = *(const s8v*)(sB + brow * 256 + (kc ^ ((brow & 7) << 3)));
    acc = __builtin_amdgcn_mfma_f32_16x16x32_bf16(a, bb, acc, 0, 0, 0);
  }
  int row0 = bi * 32 + wr * 16 + (l >> 4) * 4;
  int col = bj * 32 + wc * 16 + (l & 15);
  float T0 = *T0p;
  int cnt4[4];
#pragma unroll
  for (int rg = 0; rg < 4; ++rg) {
    float m = (acc[rg] + 1.0f) * 0.5f;
    med[(size_t)(row0 + rg) * 512 + col] = m;
    cnt4[rg] = (m >= T0 || (row0 + rg) == col) ? 1 : 0;
  }
#pragma unroll
  for (int off = 1; off < 16; off <<= 1) {
#pragma unroll
    for (int rg = 0; rg < 4; ++rg) cnt4[rg] += __shfl_xor(cnt4[rg], off);
  }
  if ((l & 15) == 0) {
#pragma unroll
    for (int rg = 0; rg < 4; ++rg) atomicAdd(&rowcnt[row0 + rg], cnt4[rg]);
  }
}

// ===================== slim epilogue: sparse Aagg + folded 768->16 dot =====================
__global__ void __launch_bounds__(256) k_epilogue(
    const float* __restrict__ med, const float* __restrict__ T0p,
    const int* __restrict__ rowcnt, const float* __restrict__ hrs,
    const float* __restrict__ pool, const float* __restrict__ pooled,
    const float* __restrict__ Afold, const float* __restrict__ bias_out,
    float* __restrict__ out) {
  __shared__ float sMedRow[512];
  __shared__ float sIn[6][128];
  __shared__ float sRed[16][16];
  __shared__ int sNbr[64];
  __shared__ float sDw[64];
  __shared__ int sNnz;
  int i = blockIdx.x, t = threadIdx.x;
  float T0 = *T0p;

  for (int j = t; j < 512; j += 256) sMedRow[j] = med[(size_t)i * 512 + j];
  if (t < 128) sIn[0][t] = hrs[i * 128 + t];
  for (int k = t; k < 384; k += 256) sIn[3 + (k >> 7)][k & 127] = pooled[(size_t)i * 384 + k];
  __syncthreads();

  if (t < 64) {
    int cnt = 0, flags = 0;
#pragma unroll
    for (int k = 0; k < 8; ++k) {
      int j = t * 8 + k;
      if (sMedRow[j] >= T0 || j == i) {
        flags |= 1 << k;
        ++cnt;
      }
    }
    int off = cnt;
    for (int d = 1; d < 64; d <<= 1) {
      int v = __shfl_up(off, d);
      if (t >= d) off += v;
    }
    off -= cnt;
    int pos = off;
#pragma unroll
    for (int k = 0; k < 8; ++k)
      if (flags & (1 << k)) {
        int j = t * 8 + k;
        if (pos < 64) {
          sNbr[pos] = j;
          sDw[pos] = rsqrtf((float)rowcnt[j]);
        }
        ++pos;
      }
    if (t == 63) sNnz = off + cnt;
  }
  __syncthreads();

  {
    int half = t >> 7, c = t & 127;
    float di = rsqrtf((float)rowcnt[i]);
    const float* srcm = half ? pool : hrs;
    float acc = 0.f;
    int nnz = sNnz;
    if (nnz <= 64) {
      for (int n = 0; n < nnz; ++n) acc += sDw[n] * srcm[sNbr[n] * 128 + c];
    } else {
      for (int j = 0; j < 512; ++j)
        if (sMedRow[j] >= T0 || j == i) acc += rsqrtf((float)rowcnt[j]) * srcm[j * 128 + c];
    }
    sIn[1 + half][c] = acc * di;
  }
  __syncthreads();

  {
    int o = t >> 4, chunk = t & 15;
    int c0 = chunk * 8;
    float acc = 0.f;
#pragma unroll
    for (int m = 0; m < 6; ++m) {
      const float* A = Afold + m * 2048;
      const float* xm = sIn[m];
#pragma unroll
      for (int k = 0; k < 8; ++k) acc += xm[c0 + k] * A[(c0 + k) * 16 + o];
    }
    sRed[o][chunk] = acc;
  }
  __syncthreads();
  if (t < 16) {
    float acc = bias_out[t];
#pragma unroll
    for (int j = 0; j < 16; ++j) acc += sRed[t][j];
    out[i * 16 + t] = acc;
  }
}

// ===================== host =====================
extern "C" void kernel_launch(void* const* d_in, const int* in_sizes, int n_in,
                              void* d_out, int out_size, void* d_ws, size_t ws_size,
                              hipStream_t stream) {
  const float* poi_x = (const float*)d_in[0];
  const float* img = (const float*)d_in[1];
  const int* edges = (const int*)d_in[2];
  const float* T0p = (const float*)d_in[4];
  const float* W1 = (const float*)d_in[5];
  const float* b1 = (const float*)d_in[6];
  const float* W2 = (const float*)d_in[7];
  const float* b2 = (const float*)d_in[8];
  const float* Whrs = (const float*)d_in[9];
  const float* bhrs = (const float*)d_in[10];
  const float* Wph = (const float*)d_in[11];
  const float* bph = (const float*)d_in[12];
  const float* Wpp = (const float*)d_in[13];
  const float* bpp = (const float*)d_in[14];
  const float* Wg_in = (const float*)d_in[15];
  const float* al_in = (const float*)d_in[16];
  const float* ar_in = (const float*)d_in[17];
  const float* bg_in = (const float*)d_in[18];
  const float* Wg_w = (const float*)d_in[19];
  const float* bg_w = (const float*)d_in[22];
  const float* Wh1 = (const float*)d_in[23];
  const float* bh1 = (const float*)d_in[24];
  const float* Wp1 = (const float*)d_in[25];
  const float* bp1 = (const float*)d_in[26];
  const float* Wfc = (const float*)d_in[27];
  const float* bfc = (const float*)d_in[28];

  const int* esrc = edges;
  const int* edst = edges + EE;

  char* ws = (char*)d_ws;
  size_t off = 0;
  auto alloc = [&](size_t nbytes) -> char* {
    char* p = ws + off;
    off += (nbytes + 255) & ~(size_t)255;
    return p;
  };
  uint8_t* Sg4 = (uint8_t*)alloc((size_t)NN * 64);  // 4.2 MB nibble count table
  u16* w1t = (u16*)alloc(8192 * 2);
  u16* w2t = (u16*)alloc(16384 * 2);
  float* hrs = (float*)alloc(512 * 128 * 4);
  float* er = (float*)alloc(512 * 3 * 4);
  float* wv = (float*)alloc(384 * 4);
  float* q = (float*)alloc(384 * 4);
  float* chv = (float*)alloc(16);
  float* Afold = (float*)alloc(6 * 2048 * 4);
  float* bias_out = (float*)alloc(16 * 4);
  float* pool = (float*)alloc(512 * 128 * 4);
  float* pooled = (float*)alloc((size_t)1536 * 128 * 4);
  u16* mfnb = (u16*)alloc(512 * 256 * 2);
  int* rowcnt = (int*)alloc(512 * 4);

  float* out = (float*)d_out;
  float* med = out + 512 * 16;

  hipMemsetAsync(Sg4, 0, (size_t)NN * 64, stream);

  size_t dynf = 156416;
  hipFuncSetAttribute((const void*)k_gcn_fused, hipFuncAttributeMaxDynamicSharedMemorySize,
                      (int)dynf);

  k_front<<<417, 1024, 0, stream>>>(esrc, edst, (uint32_t*)Sg4, W1, W2, Wg_in, al_in, ar_in,
                                    Wpp, bpp, w1t, w2t, wv, q, chv, Wg_w, Wfc, bph, bg_in,
                                    rowcnt, img, Whrs, bhrs, Wph, hrs, er, Wh1, Wp1, bfc, bh1,
                                    bp1, bg_w, Afold, bias_out);
  k_gcn_fused<<<512, 1024, dynf, stream>>>(poi_x, b1, b2, Sg4, q, chv, er, hrs, w1t, w2t, pool,
                                           pooled, mfnb);
  k_med<<<256, 256, 0, stream>>>(mfnb, T0p, med, rowcnt);
  k_epilogue<<<512, 256, 0, stream>>>(med, T0p, rowcnt, hrs, pool, pooled, Afold, bias_out,
                                      out);

  (void)in_sizes; (void)n_in; (void)out_size; (void)ws_size;
}